// Round 5
// baseline (442.368 us; speedup 1.0000x reference)
//
#include <hip/hip_runtime.h>
#include <hip/hip_bf16.h>
#include <math.h>

#define NN 50000
#define EE 800000
#define IN_DIM 128
#define H1 8
#define D1 32
#define HID1 256
#define HID2 128
#define FC1 512
#define NEG_SLOPE 0.2f

typedef short v8s __attribute__((ext_vector_type(8)));
typedef float v4f __attribute__((ext_vector_type(4)));
typedef unsigned int v4u __attribute__((ext_vector_type(4)));

__device__ __forceinline__ float bf2f(unsigned short u) {
    unsigned int x = ((unsigned int)u) << 16;
    return __uint_as_float(x);
}

// ---------------- utility kernels ----------------

__global__ void fill_zero_int(int* p, int n) {
    int i = blockIdx.x * blockDim.x + threadIdx.x;
    if (i < n) p[i] = 0;
}

__global__ void hist_kernel(const int* __restrict__ dst, int* __restrict__ counts) {
    int e = blockIdx.x * blockDim.x + threadIdx.x;
    if (e < EE) atomicAdd(&counts[dst[e]], 1);
}

// ---- hierarchical exclusive scan ----

__global__ __launch_bounds__(256) void scan_a_kernel(const int* __restrict__ counts,
                                                     int* __restrict__ excl,
                                                     int* __restrict__ bsum, int n) {
    __shared__ int wsum[4];
    int tid = threadIdx.x;
    int base = blockIdx.x * 1024 + tid * 4;
    int v0 = 0, v1 = 0, v2 = 0, v3 = 0;
    if (base + 3 < n) {
        int4 t = *(const int4*)(counts + base);
        v0 = t.x; v1 = t.y; v2 = t.z; v3 = t.w;
    } else {
        if (base + 0 < n) v0 = counts[base + 0];
        if (base + 1 < n) v1 = counts[base + 1];
        if (base + 2 < n) v2 = counts[base + 2];
        if (base + 3 < n) v3 = counts[base + 3];
    }
    int tot = v0 + v1 + v2 + v3;
    int lane = tid & 63;
    int w = tid >> 6;
    int x = tot;
    #pragma unroll
    for (int off = 1; off < 64; off <<= 1) {
        int y = __shfl_up(x, off);
        if (lane >= off) x += y;
    }
    if (lane == 63) wsum[w] = x;
    __syncthreads();
    int woff = 0;
    for (int i = 0; i < w; i++) woff += wsum[i];
    int et = woff + x - tot;
    if (base + 0 < n) excl[base + 0] = et;
    if (base + 1 < n) excl[base + 1] = et + v0;
    if (base + 2 < n) excl[base + 2] = et + v0 + v1;
    if (base + 3 < n) excl[base + 3] = et + v0 + v1 + v2;
    if (tid == 255) bsum[blockIdx.x] = woff + x;
}

__global__ __launch_bounds__(64) void scan_b_kernel(int* __restrict__ bsum,
                                                    int* __restrict__ row_ptr, int nb, int n) {
    int lane = threadIdx.x;
    int v = (lane < nb) ? bsum[lane] : 0;
    int x = v;
    #pragma unroll
    for (int off = 1; off < 64; off <<= 1) {
        int y = __shfl_up(x, off);
        if (lane >= off) x += y;
    }
    if (lane < nb) bsum[lane] = x - v;
    if (lane == 63) row_ptr[n] = x;
}

__global__ __launch_bounds__(256) void scan_c_kernel(const int* __restrict__ excl,
                                                     const int* __restrict__ bsum,
                                                     int* __restrict__ row_ptr,
                                                     int* __restrict__ cursor, int n) {
    int base = blockIdx.x * 1024 + threadIdx.x * 4;
    int off = bsum[blockIdx.x];
    #pragma unroll
    for (int j = 0; j < 4; j++) {
        int i = base + j;
        if (i < n) {
            int r = excl[i] + off;
            row_ptr[i] = r;
            cursor[i] = r;
        }
    }
}

__global__ void scatter_kernel(const int* __restrict__ src, const int* __restrict__ dst,
                               int* __restrict__ cursor, int* __restrict__ eidx,
                               int* __restrict__ srcs) {
    int e = blockIdx.x * blockDim.x + threadIdx.x;
    if (e >= EE) return;
    int d = dst[e];
    int p = atomicAdd(&cursor[d], 1);
    eidx[p] = e;
    srcs[p] = src[e];
}

__global__ void cvt_bf16_kernel(const float* __restrict__ in, __hip_bfloat16* __restrict__ out, int n) {
    int i = blockIdx.x * blockDim.x + threadIdx.x;
    if (i < n) out[i] = __float2bfloat16(in[i]);
}

// pack fp32 weight B[K][N] into MFMA fragment-major bf16
__global__ void pack_kernel(const float* __restrict__ B, __hip_bfloat16* __restrict__ Bp,
                            int K, int N) {
    int idx = blockIdx.x * blockDim.x + threadIdx.x;
    if (idx >= K * N) return;
    int k = idx / N, n = idx % N;
    int ntile = n >> 4, ks = k >> 5, kk = k & 31;
    int lane = (n & 15) | ((kk >> 3) << 4);
    int j = kk & 7;
    int KS = K >> 5;
    Bp[((size_t)(ntile * KS + ks) * 64 + lane) * 8 + j] = __float2bfloat16(B[idx]);
}

// ---------------- MFMA GEMM ----------------

__global__ __launch_bounds__(256) void mgemm_kernel(const __hip_bfloat16* __restrict__ A,
                                                    const __hip_bfloat16* __restrict__ Bp,
                                                    float* __restrict__ C,
                                                    __hip_bfloat16* __restrict__ Cbf,
                                                    int M, int K, int N) {
    int w = threadIdx.x >> 6, l = threadIdx.x & 63;
    int bm = blockIdx.x * 128 + w * 32;
    int bn = blockIdx.y * 64;
    int lr = l & 15, lk = l >> 4;
    int KS = K >> 5;
    const short* Ab = (const short*)A;
    const short* Bb = (const short*)Bp;
    v4f acc[2][4];
    #pragma unroll
    for (int mi = 0; mi < 2; mi++)
        #pragma unroll
        for (int nt = 0; nt < 4; nt++) acc[mi][nt] = (v4f)(0.f);
    for (int ks = 0; ks < KS; ks++) {
        v8s a[2];
        #pragma unroll
        for (int mi = 0; mi < 2; mi++) {
            int gm = bm + mi * 16 + lr;
            a[mi] = (gm < M) ? *(const v8s*)(Ab + (size_t)gm * K + ks * 32 + lk * 8)
                             : (v8s)(short)0;
        }
        #pragma unroll
        for (int nt = 0; nt < 4; nt++) {
            int ntile = (bn >> 4) + nt;
            v8s b = *(const v8s*)(Bb + ((size_t)(ntile * KS + ks) * 64 + l) * 8);
            acc[0][nt] = __builtin_amdgcn_mfma_f32_16x16x32_bf16(a[0], b, acc[0][nt], 0, 0, 0);
            acc[1][nt] = __builtin_amdgcn_mfma_f32_16x16x32_bf16(a[1], b, acc[1][nt], 0, 0, 0);
        }
    }
    #pragma unroll
    for (int mi = 0; mi < 2; mi++) {
        #pragma unroll
        for (int nt = 0; nt < 4; nt++) {
            int gn = bn + nt * 16 + lr;
            #pragma unroll
            for (int j = 0; j < 4; j++) {
                int gm = bm + mi * 16 + lk * 4 + j;
                if (gm < M) {
                    float v = acc[mi][nt][j];
                    C[(size_t)gm * N + gn] = v;
                    Cbf[(size_t)gm * N + gn] = __float2bfloat16(v);
                }
            }
        }
    }
}

// ---------------- fused FC head via MFMA ----------------

__global__ __launch_bounds__(256) void fc_mfma_kernel(const __hip_bfloat16* __restrict__ A,
                                                      const __hip_bfloat16* __restrict__ Bp,
                                                      const float* __restrict__ fcb1,
                                                      const float* __restrict__ fcW2,
                                                      const float* __restrict__ fcb2,
                                                      float* __restrict__ out) {
    __shared__ float red[4][32];
    int w = threadIdx.x >> 6, l = threadIdx.x & 63;
    int bm = blockIdx.x * 32;
    int lr = l & 15, lk = l >> 4;
    const int K = HID2, KS = K >> 5;
    const short* Ab = (const short*)A;
    const short* Bb = (const short*)Bp;
    v4f acc[2][8];
    #pragma unroll
    for (int mi = 0; mi < 2; mi++)
        #pragma unroll
        for (int nt = 0; nt < 8; nt++) acc[mi][nt] = (v4f)(0.f);
    for (int ks = 0; ks < KS; ks++) {
        v8s a[2];
        #pragma unroll
        for (int mi = 0; mi < 2; mi++) {
            int gm = bm + mi * 16 + lr;
            a[mi] = (gm < NN) ? *(const v8s*)(Ab + (size_t)gm * K + ks * 32 + lk * 8)
                              : (v8s)(short)0;
        }
        #pragma unroll
        for (int nt = 0; nt < 8; nt++) {
            int ntile = w * 8 + nt;
            v8s b = *(const v8s*)(Bb + ((size_t)(ntile * KS + ks) * 64 + l) * 8);
            acc[0][nt] = __builtin_amdgcn_mfma_f32_16x16x32_bf16(a[0], b, acc[0][nt], 0, 0, 0);
            acc[1][nt] = __builtin_amdgcn_mfma_f32_16x16x32_bf16(a[1], b, acc[1][nt], 0, 0, 0);
        }
    }
    float p[2][4];
    #pragma unroll
    for (int mi = 0; mi < 2; mi++)
        #pragma unroll
        for (int j = 0; j < 4; j++) p[mi][j] = 0.f;
    #pragma unroll
    for (int nt = 0; nt < 8; nt++) {
        int col = w * 128 + nt * 16 + lr;
        float b1v = fcb1[col], w2v = fcW2[col];
        #pragma unroll
        for (int mi = 0; mi < 2; mi++) {
            #pragma unroll
            for (int j = 0; j < 4; j++) {
                float v = acc[mi][nt][j] + b1v;
                p[mi][j] += ((v > 0.f) ? v : 0.f) * w2v;
            }
        }
    }
    #pragma unroll
    for (int mi = 0; mi < 2; mi++)
        #pragma unroll
        for (int j = 0; j < 4; j++) {
            float v = p[mi][j];
            v += __shfl_xor(v, 1);
            v += __shfl_xor(v, 2);
            v += __shfl_xor(v, 4);
            v += __shfl_xor(v, 8);
            p[mi][j] = v;
        }
    if (lr == 0) {
        #pragma unroll
        for (int mi = 0; mi < 2; mi++)
            #pragma unroll
            for (int j = 0; j < 4; j++) red[w][mi * 16 + lk * 4 + j] = p[mi][j];
    }
    __syncthreads();
    int tid = threadIdx.x;
    if (tid < 32) {
        int gm = bm + tid;
        if (gm < NN)
            out[gm] = red[0][tid] + red[1][tid] + red[2][tid] + red[3][tid] + fcb2[0];
    }
}

// ---------------- layer 1 attention logits ----------------

__global__ void att1_kernel(const float* __restrict__ h1, const float* __restrict__ att_src,
                            const float* __restrict__ att_dst, float* __restrict__ a_s,
                            float* __restrict__ a_d) {
    int idx = blockIdx.x * blockDim.x + threadIdx.x;
    if (idx >= NN * H1) return;
    int n = idx >> 3, h = idx & 7;
    const float* row = h1 + (size_t)n * HID1 + h * D1;
    float s = 0.f, d = 0.f;
    #pragma unroll
    for (int k = 0; k < D1; k++) {
        float v = row[k];
        s += v * att_src[h * D1 + k];
        d += v * att_dst[h * D1 + k];
    }
    a_s[idx] = s;
    a_d[idx] = d;
}

// ---------------- fused edge-logit + segment-softmax, layer 1 ----------------
// wave per node: lane = (j,h), j = lane>>3 edge slot, h = lane&7 head.
// e is recomputed from a_s gathers (1.6MB table, L2-resident) each pass.

__global__ void fsoftmax1_kernel(const int* __restrict__ row_ptr, const int* __restrict__ eidx,
                                 const int* __restrict__ srcs,
                                 const float* __restrict__ a_s, const float* __restrict__ a_d,
                                 float* __restrict__ alpha_csr, float* __restrict__ alpha1_out) {
    int n = blockIdx.x * 4 + (threadIdx.x >> 6);
    int lane = threadIdx.x & 63;
    if (n >= NN) return;
    int start = row_ptr[n], end = row_ptr[n + 1];
    if (start == end) return;
    int h = lane & 7, j = lane >> 3;
    float ad = a_d[n * 8 + h];
    float m = -INFINITY;
    for (int p = start + j; p < end; p += 8) {
        float v = a_s[srcs[p] * 8 + h] + ad;
        v = (v >= 0.f) ? v : NEG_SLOPE * v;
        m = fmaxf(m, v);
    }
    m = fmaxf(m, __shfl_xor(m, 8));
    m = fmaxf(m, __shfl_xor(m, 16));
    m = fmaxf(m, __shfl_xor(m, 32));
    float s = 0.f;
    for (int p = start + j; p < end; p += 8) {
        float v = a_s[srcs[p] * 8 + h] + ad;
        v = (v >= 0.f) ? v : NEG_SLOPE * v;
        s += expf(v - m);
    }
    s += __shfl_xor(s, 8);
    s += __shfl_xor(s, 16);
    s += __shfl_xor(s, 32);
    float inv = 1.f / (s + 1e-16f);
    for (int p = start + j; p < end; p += 8) {
        float v = a_s[srcs[p] * 8 + h] + ad;
        v = (v >= 0.f) ? v : NEG_SLOPE * v;
        float a = expf(v - m) * inv;
        alpha_csr[(size_t)p * 8 + h] = a;
        alpha1_out[(size_t)eidx[p] * 8 + h] = a;
    }
}

// ---------------- layer 1 aggregation v2: 16B gathers, 4-deep pipeline ----------------
// lane: r = l>>5 (edge sub-slot), c = l&31 (dim chunk, dims c*8..c*8+7, head c>>2).
// per 8-edge round wave covers edges {w*2+r}; 4 rounds unrolled -> 4 loads in flight.

#define CH1 128
__global__ __launch_bounds__(256) void agg1_kernel(const int* __restrict__ row_ptr,
                                                   const int* __restrict__ srcs,
                                                   const float* __restrict__ alpha_csr,
                                                   const __hip_bfloat16* __restrict__ h1bf,
                                                   const float* __restrict__ b1,
                                                   __hip_bfloat16* __restrict__ x1bf) {
    __shared__ int s_src[CH1];
    __shared__ float s_al[CH1][8];
    __shared__ float red[4][HID1];
    int n = blockIdx.x;
    int tid = threadIdx.x;
    int w = tid >> 6, l = tid & 63;
    int r = l >> 5, c = l & 31;
    int hh = c >> 2;
    int start = row_ptr[n], end = row_ptr[n + 1];
    float acc[8] = {};
    const unsigned short* hb = (const unsigned short*)h1bf;
    for (int c0 = start; c0 < end; c0 += CH1) {
        int cnt = min(CH1, end - c0);
        for (int i = tid; i < cnt; i += 256) s_src[i] = srcs[c0 + i];
        for (int i = tid; i < cnt * 8; i += 256) ((float*)s_al)[i] = alpha_csr[(size_t)c0 * 8 + i];
        __syncthreads();
        int j = w * 2 + r;
        for (; j + 24 < cnt; j += 32) {
            int s0 = s_src[j], s1 = s_src[j + 8], s2 = s_src[j + 16], s3 = s_src[j + 24];
            v4u q0 = *(const v4u*)(hb + (size_t)s0 * HID1 + c * 8);
            v4u q1 = *(const v4u*)(hb + (size_t)s1 * HID1 + c * 8);
            v4u q2 = *(const v4u*)(hb + (size_t)s2 * HID1 + c * 8);
            v4u q3 = *(const v4u*)(hb + (size_t)s3 * HID1 + c * 8);
            float al0 = s_al[j][hh], al1 = s_al[j + 8][hh];
            float al2 = s_al[j + 16][hh], al3 = s_al[j + 24][hh];
            #pragma unroll
            for (int k = 0; k < 4; k++) {
                acc[2 * k]     += al0 * __uint_as_float(q0[k] << 16);
                acc[2 * k + 1] += al0 * __uint_as_float(q0[k] & 0xffff0000u);
                acc[2 * k]     += al1 * __uint_as_float(q1[k] << 16);
                acc[2 * k + 1] += al1 * __uint_as_float(q1[k] & 0xffff0000u);
                acc[2 * k]     += al2 * __uint_as_float(q2[k] << 16);
                acc[2 * k + 1] += al2 * __uint_as_float(q2[k] & 0xffff0000u);
                acc[2 * k]     += al3 * __uint_as_float(q3[k] << 16);
                acc[2 * k + 1] += al3 * __uint_as_float(q3[k] & 0xffff0000u);
            }
        }
        for (; j < cnt; j += 8) {
            int s0 = s_src[j];
            v4u q0 = *(const v4u*)(hb + (size_t)s0 * HID1 + c * 8);
            float al0 = s_al[j][hh];
            #pragma unroll
            for (int k = 0; k < 4; k++) {
                acc[2 * k]     += al0 * __uint_as_float(q0[k] << 16);
                acc[2 * k + 1] += al0 * __uint_as_float(q0[k] & 0xffff0000u);
            }
        }
        __syncthreads();
    }
    #pragma unroll
    for (int d = 0; d < 8; d++) acc[d] += __shfl_xor(acc[d], 32);
    if (r == 0) {
        #pragma unroll
        for (int d = 0; d < 8; d++) red[w][c * 8 + d] = acc[d];
    }
    __syncthreads();
    float rr = red[0][tid] + red[1][tid] + red[2][tid] + red[3][tid] + b1[tid];
    rr = (rr > 0.f) ? rr : expf(rr) - 1.f;  // ELU
    x1bf[(size_t)n * HID1 + tid] = __float2bfloat16(rr);
}

// ---------------- layer 2 attention logits (1 head) ----------------

__global__ __launch_bounds__(64) void att2_kernel(const float* __restrict__ h2,
                                                  const float* __restrict__ att_src,
                                                  const float* __restrict__ att_dst,
                                                  float* __restrict__ a_s, float* __restrict__ a_d) {
    int n = blockIdx.x;
    int lane = threadIdx.x;
    const float* row = h2 + (size_t)n * HID2;
    float s = 0.f, d = 0.f;
    for (int k = lane; k < HID2; k += 64) {
        float v = row[k];
        s += v * att_src[k];
        d += v * att_dst[k];
    }
    for (int off = 32; off; off >>= 1) {
        s += __shfl_down(s, off);
        d += __shfl_down(d, off);
    }
    if (lane == 0) {
        a_s[n] = s;
        a_d[n] = d;
    }
}

// ---------------- fused edge-logit + segment-softmax, layer 2 ----------------

__global__ void fsoftmax2_kernel(const int* __restrict__ row_ptr, const int* __restrict__ eidx,
                                 const int* __restrict__ srcs,
                                 const float* __restrict__ a_s, const float* __restrict__ a_d,
                                 float* __restrict__ alpha_csr, float* __restrict__ alpha2_out) {
    int n = blockIdx.x * 4 + (threadIdx.x >> 6);
    int lane = threadIdx.x & 63;
    if (n >= NN) return;
    int start = row_ptr[n], end = row_ptr[n + 1];
    if (start == end) return;
    float ad = a_d[n];
    float m = -INFINITY;
    for (int p = start + lane; p < end; p += 64) {
        float v = a_s[srcs[p]] + ad;
        v = (v >= 0.f) ? v : NEG_SLOPE * v;
        m = fmaxf(m, v);
    }
    for (int off = 32; off; off >>= 1) m = fmaxf(m, __shfl_xor(m, off));
    float s = 0.f;
    for (int p = start + lane; p < end; p += 64) {
        float v = a_s[srcs[p]] + ad;
        v = (v >= 0.f) ? v : NEG_SLOPE * v;
        s += expf(v - m);
    }
    for (int off = 32; off; off >>= 1) s += __shfl_xor(s, off);
    float inv = 1.f / (s + 1e-16f);
    for (int p = start + lane; p < end; p += 64) {
        float v = a_s[srcs[p]] + ad;
        v = (v >= 0.f) ? v : NEG_SLOPE * v;
        float a = expf(v - m) * inv;
        alpha_csr[p] = a;
        alpha2_out[eidx[p]] = a;
    }
}

// ---------------- layer 2 aggregation v2: 16B gathers ----------------
// lane: rr = l>>4 (edge sub-slot 0..3), c = l&15 (dims c*8..c*8+7).
// per 16-edge round wave covers edges {w*4+rr}; 2 rounds unrolled.

#define CH2 256
__global__ __launch_bounds__(256) void agg2_kernel(const int* __restrict__ row_ptr,
                                                   const int* __restrict__ srcs,
                                                   const float* __restrict__ alpha_csr,
                                                   const __hip_bfloat16* __restrict__ h2bf,
                                                   const float* __restrict__ b2,
                                                   __hip_bfloat16* __restrict__ x2bf) {
    __shared__ int s_src[CH2];
    __shared__ float s_al[CH2];
    __shared__ float red[4][HID2];
    int n = blockIdx.x;
    int tid = threadIdx.x;
    int w = tid >> 6, l = tid & 63;
    int rr = l >> 4, c = l & 15;
    int start = row_ptr[n], end = row_ptr[n + 1];
    float acc[8] = {};
    const unsigned short* hb = (const unsigned short*)h2bf;
    for (int c0 = start; c0 < end; c0 += CH2) {
        int cnt = min(CH2, end - c0);
        for (int i = tid; i < cnt; i += 256) {
            s_src[i] = srcs[c0 + i];
            s_al[i] = alpha_csr[c0 + i];
        }
        __syncthreads();
        int j = w * 4 + rr;
        for (; j + 16 < cnt; j += 32) {
            int s0 = s_src[j], s1 = s_src[j + 16];
            v4u q0 = *(const v4u*)(hb + (size_t)s0 * HID2 + c * 8);
            v4u q1 = *(const v4u*)(hb + (size_t)s1 * HID2 + c * 8);
            float al0 = s_al[j], al1 = s_al[j + 16];
            #pragma unroll
            for (int k = 0; k < 4; k++) {
                acc[2 * k]     += al0 * __uint_as_float(q0[k] << 16);
                acc[2 * k + 1] += al0 * __uint_as_float(q0[k] & 0xffff0000u);
                acc[2 * k]     += al1 * __uint_as_float(q1[k] << 16);
                acc[2 * k + 1] += al1 * __uint_as_float(q1[k] & 0xffff0000u);
            }
        }
        for (; j < cnt; j += 16) {
            int s0 = s_src[j];
            v4u q0 = *(const v4u*)(hb + (size_t)s0 * HID2 + c * 8);
            float al0 = s_al[j];
            #pragma unroll
            for (int k = 0; k < 4; k++) {
                acc[2 * k]     += al0 * __uint_as_float(q0[k] << 16);
                acc[2 * k + 1] += al0 * __uint_as_float(q0[k] & 0xffff0000u);
            }
        }
        __syncthreads();
    }
    #pragma unroll
    for (int d = 0; d < 8; d++) {
        acc[d] += __shfl_xor(acc[d], 16);
        acc[d] += __shfl_xor(acc[d], 32);
    }
    if (rr == 0) {
        #pragma unroll
        for (int d = 0; d < 8; d++) red[w][c * 8 + d] = acc[d];
    }
    __syncthreads();
    if (tid < HID2) {
        float r = red[0][tid] + red[1][tid] + red[2][tid] + red[3][tid] + b2[tid];
        r = (r > 0.f) ? r : 0.f;  // ReLU
        x2bf[(size_t)n * HID2 + tid] = __float2bfloat16(r);
    }
}

// ---------------- host launch ----------------

extern "C" void kernel_launch(void* const* d_in, const int* in_sizes, int n_in,
                              void* d_out, int out_size, void* d_ws, size_t ws_size,
                              hipStream_t stream) {
    (void)in_sizes; (void)n_in; (void)out_size; (void)ws_size;
    const float* x        = (const float*)d_in[0];
    const int*   eindex   = (const int*)d_in[1];
    const float* W1       = (const float*)d_in[2];
    const float* att_src1 = (const float*)d_in[3];
    const float* att_dst1 = (const float*)d_in[4];
    const float* b1       = (const float*)d_in[5];
    const float* W2       = (const float*)d_in[6];
    const float* att_src2 = (const float*)d_in[7];
    const float* att_dst2 = (const float*)d_in[8];
    const float* b2       = (const float*)d_in[9];
    const float* fcW1     = (const float*)d_in[10];
    const float* fcb1     = (const float*)d_in[11];
    const float* fcW2     = (const float*)d_in[12];
    const float* fcb2     = (const float*)d_in[13];

    const int* src = eindex;
    const int* dst = eindex + EE;

    float* out_n      = (float*)d_out;               // [N]
    float* alpha1_out = out_n + NN;                  // [E,8]
    float* alpha2_out = alpha1_out + (size_t)EE * 8; // [E]

    char* ws = (char*)d_ws;
    size_t off = 0;
    auto alloc = [&](size_t bytes) {
        size_t o = off;
        off = (off + bytes + 255) & ~(size_t)255;
        return o;
    };
    size_t o_rowptr = alloc((NN + 1) * sizeof(int));
    size_t o_cursor = alloc(NN * sizeof(int));
    size_t o_counts = alloc(NN * sizeof(int));
    size_t o_excl   = alloc(NN * sizeof(int));
    size_t o_bsum   = alloc(64 * sizeof(int));
    size_t o_eidx   = alloc(EE * sizeof(int));
    size_t o_srcs   = alloc(EE * sizeof(int));
    size_t o_h1     = alloc((size_t)NN * HID1 * sizeof(float));
    size_t o_e1s    = alloc((size_t)EE * H1 * sizeof(float));
    size_t o_as1    = alloc((size_t)NN * H1 * sizeof(float));
    size_t o_ad1    = alloc((size_t)NN * H1 * sizeof(float));
    size_t o_h1bf   = alloc((size_t)NN * HID1 * sizeof(__hip_bfloat16));
    size_t o_xbf    = alloc((size_t)NN * IN_DIM * sizeof(__hip_bfloat16));
    size_t o_x1bf   = alloc((size_t)NN * HID1 * sizeof(__hip_bfloat16));
    size_t o_x2bf   = alloc((size_t)NN * HID2 * sizeof(__hip_bfloat16));
    size_t o_W1p    = alloc((size_t)IN_DIM * HID1 * sizeof(__hip_bfloat16));
    size_t o_W2p    = alloc((size_t)HID1 * HID2 * sizeof(__hip_bfloat16));
    size_t o_fW1p   = alloc((size_t)HID2 * FC1 * sizeof(__hip_bfloat16));

    int*   row_ptr = (int*)(ws + o_rowptr);
    int*   cursor  = (int*)(ws + o_cursor);
    int*   counts  = (int*)(ws + o_counts);
    int*   excl    = (int*)(ws + o_excl);
    int*   bsum    = (int*)(ws + o_bsum);
    int*   eidx    = (int*)(ws + o_eidx);
    int*   srcs    = (int*)(ws + o_srcs);
    float* h1      = (float*)(ws + o_h1);
    float* e1s     = (float*)(ws + o_e1s);
    float* a_s1    = (float*)(ws + o_as1);
    float* a_d1    = (float*)(ws + o_ad1);
    __hip_bfloat16* h1bf  = (__hip_bfloat16*)(ws + o_h1bf);
    __hip_bfloat16* xbf   = (__hip_bfloat16*)(ws + o_xbf);
    __hip_bfloat16* x1bf  = (__hip_bfloat16*)(ws + o_x1bf);
    __hip_bfloat16* x2bf  = (__hip_bfloat16*)(ws + o_x2bf);
    __hip_bfloat16* W1p   = (__hip_bfloat16*)(ws + o_W1p);
    __hip_bfloat16* W2p   = (__hip_bfloat16*)(ws + o_W2p);
    __hip_bfloat16* fW1p  = (__hip_bfloat16*)(ws + o_fW1p);
    // layer-2 aliases
    float* h2   = h1;
    float* e2s  = e1s;
    float* a_s2 = a_s1;
    float* a_d2 = a_d1;
    __hip_bfloat16* h2bf = h1bf;

    const int SCAN_NB = (NN + 1023) / 1024;  // 49

    // ---- build CSR by dst ----
    fill_zero_int<<<(NN + 255) / 256, 256, 0, stream>>>(counts, NN);
    hist_kernel<<<(EE + 255) / 256, 256, 0, stream>>>(dst, counts);
    scan_a_kernel<<<SCAN_NB, 256, 0, stream>>>(counts, excl, bsum, NN);
    scan_b_kernel<<<1, 64, 0, stream>>>(bsum, row_ptr, SCAN_NB, NN);
    scan_c_kernel<<<SCAN_NB, 256, 0, stream>>>(excl, bsum, row_ptr, cursor, NN);
    scatter_kernel<<<(EE + 255) / 256, 256, 0, stream>>>(src, dst, cursor, eidx, srcs);

    // ---- input conversions / weight packing ----
    cvt_bf16_kernel<<<(NN * IN_DIM + 255) / 256, 256, 0, stream>>>(x, xbf, NN * IN_DIM);
    pack_kernel<<<(IN_DIM * HID1 + 255) / 256, 256, 0, stream>>>(W1, W1p, IN_DIM, HID1);
    pack_kernel<<<(HID1 * HID2 + 255) / 256, 256, 0, stream>>>(W2, W2p, HID1, HID2);
    pack_kernel<<<(HID2 * FC1 + 255) / 256, 256, 0, stream>>>(fcW1, fW1p, HID2, FC1);

    // ---- layer 1 ----
    mgemm_kernel<<<dim3((NN + 127) / 128, HID1 / 64), 256, 0, stream>>>(
        xbf, W1p, h1, h1bf, NN, IN_DIM, HID1);
    att1_kernel<<<(NN * H1 + 255) / 256, 256, 0, stream>>>(h1, att_src1, att_dst1, a_s1, a_d1);
    fsoftmax1_kernel<<<(NN + 3) / 4, 256, 0, stream>>>(row_ptr, eidx, srcs, a_s1, a_d1,
                                                       e1s, alpha1_out);
    agg1_kernel<<<NN, 256, 0, stream>>>(row_ptr, srcs, e1s, h1bf, b1, x1bf);

    // ---- layer 2 ----
    mgemm_kernel<<<dim3((NN + 127) / 128, HID2 / 64), 256, 0, stream>>>(
        x1bf, W2p, h2, h2bf, NN, HID1, HID2);
    att2_kernel<<<NN, 64, 0, stream>>>(h2, att_src2, att_dst2, a_s2, a_d2);
    fsoftmax2_kernel<<<(NN + 3) / 4, 256, 0, stream>>>(row_ptr, eidx, srcs, a_s2, a_d2,
                                                       e2s, alpha2_out);
    agg2_kernel<<<NN, 256, 0, stream>>>(row_ptr, srcs, e2s, h2bf, b2, x2bf);

    // ---- FC head ----
    fc_mfma_kernel<<<(NN + 31) / 32, 256, 0, stream>>>(x2bf, fW1p, fcb1, fcW2, fcb2, out_n);
}

// Round 6
// 405.540 us; speedup vs baseline: 1.0908x; 1.0908x over previous
//
#include <hip/hip_runtime.h>
#include <hip/hip_bf16.h>
#include <math.h>

#define NN 50000
#define EE 800000
#define IN_DIM 128
#define H1 8
#define D1 32
#define HID1 256
#define HID2 128
#define FC1 512
#define NEG_SLOPE 0.2f

typedef short v8s __attribute__((ext_vector_type(8)));
typedef float v4f __attribute__((ext_vector_type(4)));

__device__ __forceinline__ float bf2f(unsigned short u) {
    unsigned int x = ((unsigned int)u) << 16;
    return __uint_as_float(x);
}
__device__ __forceinline__ unsigned short f2bf(float v) {
    __hip_bfloat16 h = __float2bfloat16(v);
    return *(unsigned short*)&h;
}

// ---------------- utility kernels ----------------

__global__ void fill_zero_int(int* p, int n) {
    int i = blockIdx.x * blockDim.x + threadIdx.x;
    if (i < n) p[i] = 0;
}

__global__ void hist_kernel(const int* __restrict__ dst, int* __restrict__ counts) {
    int e = blockIdx.x * blockDim.x + threadIdx.x;
    if (e < EE) atomicAdd(&counts[dst[e]], 1);
}

// ---- hierarchical exclusive scan ----

__global__ __launch_bounds__(256) void scan_a_kernel(const int* __restrict__ counts,
                                                     int* __restrict__ excl,
                                                     int* __restrict__ bsum, int n) {
    __shared__ int wsum[4];
    int tid = threadIdx.x;
    int base = blockIdx.x * 1024 + tid * 4;
    int v0 = 0, v1 = 0, v2 = 0, v3 = 0;
    if (base + 3 < n) {
        int4 t = *(const int4*)(counts + base);
        v0 = t.x; v1 = t.y; v2 = t.z; v3 = t.w;
    } else {
        if (base + 0 < n) v0 = counts[base + 0];
        if (base + 1 < n) v1 = counts[base + 1];
        if (base + 2 < n) v2 = counts[base + 2];
        if (base + 3 < n) v3 = counts[base + 3];
    }
    int tot = v0 + v1 + v2 + v3;
    int lane = tid & 63;
    int w = tid >> 6;
    int x = tot;
    #pragma unroll
    for (int off = 1; off < 64; off <<= 1) {
        int y = __shfl_up(x, off);
        if (lane >= off) x += y;
    }
    if (lane == 63) wsum[w] = x;
    __syncthreads();
    int woff = 0;
    for (int i = 0; i < w; i++) woff += wsum[i];
    int et = woff + x - tot;
    if (base + 0 < n) excl[base + 0] = et;
    if (base + 1 < n) excl[base + 1] = et + v0;
    if (base + 2 < n) excl[base + 2] = et + v0 + v1;
    if (base + 3 < n) excl[base + 3] = et + v0 + v1 + v2;
    if (tid == 255) bsum[blockIdx.x] = woff + x;
}

__global__ __launch_bounds__(64) void scan_b_kernel(int* __restrict__ bsum,
                                                    int* __restrict__ row_ptr, int nb, int n) {
    int lane = threadIdx.x;
    int v = (lane < nb) ? bsum[lane] : 0;
    int x = v;
    #pragma unroll
    for (int off = 1; off < 64; off <<= 1) {
        int y = __shfl_up(x, off);
        if (lane >= off) x += y;
    }
    if (lane < nb) bsum[lane] = x - v;
    if (lane == 63) row_ptr[n] = x;
}

__global__ __launch_bounds__(256) void scan_c_kernel(const int* __restrict__ excl,
                                                     const int* __restrict__ bsum,
                                                     int* __restrict__ row_ptr,
                                                     int* __restrict__ cursor, int n) {
    int base = blockIdx.x * 1024 + threadIdx.x * 4;
    int off = bsum[blockIdx.x];
    #pragma unroll
    for (int j = 0; j < 4; j++) {
        int i = base + j;
        if (i < n) {
            int r = excl[i] + off;
            row_ptr[i] = r;
            cursor[i] = r;
        }
    }
}

__global__ void scatter_kernel(const int* __restrict__ src, const int* __restrict__ dst,
                               int* __restrict__ cursor, int* __restrict__ eidx,
                               int* __restrict__ srcs) {
    int e = blockIdx.x * blockDim.x + threadIdx.x;
    if (e >= EE) return;
    int d = dst[e];
    int p = atomicAdd(&cursor[d], 1);
    eidx[p] = e;
    srcs[p] = src[e];
}

__global__ void cvt_bf16_kernel(const float* __restrict__ in, __hip_bfloat16* __restrict__ out, int n) {
    int i = blockIdx.x * blockDim.x + threadIdx.x;
    if (i < n) out[i] = __float2bfloat16(in[i]);
}

// pack fp32 weight B[K][N] into MFMA fragment-major bf16
__global__ void pack_kernel(const float* __restrict__ B, __hip_bfloat16* __restrict__ Bp,
                            int K, int N) {
    int idx = blockIdx.x * blockDim.x + threadIdx.x;
    if (idx >= K * N) return;
    int k = idx / N, n = idx % N;
    int ntile = n >> 4, ks = k >> 5, kk = k & 31;
    int lane = (n & 15) | ((kk >> 3) << 4);
    int j = kk & 7;
    int KS = K >> 5;
    Bp[((size_t)(ntile * KS + ks) * 64 + lane) * 8 + j] = __float2bfloat16(B[idx]);
}

// ---------------- MFMA GEMM ----------------

__global__ __launch_bounds__(256) void mgemm_kernel(const __hip_bfloat16* __restrict__ A,
                                                    const __hip_bfloat16* __restrict__ Bp,
                                                    float* __restrict__ C,
                                                    __hip_bfloat16* __restrict__ Cbf,
                                                    int M, int K, int N) {
    int w = threadIdx.x >> 6, l = threadIdx.x & 63;
    int bm = blockIdx.x * 128 + w * 32;
    int bn = blockIdx.y * 64;
    int lr = l & 15, lk = l >> 4;
    int KS = K >> 5;
    const short* Ab = (const short*)A;
    const short* Bb = (const short*)Bp;
    v4f acc[2][4];
    #pragma unroll
    for (int mi = 0; mi < 2; mi++)
        #pragma unroll
        for (int nt = 0; nt < 4; nt++) acc[mi][nt] = (v4f)(0.f);
    for (int ks = 0; ks < KS; ks++) {
        v8s a[2];
        #pragma unroll
        for (int mi = 0; mi < 2; mi++) {
            int gm = bm + mi * 16 + lr;
            a[mi] = (gm < M) ? *(const v8s*)(Ab + (size_t)gm * K + ks * 32 + lk * 8)
                             : (v8s)(short)0;
        }
        #pragma unroll
        for (int nt = 0; nt < 4; nt++) {
            int ntile = (bn >> 4) + nt;
            v8s b = *(const v8s*)(Bb + ((size_t)(ntile * KS + ks) * 64 + l) * 8);
            acc[0][nt] = __builtin_amdgcn_mfma_f32_16x16x32_bf16(a[0], b, acc[0][nt], 0, 0, 0);
            acc[1][nt] = __builtin_amdgcn_mfma_f32_16x16x32_bf16(a[1], b, acc[1][nt], 0, 0, 0);
        }
    }
    #pragma unroll
    for (int mi = 0; mi < 2; mi++) {
        #pragma unroll
        for (int nt = 0; nt < 4; nt++) {
            int gn = bn + nt * 16 + lr;
            #pragma unroll
            for (int j = 0; j < 4; j++) {
                int gm = bm + mi * 16 + lk * 4 + j;
                if (gm < M) {
                    float v = acc[mi][nt][j];
                    C[(size_t)gm * N + gn] = v;
                    Cbf[(size_t)gm * N + gn] = __float2bfloat16(v);
                }
            }
        }
    }
}

// ---------------- fused FC head via MFMA ----------------

__global__ __launch_bounds__(256) void fc_mfma_kernel(const __hip_bfloat16* __restrict__ A,
                                                      const __hip_bfloat16* __restrict__ Bp,
                                                      const float* __restrict__ fcb1,
                                                      const float* __restrict__ fcW2,
                                                      const float* __restrict__ fcb2,
                                                      float* __restrict__ out) {
    __shared__ float red[4][32];
    int w = threadIdx.x >> 6, l = threadIdx.x & 63;
    int bm = blockIdx.x * 32;
    int lr = l & 15, lk = l >> 4;
    const int K = HID2, KS = K >> 5;
    const short* Ab = (const short*)A;
    const short* Bb = (const short*)Bp;
    v4f acc[2][8];
    #pragma unroll
    for (int mi = 0; mi < 2; mi++)
        #pragma unroll
        for (int nt = 0; nt < 8; nt++) acc[mi][nt] = (v4f)(0.f);
    for (int ks = 0; ks < KS; ks++) {
        v8s a[2];
        #pragma unroll
        for (int mi = 0; mi < 2; mi++) {
            int gm = bm + mi * 16 + lr;
            a[mi] = (gm < NN) ? *(const v8s*)(Ab + (size_t)gm * K + ks * 32 + lk * 8)
                              : (v8s)(short)0;
        }
        #pragma unroll
        for (int nt = 0; nt < 8; nt++) {
            int ntile = w * 8 + nt;
            v8s b = *(const v8s*)(Bb + ((size_t)(ntile * KS + ks) * 64 + l) * 8);
            acc[0][nt] = __builtin_amdgcn_mfma_f32_16x16x32_bf16(a[0], b, acc[0][nt], 0, 0, 0);
            acc[1][nt] = __builtin_amdgcn_mfma_f32_16x16x32_bf16(a[1], b, acc[1][nt], 0, 0, 0);
        }
    }
    float p[2][4];
    #pragma unroll
    for (int mi = 0; mi < 2; mi++)
        #pragma unroll
        for (int j = 0; j < 4; j++) p[mi][j] = 0.f;
    #pragma unroll
    for (int nt = 0; nt < 8; nt++) {
        int col = w * 128 + nt * 16 + lr;
        float b1v = fcb1[col], w2v = fcW2[col];
        #pragma unroll
        for (int mi = 0; mi < 2; mi++) {
            #pragma unroll
            for (int j = 0; j < 4; j++) {
                float v = acc[mi][nt][j] + b1v;
                p[mi][j] += ((v > 0.f) ? v : 0.f) * w2v;
            }
        }
    }
    #pragma unroll
    for (int mi = 0; mi < 2; mi++)
        #pragma unroll
        for (int j = 0; j < 4; j++) {
            float v = p[mi][j];
            v += __shfl_xor(v, 1);
            v += __shfl_xor(v, 2);
            v += __shfl_xor(v, 4);
            v += __shfl_xor(v, 8);
            p[mi][j] = v;
        }
    if (lr == 0) {
        #pragma unroll
        for (int mi = 0; mi < 2; mi++)
            #pragma unroll
            for (int j = 0; j < 4; j++) red[w][mi * 16 + lk * 4 + j] = p[mi][j];
    }
    __syncthreads();
    int tid = threadIdx.x;
    if (tid < 32) {
        int gm = bm + tid;
        if (gm < NN)
            out[gm] = red[0][tid] + red[1][tid] + red[2][tid] + red[3][tid] + fcb2[0];
    }
}

// ---------------- layer 1 attention logits ----------------

__global__ void att1_kernel(const float* __restrict__ h1, const float* __restrict__ att_src,
                            const float* __restrict__ att_dst, float* __restrict__ a_s,
                            float* __restrict__ a_d) {
    int idx = blockIdx.x * blockDim.x + threadIdx.x;
    if (idx >= NN * H1) return;
    int n = idx >> 3, h = idx & 7;
    const float* row = h1 + (size_t)n * HID1 + h * D1;
    float s = 0.f, d = 0.f;
    #pragma unroll
    for (int k = 0; k < D1; k++) {
        float v = row[k];
        s += v * att_src[h * D1 + k];
        d += v * att_dst[h * D1 + k];
    }
    a_s[idx] = s;
    a_d[idx] = d;
}

// ---------------- fused edge-logit + segment-softmax, layer 1 ----------------
// fast path (cnt<=64): lane-per-edge, one 32B a_s gather per edge, register e-values,
// butterfly shfl_xor reductions. Fallback: 3-pass gather (j,h layout).

__global__ void fsoftmax1_kernel(const int* __restrict__ row_ptr, const int* __restrict__ eidx,
                                 const int* __restrict__ srcs,
                                 const float* __restrict__ a_s, const float* __restrict__ a_d,
                                 float* __restrict__ alpha_csr, float* __restrict__ alpha1_out) {
    int n = blockIdx.x * 4 + (threadIdx.x >> 6);
    int lane = threadIdx.x & 63;
    if (n >= NN) return;
    int start = row_ptr[n], end = row_ptr[n + 1];
    int cnt = end - start;
    if (cnt == 0) return;
    if (cnt <= 64) {
        int p = start + lane;
        bool act = lane < cnt;
        int sj = act ? srcs[p] : 0;
        v4f as0 = *(const v4f*)(a_s + (size_t)sj * 8);
        v4f as1 = *(const v4f*)(a_s + (size_t)sj * 8 + 4);
        v4f ad0 = *(const v4f*)(a_d + (size_t)n * 8);
        v4f ad1 = *(const v4f*)(a_d + (size_t)n * 8 + 4);
        float ev[8];
        #pragma unroll
        for (int h = 0; h < 4; h++) {
            float v = as0[h] + ad0[h];
            v = (v >= 0.f) ? v : NEG_SLOPE * v;
            ev[h] = act ? v : -INFINITY;
            float v2 = as1[h] + ad1[h];
            v2 = (v2 >= 0.f) ? v2 : NEG_SLOPE * v2;
            ev[h + 4] = act ? v2 : -INFINITY;
        }
        float mv[8];
        #pragma unroll
        for (int h = 0; h < 8; h++) mv[h] = ev[h];
        #pragma unroll
        for (int off = 1; off < 64; off <<= 1) {
            #pragma unroll
            for (int h = 0; h < 8; h++) mv[h] = fmaxf(mv[h], __shfl_xor(mv[h], off));
        }
        float ex[8], sv[8];
        #pragma unroll
        for (int h = 0; h < 8; h++) {
            ex[h] = expf(ev[h] - mv[h]);  // inactive: exp(-inf)=0
            sv[h] = ex[h];
        }
        #pragma unroll
        for (int off = 1; off < 64; off <<= 1) {
            #pragma unroll
            for (int h = 0; h < 8; h++) sv[h] += __shfl_xor(sv[h], off);
        }
        if (act) {
            v4f o0, o1;
            #pragma unroll
            for (int h = 0; h < 4; h++) {
                o0[h] = ex[h] / (sv[h] + 1e-16f);
                o1[h] = ex[h + 4] / (sv[h + 4] + 1e-16f);
            }
            *(v4f*)(alpha_csr + (size_t)p * 8) = o0;
            *(v4f*)(alpha_csr + (size_t)p * 8 + 4) = o1;
            int eo = eidx[p];
            *(v4f*)(alpha1_out + (size_t)eo * 8) = o0;
            *(v4f*)(alpha1_out + (size_t)eo * 8 + 4) = o1;
        }
    } else {
        int h = lane & 7, j = lane >> 3;
        float ad = a_d[n * 8 + h];
        float m = -INFINITY;
        for (int p = start + j; p < end; p += 8) {
            float v = a_s[srcs[p] * 8 + h] + ad;
            v = (v >= 0.f) ? v : NEG_SLOPE * v;
            m = fmaxf(m, v);
        }
        m = fmaxf(m, __shfl_xor(m, 8));
        m = fmaxf(m, __shfl_xor(m, 16));
        m = fmaxf(m, __shfl_xor(m, 32));
        float s = 0.f;
        for (int p = start + j; p < end; p += 8) {
            float v = a_s[srcs[p] * 8 + h] + ad;
            v = (v >= 0.f) ? v : NEG_SLOPE * v;
            s += expf(v - m);
        }
        s += __shfl_xor(s, 8);
        s += __shfl_xor(s, 16);
        s += __shfl_xor(s, 32);
        float inv = 1.f / (s + 1e-16f);
        for (int p = start + j; p < end; p += 8) {
            float v = a_s[srcs[p] * 8 + h] + ad;
            v = (v >= 0.f) ? v : NEG_SLOPE * v;
            float a = expf(v - m) * inv;
            alpha_csr[(size_t)p * 8 + h] = a;
            alpha1_out[(size_t)eidx[p] * 8 + h] = a;
        }
    }
}

// ---------------- layer 1 aggregation: wave-per-node, register/shfl, no LDS ----------------
// lane l owns dims 4l..4l+3 (8B ushort4 gather); head h = l>>3.
// 16-edge chunks: srcs in lane regs (lane<16), alphas in 2 regs; __shfl broadcast.

__global__ __launch_bounds__(256) void agg1_kernel(const int* __restrict__ row_ptr,
                                                   const int* __restrict__ srcs,
                                                   const float* __restrict__ alpha_csr,
                                                   const __hip_bfloat16* __restrict__ h1bf,
                                                   const float* __restrict__ b1,
                                                   __hip_bfloat16* __restrict__ x1bf) {
    int w = threadIdx.x >> 6, l = threadIdx.x & 63;
    int n = blockIdx.x * 4 + w;
    if (n >= NN) return;
    int h = l >> 3;
    int start = row_ptr[n], end = row_ptr[n + 1];
    float acc0 = 0.f, acc1 = 0.f, acc2 = 0.f, acc3 = 0.f;
    const unsigned short* hb = (const unsigned short*)h1bf;
    for (int c0 = start; c0 < end; c0 += 16) {
        int cnt = min(16, end - c0);
        int s_reg = (l < cnt) ? srcs[c0 + l] : 0;
        float a0 = (l < cnt * 8) ? alpha_csr[(size_t)c0 * 8 + l] : 0.f;
        float a1 = (l + 64 < cnt * 8) ? alpha_csr[(size_t)c0 * 8 + 64 + l] : 0.f;
        #pragma unroll 4
        for (int j = 0; j < cnt; ++j) {
            int sj = __shfl(s_reg, j);
            float al = __shfl((j & 8) ? a1 : a0, ((j & 7) << 3) + h);
            ushort4 q = *(const ushort4*)(hb + (size_t)sj * HID1 + l * 4);
            acc0 += al * bf2f(q.x);
            acc1 += al * bf2f(q.y);
            acc2 += al * bf2f(q.z);
            acc3 += al * bf2f(q.w);
        }
    }
    float4 bb = *(const float4*)(b1 + l * 4);
    float r0 = acc0 + bb.x, r1 = acc1 + bb.y, r2 = acc2 + bb.z, r3 = acc3 + bb.w;
    r0 = (r0 > 0.f) ? r0 : expf(r0) - 1.f;
    r1 = (r1 > 0.f) ? r1 : expf(r1) - 1.f;
    r2 = (r2 > 0.f) ? r2 : expf(r2) - 1.f;
    r3 = (r3 > 0.f) ? r3 : expf(r3) - 1.f;
    ushort4 o;
    o.x = f2bf(r0); o.y = f2bf(r1); o.z = f2bf(r2); o.w = f2bf(r3);
    *(ushort4*)((unsigned short*)x1bf + (size_t)n * HID1 + l * 4) = o;
}

// ---------------- layer 2 attention logits (1 head) ----------------

__global__ __launch_bounds__(64) void att2_kernel(const float* __restrict__ h2,
                                                  const float* __restrict__ att_src,
                                                  const float* __restrict__ att_dst,
                                                  float* __restrict__ a_s, float* __restrict__ a_d) {
    int n = blockIdx.x;
    int lane = threadIdx.x;
    const float* row = h2 + (size_t)n * HID2;
    float s = 0.f, d = 0.f;
    for (int k = lane; k < HID2; k += 64) {
        float v = row[k];
        s += v * att_src[k];
        d += v * att_dst[k];
    }
    for (int off = 32; off; off >>= 1) {
        s += __shfl_down(s, off);
        d += __shfl_down(d, off);
    }
    if (lane == 0) {
        a_s[n] = s;
        a_d[n] = d;
    }
}

// ---------------- fused edge-logit + segment-softmax, layer 2 ----------------

__global__ void fsoftmax2_kernel(const int* __restrict__ row_ptr, const int* __restrict__ eidx,
                                 const int* __restrict__ srcs,
                                 const float* __restrict__ a_s, const float* __restrict__ a_d,
                                 float* __restrict__ alpha_csr, float* __restrict__ alpha2_out) {
    int n = blockIdx.x * 4 + (threadIdx.x >> 6);
    int lane = threadIdx.x & 63;
    if (n >= NN) return;
    int start = row_ptr[n], end = row_ptr[n + 1];
    int cnt = end - start;
    if (cnt == 0) return;
    float ad = a_d[n];
    if (cnt <= 64) {
        int p = start + lane;
        bool act = lane < cnt;
        int sj = act ? srcs[p] : 0;
        float v = a_s[sj] + ad;
        v = (v >= 0.f) ? v : NEG_SLOPE * v;
        float e = act ? v : -INFINITY;
        float m = e;
        #pragma unroll
        for (int off = 1; off < 64; off <<= 1) m = fmaxf(m, __shfl_xor(m, off));
        float ex = expf(e - m);
        float s = ex;
        #pragma unroll
        for (int off = 1; off < 64; off <<= 1) s += __shfl_xor(s, off);
        if (act) {
            float a = ex / (s + 1e-16f);
            alpha_csr[p] = a;
            alpha2_out[eidx[p]] = a;
        }
    } else {
        float m = -INFINITY;
        for (int p = start + lane; p < end; p += 64) {
            float v = a_s[srcs[p]] + ad;
            v = (v >= 0.f) ? v : NEG_SLOPE * v;
            m = fmaxf(m, v);
        }
        for (int off = 32; off; off >>= 1) m = fmaxf(m, __shfl_xor(m, off));
        float s = 0.f;
        for (int p = start + lane; p < end; p += 64) {
            float v = a_s[srcs[p]] + ad;
            v = (v >= 0.f) ? v : NEG_SLOPE * v;
            s += expf(v - m);
        }
        for (int off = 32; off; off >>= 1) s += __shfl_xor(s, off);
        float inv = 1.f / (s + 1e-16f);
        for (int p = start + lane; p < end; p += 64) {
            float v = a_s[srcs[p]] + ad;
            v = (v >= 0.f) ? v : NEG_SLOPE * v;
            float a = expf(v - m) * inv;
            alpha_csr[p] = a;
            alpha2_out[eidx[p]] = a;
        }
    }
}

// ---------------- layer 2 aggregation: wave-per-node, register/shfl ----------------
// lane: r = l>>5 (edge sub-slot 0/1), c = l&31 owns dims 4c..4c+3 (8B gather).
// 64-edge chunks in lane regs; 2 edges per round; final shfl_xor(32) reduce.

__global__ __launch_bounds__(256) void agg2_kernel(const int* __restrict__ row_ptr,
                                                   const int* __restrict__ srcs,
                                                   const float* __restrict__ alpha_csr,
                                                   const __hip_bfloat16* __restrict__ h2bf,
                                                   const float* __restrict__ b2,
                                                   __hip_bfloat16* __restrict__ x2bf) {
    int w = threadIdx.x >> 6, l = threadIdx.x & 63;
    int n = blockIdx.x * 4 + w;
    if (n >= NN) return;
    int r = l >> 5, c = l & 31;
    int start = row_ptr[n], end = row_ptr[n + 1];
    float acc0 = 0.f, acc1 = 0.f, acc2 = 0.f, acc3 = 0.f;
    const unsigned short* hb = (const unsigned short*)h2bf;
    for (int c0 = start; c0 < end; c0 += 64) {
        int cnt = min(64, end - c0);
        int s_reg = (l < cnt) ? srcs[c0 + l] : 0;
        float a_reg = (l < cnt) ? alpha_csr[c0 + l] : 0.f;
        #pragma unroll 4
        for (int j = 0; j < cnt; j += 2) {
            int jj = j + r;
            int sj = __shfl(s_reg, jj);
            float al = __shfl(a_reg, jj);
            if (jj < cnt) {
                ushort4 q = *(const ushort4*)(hb + (size_t)sj * HID2 + c * 4);
                acc0 += al * bf2f(q.x);
                acc1 += al * bf2f(q.y);
                acc2 += al * bf2f(q.z);
                acc3 += al * bf2f(q.w);
            }
        }
    }
    acc0 += __shfl_xor(acc0, 32);
    acc1 += __shfl_xor(acc1, 32);
    acc2 += __shfl_xor(acc2, 32);
    acc3 += __shfl_xor(acc3, 32);
    if (r == 0) {
        float4 bb = *(const float4*)(b2 + c * 4);
        float r0 = acc0 + bb.x, r1 = acc1 + bb.y, r2 = acc2 + bb.z, r3 = acc3 + bb.w;
        r0 = (r0 > 0.f) ? r0 : 0.f;
        r1 = (r1 > 0.f) ? r1 : 0.f;
        r2 = (r2 > 0.f) ? r2 : 0.f;
        r3 = (r3 > 0.f) ? r3 : 0.f;
        ushort4 o;
        o.x = f2bf(r0); o.y = f2bf(r1); o.z = f2bf(r2); o.w = f2bf(r3);
        *(ushort4*)((unsigned short*)x2bf + (size_t)n * HID2 + c * 4) = o;
    }
}

// ---------------- host launch ----------------

extern "C" void kernel_launch(void* const* d_in, const int* in_sizes, int n_in,
                              void* d_out, int out_size, void* d_ws, size_t ws_size,
                              hipStream_t stream) {
    (void)in_sizes; (void)n_in; (void)out_size; (void)ws_size;
    const float* x        = (const float*)d_in[0];
    const int*   eindex   = (const int*)d_in[1];
    const float* W1       = (const float*)d_in[2];
    const float* att_src1 = (const float*)d_in[3];
    const float* att_dst1 = (const float*)d_in[4];
    const float* b1       = (const float*)d_in[5];
    const float* W2       = (const float*)d_in[6];
    const float* att_src2 = (const float*)d_in[7];
    const float* att_dst2 = (const float*)d_in[8];
    const float* b2       = (const float*)d_in[9];
    const float* fcW1     = (const float*)d_in[10];
    const float* fcb1     = (const float*)d_in[11];
    const float* fcW2     = (const float*)d_in[12];
    const float* fcb2     = (const float*)d_in[13];

    const int* src = eindex;
    const int* dst = eindex + EE;

    float* out_n      = (float*)d_out;               // [N]
    float* alpha1_out = out_n + NN;                  // [E,8]
    float* alpha2_out = alpha1_out + (size_t)EE * 8; // [E]

    char* ws = (char*)d_ws;
    size_t off = 0;
    auto alloc = [&](size_t bytes) {
        size_t o = off;
        off = (off + bytes + 255) & ~(size_t)255;
        return o;
    };
    size_t o_rowptr = alloc((NN + 1) * sizeof(int));
    size_t o_cursor = alloc(NN * sizeof(int));
    size_t o_counts = alloc(NN * sizeof(int));
    size_t o_excl   = alloc(NN * sizeof(int));
    size_t o_bsum   = alloc(64 * sizeof(int));
    size_t o_eidx   = alloc(EE * sizeof(int));
    size_t o_srcs   = alloc(EE * sizeof(int));
    size_t o_h1     = alloc((size_t)NN * HID1 * sizeof(float));
    size_t o_e1s    = alloc((size_t)EE * H1 * sizeof(float));
    size_t o_as1    = alloc((size_t)NN * H1 * sizeof(float));
    size_t o_ad1    = alloc((size_t)NN * H1 * sizeof(float));
    size_t o_h1bf   = alloc((size_t)NN * HID1 * sizeof(__hip_bfloat16));
    size_t o_xbf    = alloc((size_t)NN * IN_DIM * sizeof(__hip_bfloat16));
    size_t o_x1bf   = alloc((size_t)NN * HID1 * sizeof(__hip_bfloat16));
    size_t o_x2bf   = alloc((size_t)NN * HID2 * sizeof(__hip_bfloat16));
    size_t o_W1p    = alloc((size_t)IN_DIM * HID1 * sizeof(__hip_bfloat16));
    size_t o_W2p    = alloc((size_t)HID1 * HID2 * sizeof(__hip_bfloat16));
    size_t o_fW1p   = alloc((size_t)HID2 * FC1 * sizeof(__hip_bfloat16));

    int*   row_ptr = (int*)(ws + o_rowptr);
    int*   cursor  = (int*)(ws + o_cursor);
    int*   counts  = (int*)(ws + o_counts);
    int*   excl    = (int*)(ws + o_excl);
    int*   bsum    = (int*)(ws + o_bsum);
    int*   eidx    = (int*)(ws + o_eidx);
    int*   srcs    = (int*)(ws + o_srcs);
    float* h1      = (float*)(ws + o_h1);
    float* e1s     = (float*)(ws + o_e1s);
    float* a_s1    = (float*)(ws + o_as1);
    float* a_d1    = (float*)(ws + o_ad1);
    __hip_bfloat16* h1bf  = (__hip_bfloat16*)(ws + o_h1bf);
    __hip_bfloat16* xbf   = (__hip_bfloat16*)(ws + o_xbf);
    __hip_bfloat16* x1bf  = (__hip_bfloat16*)(ws + o_x1bf);
    __hip_bfloat16* x2bf  = (__hip_bfloat16*)(ws + o_x2bf);
    __hip_bfloat16* W1p   = (__hip_bfloat16*)(ws + o_W1p);
    __hip_bfloat16* W2p   = (__hip_bfloat16*)(ws + o_W2p);
    __hip_bfloat16* fW1p  = (__hip_bfloat16*)(ws + o_fW1p);
    // layer-2 aliases
    float* h2   = h1;
    float* e2s  = e1s;
    float* a_s2 = a_s1;
    float* a_d2 = a_d1;
    __hip_bfloat16* h2bf = h1bf;

    const int SCAN_NB = (NN + 1023) / 1024;  // 49

    // ---- build CSR by dst ----
    fill_zero_int<<<(NN + 255) / 256, 256, 0, stream>>>(counts, NN);
    hist_kernel<<<(EE + 255) / 256, 256, 0, stream>>>(dst, counts);
    scan_a_kernel<<<SCAN_NB, 256, 0, stream>>>(counts, excl, bsum, NN);
    scan_b_kernel<<<1, 64, 0, stream>>>(bsum, row_ptr, SCAN_NB, NN);
    scan_c_kernel<<<SCAN_NB, 256, 0, stream>>>(excl, bsum, row_ptr, cursor, NN);
    scatter_kernel<<<(EE + 255) / 256, 256, 0, stream>>>(src, dst, cursor, eidx, srcs);

    // ---- input conversions / weight packing ----
    cvt_bf16_kernel<<<(NN * IN_DIM + 255) / 256, 256, 0, stream>>>(x, xbf, NN * IN_DIM);
    pack_kernel<<<(IN_DIM * HID1 + 255) / 256, 256, 0, stream>>>(W1, W1p, IN_DIM, HID1);
    pack_kernel<<<(HID1 * HID2 + 255) / 256, 256, 0, stream>>>(W2, W2p, HID1, HID2);
    pack_kernel<<<(HID2 * FC1 + 255) / 256, 256, 0, stream>>>(fcW1, fW1p, HID2, FC1);

    // ---- layer 1 ----
    mgemm_kernel<<<dim3((NN + 127) / 128, HID1 / 64), 256, 0, stream>>>(
        xbf, W1p, h1, h1bf, NN, IN_DIM, HID1);
    att1_kernel<<<(NN * H1 + 255) / 256, 256, 0, stream>>>(h1, att_src1, att_dst1, a_s1, a_d1);
    fsoftmax1_kernel<<<(NN + 3) / 4, 256, 0, stream>>>(row_ptr, eidx, srcs, a_s1, a_d1,
                                                       e1s, alpha1_out);
    agg1_kernel<<<(NN + 3) / 4, 256, 0, stream>>>(row_ptr, srcs, e1s, h1bf, b1, x1bf);

    // ---- layer 2 ----
    mgemm_kernel<<<dim3((NN + 127) / 128, HID2 / 64), 256, 0, stream>>>(
        x1bf, W2p, h2, h2bf, NN, HID1, HID2);
    att2_kernel<<<NN, 64, 0, stream>>>(h2, att_src2, att_dst2, a_s2, a_d2);
    fsoftmax2_kernel<<<(NN + 3) / 4, 256, 0, stream>>>(row_ptr, eidx, srcs, a_s2, a_d2,
                                                       e2s, alpha2_out);
    agg2_kernel<<<(NN + 3) / 4, 256, 0, stream>>>(row_ptr, srcs, e2s, h2bf, b2, x2bf);

    // ---- FC head ----
    fc_mfma_kernel<<<(NN + 31) / 32, 256, 0, stream>>>(x2bf, fW1p, fcb1, fcW2, fcb2, out_n);
}

// Round 7
// 368.027 us; speedup vs baseline: 1.2020x; 1.1019x over previous
//
#include <hip/hip_runtime.h>
#include <hip/hip_bf16.h>
#include <math.h>

#define NN 50000
#define EE 800000
#define IN_DIM 128
#define H1 8
#define D1 32
#define HID1 256
#define HID2 128
#define FC1 512
#define NEG_SLOPE 0.2f

typedef short v8s __attribute__((ext_vector_type(8)));
typedef float v4f __attribute__((ext_vector_type(4)));
typedef unsigned int v4u __attribute__((ext_vector_type(4)));

__device__ __forceinline__ float bf2f(unsigned short u) {
    unsigned int x = ((unsigned int)u) << 16;
    return __uint_as_float(x);
}
__device__ __forceinline__ unsigned short f2bf(float v) {
    __hip_bfloat16 h = __float2bfloat16(v);
    return *(unsigned short*)&h;
}

// ---------------- utility kernels ----------------

__global__ void fill_zero_int(int* p, int n) {
    int i = blockIdx.x * blockDim.x + threadIdx.x;
    if (i < n) p[i] = 0;
}

__global__ void hist_kernel(const int* __restrict__ dst, int* __restrict__ counts) {
    int e = blockIdx.x * blockDim.x + threadIdx.x;
    if (e < EE) atomicAdd(&counts[dst[e]], 1);
}

// ---- hierarchical exclusive scan ----

__global__ __launch_bounds__(256) void scan_a_kernel(const int* __restrict__ counts,
                                                     int* __restrict__ excl,
                                                     int* __restrict__ bsum, int n) {
    __shared__ int wsum[4];
    int tid = threadIdx.x;
    int base = blockIdx.x * 1024 + tid * 4;
    int v0 = 0, v1 = 0, v2 = 0, v3 = 0;
    if (base + 3 < n) {
        int4 t = *(const int4*)(counts + base);
        v0 = t.x; v1 = t.y; v2 = t.z; v3 = t.w;
    } else {
        if (base + 0 < n) v0 = counts[base + 0];
        if (base + 1 < n) v1 = counts[base + 1];
        if (base + 2 < n) v2 = counts[base + 2];
        if (base + 3 < n) v3 = counts[base + 3];
    }
    int tot = v0 + v1 + v2 + v3;
    int lane = tid & 63;
    int w = tid >> 6;
    int x = tot;
    #pragma unroll
    for (int off = 1; off < 64; off <<= 1) {
        int y = __shfl_up(x, off);
        if (lane >= off) x += y;
    }
    if (lane == 63) wsum[w] = x;
    __syncthreads();
    int woff = 0;
    for (int i = 0; i < w; i++) woff += wsum[i];
    int et = woff + x - tot;
    if (base + 0 < n) excl[base + 0] = et;
    if (base + 1 < n) excl[base + 1] = et + v0;
    if (base + 2 < n) excl[base + 2] = et + v0 + v1;
    if (base + 3 < n) excl[base + 3] = et + v0 + v1 + v2;
    if (tid == 255) bsum[blockIdx.x] = woff + x;
}

__global__ __launch_bounds__(64) void scan_b_kernel(int* __restrict__ bsum,
                                                    int* __restrict__ row_ptr, int nb, int n) {
    int lane = threadIdx.x;
    int v = (lane < nb) ? bsum[lane] : 0;
    int x = v;
    #pragma unroll
    for (int off = 1; off < 64; off <<= 1) {
        int y = __shfl_up(x, off);
        if (lane >= off) x += y;
    }
    if (lane < nb) bsum[lane] = x - v;
    if (lane == 63) row_ptr[n] = x;
}

__global__ __launch_bounds__(256) void scan_c_kernel(const int* __restrict__ excl,
                                                     const int* __restrict__ bsum,
                                                     int* __restrict__ row_ptr,
                                                     int* __restrict__ cursor, int n) {
    int base = blockIdx.x * 1024 + threadIdx.x * 4;
    int off = bsum[blockIdx.x];
    #pragma unroll
    for (int j = 0; j < 4; j++) {
        int i = base + j;
        if (i < n) {
            int r = excl[i] + off;
            row_ptr[i] = r;
            cursor[i] = r;
        }
    }
}

__global__ void scatter_kernel(const int* __restrict__ src, const int* __restrict__ dst,
                               int* __restrict__ cursor, int* __restrict__ eidx,
                               int* __restrict__ srcs) {
    int e = blockIdx.x * blockDim.x + threadIdx.x;
    if (e >= EE) return;
    int d = dst[e];
    int p = atomicAdd(&cursor[d], 1);
    eidx[p] = e;
    srcs[p] = src[e];
}

__global__ void cvt_bf16_kernel(const float* __restrict__ in, __hip_bfloat16* __restrict__ out, int n) {
    int i = blockIdx.x * blockDim.x + threadIdx.x;
    if (i < n) out[i] = __float2bfloat16(in[i]);
}

// pack fp32 weight B[K][N] into MFMA fragment-major bf16
__global__ void pack_kernel(const float* __restrict__ B, __hip_bfloat16* __restrict__ Bp,
                            int K, int N) {
    int idx = blockIdx.x * blockDim.x + threadIdx.x;
    if (idx >= K * N) return;
    int k = idx / N, n = idx % N;
    int ntile = n >> 4, ks = k >> 5, kk = k & 31;
    int lane = (n & 15) | ((kk >> 3) << 4);
    int j = kk & 7;
    int KS = K >> 5;
    Bp[((size_t)(ntile * KS + ks) * 64 + lane) * 8 + j] = __float2bfloat16(B[idx]);
}

// ---------------- MFMA GEMM (bf16 in, bf16 out) ----------------

__global__ __launch_bounds__(256) void mgemm_kernel(const __hip_bfloat16* __restrict__ A,
                                                    const __hip_bfloat16* __restrict__ Bp,
                                                    __hip_bfloat16* __restrict__ Cbf,
                                                    int M, int K, int N) {
    int w = threadIdx.x >> 6, l = threadIdx.x & 63;
    int bm = blockIdx.x * 128 + w * 32;
    int bn = blockIdx.y * 64;
    int lr = l & 15, lk = l >> 4;
    int KS = K >> 5;
    const short* Ab = (const short*)A;
    const short* Bb = (const short*)Bp;
    v4f acc[2][4];
    #pragma unroll
    for (int mi = 0; mi < 2; mi++)
        #pragma unroll
        for (int nt = 0; nt < 4; nt++) acc[mi][nt] = (v4f)(0.f);
    for (int ks = 0; ks < KS; ks++) {
        v8s a[2];
        #pragma unroll
        for (int mi = 0; mi < 2; mi++) {
            int gm = bm + mi * 16 + lr;
            a[mi] = (gm < M) ? *(const v8s*)(Ab + (size_t)gm * K + ks * 32 + lk * 8)
                             : (v8s)(short)0;
        }
        #pragma unroll
        for (int nt = 0; nt < 4; nt++) {
            int ntile = (bn >> 4) + nt;
            v8s b = *(const v8s*)(Bb + ((size_t)(ntile * KS + ks) * 64 + l) * 8);
            acc[0][nt] = __builtin_amdgcn_mfma_f32_16x16x32_bf16(a[0], b, acc[0][nt], 0, 0, 0);
            acc[1][nt] = __builtin_amdgcn_mfma_f32_16x16x32_bf16(a[1], b, acc[1][nt], 0, 0, 0);
        }
    }
    #pragma unroll
    for (int mi = 0; mi < 2; mi++) {
        #pragma unroll
        for (int nt = 0; nt < 4; nt++) {
            int gn = bn + nt * 16 + lr;
            #pragma unroll
            for (int j = 0; j < 4; j++) {
                int gm = bm + mi * 16 + lk * 4 + j;
                if (gm < M)
                    Cbf[(size_t)gm * N + gn] = __float2bfloat16(acc[mi][nt][j]);
            }
        }
    }
}

// ---------------- fused FC head via MFMA ----------------

__global__ __launch_bounds__(256) void fc_mfma_kernel(const __hip_bfloat16* __restrict__ A,
                                                      const __hip_bfloat16* __restrict__ Bp,
                                                      const float* __restrict__ fcb1,
                                                      const float* __restrict__ fcW2,
                                                      const float* __restrict__ fcb2,
                                                      float* __restrict__ out) {
    __shared__ float red[4][32];
    int w = threadIdx.x >> 6, l = threadIdx.x & 63;
    int bm = blockIdx.x * 32;
    int lr = l & 15, lk = l >> 4;
    const int K = HID2, KS = K >> 5;
    const short* Ab = (const short*)A;
    const short* Bb = (const short*)Bp;
    v4f acc[2][8];
    #pragma unroll
    for (int mi = 0; mi < 2; mi++)
        #pragma unroll
        for (int nt = 0; nt < 8; nt++) acc[mi][nt] = (v4f)(0.f);
    for (int ks = 0; ks < KS; ks++) {
        v8s a[2];
        #pragma unroll
        for (int mi = 0; mi < 2; mi++) {
            int gm = bm + mi * 16 + lr;
            a[mi] = (gm < NN) ? *(const v8s*)(Ab + (size_t)gm * K + ks * 32 + lk * 8)
                              : (v8s)(short)0;
        }
        #pragma unroll
        for (int nt = 0; nt < 8; nt++) {
            int ntile = w * 8 + nt;
            v8s b = *(const v8s*)(Bb + ((size_t)(ntile * KS + ks) * 64 + l) * 8);
            acc[0][nt] = __builtin_amdgcn_mfma_f32_16x16x32_bf16(a[0], b, acc[0][nt], 0, 0, 0);
            acc[1][nt] = __builtin_amdgcn_mfma_f32_16x16x32_bf16(a[1], b, acc[1][nt], 0, 0, 0);
        }
    }
    float p[2][4];
    #pragma unroll
    for (int mi = 0; mi < 2; mi++)
        #pragma unroll
        for (int j = 0; j < 4; j++) p[mi][j] = 0.f;
    #pragma unroll
    for (int nt = 0; nt < 8; nt++) {
        int col = w * 128 + nt * 16 + lr;
        float b1v = fcb1[col], w2v = fcW2[col];
        #pragma unroll
        for (int mi = 0; mi < 2; mi++) {
            #pragma unroll
            for (int j = 0; j < 4; j++) {
                float v = acc[mi][nt][j] + b1v;
                p[mi][j] += ((v > 0.f) ? v : 0.f) * w2v;
            }
        }
    }
    #pragma unroll
    for (int mi = 0; mi < 2; mi++)
        #pragma unroll
        for (int j = 0; j < 4; j++) {
            float v = p[mi][j];
            v += __shfl_xor(v, 1);
            v += __shfl_xor(v, 2);
            v += __shfl_xor(v, 4);
            v += __shfl_xor(v, 8);
            p[mi][j] = v;
        }
    if (lr == 0) {
        #pragma unroll
        for (int mi = 0; mi < 2; mi++)
            #pragma unroll
            for (int j = 0; j < 4; j++) red[w][mi * 16 + lk * 4 + j] = p[mi][j];
    }
    __syncthreads();
    int tid = threadIdx.x;
    if (tid < 32) {
        int gm = bm + tid;
        if (gm < NN)
            out[gm] = red[0][tid] + red[1][tid] + red[2][tid] + red[3][tid] + fcb2[0];
    }
}

// ---------------- layer 1 attention logits (bf16 input) ----------------

__global__ void att1_kernel(const __hip_bfloat16* __restrict__ h1bf,
                            const float* __restrict__ att_src,
                            const float* __restrict__ att_dst, float* __restrict__ a_s,
                            float* __restrict__ a_d) {
    int idx = blockIdx.x * blockDim.x + threadIdx.x;
    if (idx >= NN * H1) return;
    int n = idx >> 3, h = idx & 7;
    const v4u* row = (const v4u*)((const unsigned short*)h1bf + (size_t)n * HID1 + h * D1);
    float s = 0.f, d = 0.f;
    #pragma unroll
    for (int q = 0; q < 4; q++) {
        v4u v = row[q];
        #pragma unroll
        for (int k = 0; k < 4; k++) {
            float lo = __uint_as_float(v[k] << 16);
            float hi = __uint_as_float(v[k] & 0xffff0000u);
            int kk = q * 8 + k * 2;
            s += lo * att_src[h * D1 + kk] + hi * att_src[h * D1 + kk + 1];
            d += lo * att_dst[h * D1 + kk] + hi * att_dst[h * D1 + kk + 1];
        }
    }
    a_s[idx] = s;
    a_d[idx] = d;
}

// ---------------- fused edge-logit + segment-softmax, layer 1 ----------------

__global__ void fsoftmax1_kernel(const int* __restrict__ row_ptr, const int* __restrict__ eidx,
                                 const int* __restrict__ srcs,
                                 const float* __restrict__ a_s, const float* __restrict__ a_d,
                                 float* __restrict__ alpha_csr, float* __restrict__ alpha1_out) {
    int n = blockIdx.x * 4 + (threadIdx.x >> 6);
    int lane = threadIdx.x & 63;
    if (n >= NN) return;
    int start = row_ptr[n], end = row_ptr[n + 1];
    int cnt = end - start;
    if (cnt == 0) return;
    if (cnt <= 64) {
        int p = start + lane;
        bool act = lane < cnt;
        int sj = act ? srcs[p] : 0;
        v4f as0 = *(const v4f*)(a_s + (size_t)sj * 8);
        v4f as1 = *(const v4f*)(a_s + (size_t)sj * 8 + 4);
        v4f ad0 = *(const v4f*)(a_d + (size_t)n * 8);
        v4f ad1 = *(const v4f*)(a_d + (size_t)n * 8 + 4);
        float ev[8];
        #pragma unroll
        for (int h = 0; h < 4; h++) {
            float v = as0[h] + ad0[h];
            v = (v >= 0.f) ? v : NEG_SLOPE * v;
            ev[h] = act ? v : -INFINITY;
            float v2 = as1[h] + ad1[h];
            v2 = (v2 >= 0.f) ? v2 : NEG_SLOPE * v2;
            ev[h + 4] = act ? v2 : -INFINITY;
        }
        float mv[8];
        #pragma unroll
        for (int h = 0; h < 8; h++) mv[h] = ev[h];
        #pragma unroll
        for (int off = 1; off < 64; off <<= 1) {
            #pragma unroll
            for (int h = 0; h < 8; h++) mv[h] = fmaxf(mv[h], __shfl_xor(mv[h], off));
        }
        float ex[8], sv[8];
        #pragma unroll
        for (int h = 0; h < 8; h++) {
            ex[h] = expf(ev[h] - mv[h]);
            sv[h] = ex[h];
        }
        #pragma unroll
        for (int off = 1; off < 64; off <<= 1) {
            #pragma unroll
            for (int h = 0; h < 8; h++) sv[h] += __shfl_xor(sv[h], off);
        }
        if (act) {
            v4f o0, o1;
            #pragma unroll
            for (int h = 0; h < 4; h++) {
                o0[h] = ex[h] / (sv[h] + 1e-16f);
                o1[h] = ex[h + 4] / (sv[h + 4] + 1e-16f);
            }
            *(v4f*)(alpha_csr + (size_t)p * 8) = o0;
            *(v4f*)(alpha_csr + (size_t)p * 8 + 4) = o1;
            int eo = eidx[p];
            *(v4f*)(alpha1_out + (size_t)eo * 8) = o0;
            *(v4f*)(alpha1_out + (size_t)eo * 8 + 4) = o1;
        }
    } else {
        int h = lane & 7, j = lane >> 3;
        float ad = a_d[n * 8 + h];
        float m = -INFINITY;
        for (int p = start + j; p < end; p += 8) {
            float v = a_s[srcs[p] * 8 + h] + ad;
            v = (v >= 0.f) ? v : NEG_SLOPE * v;
            m = fmaxf(m, v);
        }
        m = fmaxf(m, __shfl_xor(m, 8));
        m = fmaxf(m, __shfl_xor(m, 16));
        m = fmaxf(m, __shfl_xor(m, 32));
        float s = 0.f;
        for (int p = start + j; p < end; p += 8) {
            float v = a_s[srcs[p] * 8 + h] + ad;
            v = (v >= 0.f) ? v : NEG_SLOPE * v;
            s += expf(v - m);
        }
        s += __shfl_xor(s, 8);
        s += __shfl_xor(s, 16);
        s += __shfl_xor(s, 32);
        float inv = 1.f / (s + 1e-16f);
        for (int p = start + j; p < end; p += 8) {
            float v = a_s[srcs[p] * 8 + h] + ad;
            v = (v >= 0.f) ? v : NEG_SLOPE * v;
            float a = expf(v - m) * inv;
            alpha_csr[(size_t)p * 8 + h] = a;
            alpha1_out[(size_t)eidx[p] * 8 + h] = a;
        }
    }
}

// ---------------- layer 1 aggregation v3: wave-per-node, 8-deep batched gathers ----------------
// lane l owns dims 4l..4l+3; 64-edge chunk in regs; 8 groups x 8 edges, loads batched.

__global__ __launch_bounds__(256) void agg1_kernel(const int* __restrict__ row_ptr,
                                                   const int* __restrict__ srcs,
                                                   const float* __restrict__ alpha_csr,
                                                   const __hip_bfloat16* __restrict__ h1bf,
                                                   const float* __restrict__ b1,
                                                   __hip_bfloat16* __restrict__ x1bf) {
    int w = threadIdx.x >> 6, l = threadIdx.x & 63;
    int n = blockIdx.x * 4 + w;
    if (n >= NN) return;
    int h = l >> 3;
    int start = row_ptr[n], end = row_ptr[n + 1];
    float acc0 = 0.f, acc1 = 0.f, acc2 = 0.f, acc3 = 0.f;
    const unsigned short* hb = (const unsigned short*)h1bf;
    for (int c0 = start; c0 < end; c0 += 64) {
        int cnt = min(64, end - c0);
        int s_reg = (l < cnt) ? srcs[c0 + l] : 0;
        const float* ab = alpha_csr + (size_t)c0 * 8;
        int tot = cnt * 8;
        float aarr[8];
        #pragma unroll
        for (int K = 0; K < 8; K++)
            aarr[K] = (K * 64 + l < tot) ? ab[K * 64 + l] : 0.f;
        int rounds = (cnt + 7) >> 3;
        #pragma unroll
        for (int K = 0; K < 8; K++) {
            if (K < rounds) {
                int sj[8];
                float Aj[8];
                ushort4 qj[8];
                #pragma unroll
                for (int t = 0; t < 8; t++) {
                    sj[t] = __shfl(s_reg, K * 8 + t);
                    Aj[t] = __shfl(aarr[K], (t << 3) + h);
                }
                #pragma unroll
                for (int t = 0; t < 8; t++)
                    qj[t] = *(const ushort4*)(hb + (size_t)sj[t] * HID1 + l * 4);
                #pragma unroll
                for (int t = 0; t < 8; t++) {
                    acc0 += Aj[t] * bf2f(qj[t].x);
                    acc1 += Aj[t] * bf2f(qj[t].y);
                    acc2 += Aj[t] * bf2f(qj[t].z);
                    acc3 += Aj[t] * bf2f(qj[t].w);
                }
            }
        }
    }
    float4 bb = *(const float4*)(b1 + l * 4);
    float r0 = acc0 + bb.x, r1 = acc1 + bb.y, r2 = acc2 + bb.z, r3 = acc3 + bb.w;
    r0 = (r0 > 0.f) ? r0 : expf(r0) - 1.f;
    r1 = (r1 > 0.f) ? r1 : expf(r1) - 1.f;
    r2 = (r2 > 0.f) ? r2 : expf(r2) - 1.f;
    r3 = (r3 > 0.f) ? r3 : expf(r3) - 1.f;
    ushort4 o;
    o.x = f2bf(r0); o.y = f2bf(r1); o.z = f2bf(r2); o.w = f2bf(r3);
    *(ushort4*)((unsigned short*)x1bf + (size_t)n * HID1 + l * 4) = o;
}

// ---------------- layer 2 attention logits (1 head, bf16 input) ----------------

__global__ __launch_bounds__(64) void att2_kernel(const __hip_bfloat16* __restrict__ h2bf,
                                                  const float* __restrict__ att_src,
                                                  const float* __restrict__ att_dst,
                                                  float* __restrict__ a_s, float* __restrict__ a_d) {
    int n = blockIdx.x;
    int lane = threadIdx.x;
    const unsigned short* row = (const unsigned short*)h2bf + (size_t)n * HID2;
    unsigned int v = *(const unsigned int*)(row + lane * 2);
    float lo = __uint_as_float(v << 16);
    float hi = __uint_as_float(v & 0xffff0000u);
    float s = lo * att_src[lane * 2] + hi * att_src[lane * 2 + 1];
    float d = lo * att_dst[lane * 2] + hi * att_dst[lane * 2 + 1];
    for (int off = 32; off; off >>= 1) {
        s += __shfl_down(s, off);
        d += __shfl_down(d, off);
    }
    if (lane == 0) {
        a_s[n] = s;
        a_d[n] = d;
    }
}

// ---------------- fused edge-logit + segment-softmax, layer 2 ----------------

__global__ void fsoftmax2_kernel(const int* __restrict__ row_ptr, const int* __restrict__ eidx,
                                 const int* __restrict__ srcs,
                                 const float* __restrict__ a_s, const float* __restrict__ a_d,
                                 float* __restrict__ alpha_csr, float* __restrict__ alpha2_out) {
    int n = blockIdx.x * 4 + (threadIdx.x >> 6);
    int lane = threadIdx.x & 63;
    if (n >= NN) return;
    int start = row_ptr[n], end = row_ptr[n + 1];
    int cnt = end - start;
    if (cnt == 0) return;
    float ad = a_d[n];
    if (cnt <= 64) {
        int p = start + lane;
        bool act = lane < cnt;
        int sj = act ? srcs[p] : 0;
        float v = a_s[sj] + ad;
        v = (v >= 0.f) ? v : NEG_SLOPE * v;
        float e = act ? v : -INFINITY;
        float m = e;
        #pragma unroll
        for (int off = 1; off < 64; off <<= 1) m = fmaxf(m, __shfl_xor(m, off));
        float ex = expf(e - m);
        float s = ex;
        #pragma unroll
        for (int off = 1; off < 64; off <<= 1) s += __shfl_xor(s, off);
        if (act) {
            float a = ex / (s + 1e-16f);
            alpha_csr[p] = a;
            alpha2_out[eidx[p]] = a;
        }
    } else {
        float m = -INFINITY;
        for (int p = start + lane; p < end; p += 64) {
            float v = a_s[srcs[p]] + ad;
            v = (v >= 0.f) ? v : NEG_SLOPE * v;
            m = fmaxf(m, v);
        }
        for (int off = 32; off; off >>= 1) m = fmaxf(m, __shfl_xor(m, off));
        float s = 0.f;
        for (int p = start + lane; p < end; p += 64) {
            float v = a_s[srcs[p]] + ad;
            v = (v >= 0.f) ? v : NEG_SLOPE * v;
            s += expf(v - m);
        }
        for (int off = 32; off; off >>= 1) s += __shfl_xor(s, off);
        float inv = 1.f / (s + 1e-16f);
        for (int p = start + lane; p < end; p += 64) {
            float v = a_s[srcs[p]] + ad;
            v = (v >= 0.f) ? v : NEG_SLOPE * v;
            float a = expf(v - m) * inv;
            alpha_csr[p] = a;
            alpha2_out[eidx[p]] = a;
        }
    }
}

// ---------------- layer 2 aggregation v3: wave-per-node, batched gathers ----------------
// r = l>>5 edge subslot, c = l&31 owns dims 4c..4c+3; 8 edges per group (4 per subslot).

__global__ __launch_bounds__(256) void agg2_kernel(const int* __restrict__ row_ptr,
                                                   const int* __restrict__ srcs,
                                                   const float* __restrict__ alpha_csr,
                                                   const __hip_bfloat16* __restrict__ h2bf,
                                                   const float* __restrict__ b2,
                                                   __hip_bfloat16* __restrict__ x2bf) {
    int w = threadIdx.x >> 6, l = threadIdx.x & 63;
    int n = blockIdx.x * 4 + w;
    if (n >= NN) return;
    int r = l >> 5, c = l & 31;
    int start = row_ptr[n], end = row_ptr[n + 1];
    float acc0 = 0.f, acc1 = 0.f, acc2 = 0.f, acc3 = 0.f;
    const unsigned short* hb = (const unsigned short*)h2bf;
    for (int c0 = start; c0 < end; c0 += 64) {
        int cnt = min(64, end - c0);
        int s_reg = (l < cnt) ? srcs[c0 + l] : 0;
        float a_reg = (l < cnt) ? alpha_csr[c0 + l] : 0.f;
        int rounds = (cnt + 7) >> 3;
        #pragma unroll
        for (int K = 0; K < 8; K++) {
            if (K < rounds) {
                int sj[4];
                float Aj[4];
                ushort4 qj[4];
                #pragma unroll
                for (int t = 0; t < 4; t++) {
                    int j = K * 8 + t * 2 + r;
                    sj[t] = __shfl(s_reg, j);
                    Aj[t] = __shfl(a_reg, j);
                }
                #pragma unroll
                for (int t = 0; t < 4; t++)
                    qj[t] = *(const ushort4*)(hb + (size_t)sj[t] * HID2 + c * 4);
                #pragma unroll
                for (int t = 0; t < 4; t++) {
                    acc0 += Aj[t] * bf2f(qj[t].x);
                    acc1 += Aj[t] * bf2f(qj[t].y);
                    acc2 += Aj[t] * bf2f(qj[t].z);
                    acc3 += Aj[t] * bf2f(qj[t].w);
                }
            }
        }
    }
    acc0 += __shfl_xor(acc0, 32);
    acc1 += __shfl_xor(acc1, 32);
    acc2 += __shfl_xor(acc2, 32);
    acc3 += __shfl_xor(acc3, 32);
    if (r == 0) {
        float4 bb = *(const float4*)(b2 + c * 4);
        float r0 = acc0 + bb.x, r1 = acc1 + bb.y, r2 = acc2 + bb.z, r3 = acc3 + bb.w;
        r0 = (r0 > 0.f) ? r0 : 0.f;
        r1 = (r1 > 0.f) ? r1 : 0.f;
        r2 = (r2 > 0.f) ? r2 : 0.f;
        r3 = (r3 > 0.f) ? r3 : 0.f;
        ushort4 o;
        o.x = f2bf(r0); o.y = f2bf(r1); o.z = f2bf(r2); o.w = f2bf(r3);
        *(ushort4*)((unsigned short*)x2bf + (size_t)n * HID2 + c * 4) = o;
    }
}

// ---------------- host launch ----------------

extern "C" void kernel_launch(void* const* d_in, const int* in_sizes, int n_in,
                              void* d_out, int out_size, void* d_ws, size_t ws_size,
                              hipStream_t stream) {
    (void)in_sizes; (void)n_in; (void)out_size; (void)ws_size;
    const float* x        = (const float*)d_in[0];
    const int*   eindex   = (const int*)d_in[1];
    const float* W1       = (const float*)d_in[2];
    const float* att_src1 = (const float*)d_in[3];
    const float* att_dst1 = (const float*)d_in[4];
    const float* b1       = (const float*)d_in[5];
    const float* W2       = (const float*)d_in[6];
    const float* att_src2 = (const float*)d_in[7];
    const float* att_dst2 = (const float*)d_in[8];
    const float* b2       = (const float*)d_in[9];
    const float* fcW1     = (const float*)d_in[10];
    const float* fcb1     = (const float*)d_in[11];
    const float* fcW2     = (const float*)d_in[12];
    const float* fcb2     = (const float*)d_in[13];

    const int* src = eindex;
    const int* dst = eindex + EE;

    float* out_n      = (float*)d_out;               // [N]
    float* alpha1_out = out_n + NN;                  // [E,8]
    float* alpha2_out = alpha1_out + (size_t)EE * 8; // [E]

    char* ws = (char*)d_ws;
    size_t off = 0;
    auto alloc = [&](size_t bytes) {
        size_t o = off;
        off = (off + bytes + 255) & ~(size_t)255;
        return o;
    };
    size_t o_rowptr = alloc((NN + 1) * sizeof(int));
    size_t o_cursor = alloc(NN * sizeof(int));
    size_t o_counts = alloc(NN * sizeof(int));
    size_t o_excl   = alloc(NN * sizeof(int));
    size_t o_bsum   = alloc(64 * sizeof(int));
    size_t o_eidx   = alloc(EE * sizeof(int));
    size_t o_srcs   = alloc(EE * sizeof(int));
    size_t o_e1s    = alloc((size_t)EE * H1 * sizeof(float));
    size_t o_as1    = alloc((size_t)NN * H1 * sizeof(float));
    size_t o_ad1    = alloc((size_t)NN * H1 * sizeof(float));
    size_t o_h1bf   = alloc((size_t)NN * HID1 * sizeof(__hip_bfloat16));
    size_t o_xbf    = alloc((size_t)NN * IN_DIM * sizeof(__hip_bfloat16));
    size_t o_x1bf   = alloc((size_t)NN * HID1 * sizeof(__hip_bfloat16));
    size_t o_h2bf   = alloc((size_t)NN * HID2 * sizeof(__hip_bfloat16));
    size_t o_x2bf   = alloc((size_t)NN * HID2 * sizeof(__hip_bfloat16));
    size_t o_W1p    = alloc((size_t)IN_DIM * HID1 * sizeof(__hip_bfloat16));
    size_t o_W2p    = alloc((size_t)HID1 * HID2 * sizeof(__hip_bfloat16));
    size_t o_fW1p   = alloc((size_t)HID2 * FC1 * sizeof(__hip_bfloat16));

    int*   row_ptr = (int*)(ws + o_rowptr);
    int*   cursor  = (int*)(ws + o_cursor);
    int*   counts  = (int*)(ws + o_counts);
    int*   excl    = (int*)(ws + o_excl);
    int*   bsum    = (int*)(ws + o_bsum);
    int*   eidx    = (int*)(ws + o_eidx);
    int*   srcs    = (int*)(ws + o_srcs);
    float* e1s     = (float*)(ws + o_e1s);
    float* a_s1    = (float*)(ws + o_as1);
    float* a_d1    = (float*)(ws + o_ad1);
    __hip_bfloat16* h1bf  = (__hip_bfloat16*)(ws + o_h1bf);
    __hip_bfloat16* xbf   = (__hip_bfloat16*)(ws + o_xbf);
    __hip_bfloat16* x1bf  = (__hip_bfloat16*)(ws + o_x1bf);
    __hip_bfloat16* h2bf  = (__hip_bfloat16*)(ws + o_h2bf);
    __hip_bfloat16* x2bf  = (__hip_bfloat16*)(ws + o_x2bf);
    __hip_bfloat16* W1p   = (__hip_bfloat16*)(ws + o_W1p);
    __hip_bfloat16* W2p   = (__hip_bfloat16*)(ws + o_W2p);
    __hip_bfloat16* fW1p  = (__hip_bfloat16*)(ws + o_fW1p);
    // layer-2 aliases
    float* e2s  = e1s;
    float* a_s2 = a_s1;
    float* a_d2 = a_d1;

    const int SCAN_NB = (NN + 1023) / 1024;  // 49

    // ---- build CSR by dst ----
    fill_zero_int<<<(NN + 255) / 256, 256, 0, stream>>>(counts, NN);
    hist_kernel<<<(EE + 255) / 256, 256, 0, stream>>>(dst, counts);
    scan_a_kernel<<<SCAN_NB, 256, 0, stream>>>(counts, excl, bsum, NN);
    scan_b_kernel<<<1, 64, 0, stream>>>(bsum, row_ptr, SCAN_NB, NN);
    scan_c_kernel<<<SCAN_NB, 256, 0, stream>>>(excl, bsum, row_ptr, cursor, NN);
    scatter_kernel<<<(EE + 255) / 256, 256, 0, stream>>>(src, dst, cursor, eidx, srcs);

    // ---- input conversions / weight packing ----
    cvt_bf16_kernel<<<(NN * IN_DIM + 255) / 256, 256, 0, stream>>>(x, xbf, NN * IN_DIM);
    pack_kernel<<<(IN_DIM * HID1 + 255) / 256, 256, 0, stream>>>(W1, W1p, IN_DIM, HID1);
    pack_kernel<<<(HID1 * HID2 + 255) / 256, 256, 0, stream>>>(W2, W2p, HID1, HID2);
    pack_kernel<<<(HID2 * FC1 + 255) / 256, 256, 0, stream>>>(fcW1, fW1p, HID2, FC1);

    // ---- layer 1 ----
    mgemm_kernel<<<dim3((NN + 127) / 128, HID1 / 64), 256, 0, stream>>>(
        xbf, W1p, h1bf, NN, IN_DIM, HID1);
    att1_kernel<<<(NN * H1 + 255) / 256, 256, 0, stream>>>(h1bf, att_src1, att_dst1, a_s1, a_d1);
    fsoftmax1_kernel<<<(NN + 3) / 4, 256, 0, stream>>>(row_ptr, eidx, srcs, a_s1, a_d1,
                                                       e1s, alpha1_out);
    agg1_kernel<<<(NN + 3) / 4, 256, 0, stream>>>(row_ptr, srcs, e1s, h1bf, b1, x1bf);

    // ---- layer 2 ----
    mgemm_kernel<<<dim3((NN + 127) / 128, HID2 / 64), 256, 0, stream>>>(
        x1bf, W2p, h2bf, NN, HID1, HID2);
    att2_kernel<<<NN, 64, 0, stream>>>(h2bf, att_src2, att_dst2, a_s2, a_d2);
    fsoftmax2_kernel<<<(NN + 3) / 4, 256, 0, stream>>>(row_ptr, eidx, srcs, a_s2, a_d2,
                                                       e2s, alpha2_out);
    agg2_kernel<<<(NN + 3) / 4, 256, 0, stream>>>(row_ptr, srcs, e2s, h2bf, b2, x2bf);

    // ---- FC head ----
    fc_mfma_kernel<<<(NN + 31) / 32, 256, 0, stream>>>(x2bf, fW1p, fcb1, fcW2, fcb2, out_n);
}

// Round 8
// 326.696 us; speedup vs baseline: 1.3541x; 1.1265x over previous
//
#include <hip/hip_runtime.h>
#include <hip/hip_bf16.h>
#include <math.h>

#define NN 50000
#define EE 800000
#define IN_DIM 128
#define H1 8
#define D1 32
#define HID1 256
#define HID2 128
#define FC1 512
#define NEG_SLOPE 0.2f

typedef short v8s __attribute__((ext_vector_type(8)));
typedef float v4f __attribute__((ext_vector_type(4)));
typedef unsigned int v4u __attribute__((ext_vector_type(4)));

__device__ __forceinline__ float bf2f(unsigned short u) {
    unsigned int x = ((unsigned int)u) << 16;
    return __uint_as_float(x);
}
__device__ __forceinline__ unsigned short f2bf(float v) {
    __hip_bfloat16 h = __float2bfloat16(v);
    return *(unsigned short*)&h;
}

// ---------------- utility kernels ----------------

__global__ void fill_zero_int(int* p, int n) {
    int i = blockIdx.x * blockDim.x + threadIdx.x;
    if (i < n) p[i] = 0;
}

__global__ void hist_kernel(const int* __restrict__ dst, int* __restrict__ counts) {
    int e = blockIdx.x * blockDim.x + threadIdx.x;
    if (e < EE) atomicAdd(&counts[dst[e]], 1);
}

// ---- hierarchical exclusive scan ----

__global__ __launch_bounds__(256) void scan_a_kernel(const int* __restrict__ counts,
                                                     int* __restrict__ excl,
                                                     int* __restrict__ bsum, int n) {
    __shared__ int wsum[4];
    int tid = threadIdx.x;
    int base = blockIdx.x * 1024 + tid * 4;
    int v0 = 0, v1 = 0, v2 = 0, v3 = 0;
    if (base + 3 < n) {
        int4 t = *(const int4*)(counts + base);
        v0 = t.x; v1 = t.y; v2 = t.z; v3 = t.w;
    } else {
        if (base + 0 < n) v0 = counts[base + 0];
        if (base + 1 < n) v1 = counts[base + 1];
        if (base + 2 < n) v2 = counts[base + 2];
        if (base + 3 < n) v3 = counts[base + 3];
    }
    int tot = v0 + v1 + v2 + v3;
    int lane = tid & 63;
    int w = tid >> 6;
    int x = tot;
    #pragma unroll
    for (int off = 1; off < 64; off <<= 1) {
        int y = __shfl_up(x, off);
        if (lane >= off) x += y;
    }
    if (lane == 63) wsum[w] = x;
    __syncthreads();
    int woff = 0;
    for (int i = 0; i < w; i++) woff += wsum[i];
    int et = woff + x - tot;
    if (base + 0 < n) excl[base + 0] = et;
    if (base + 1 < n) excl[base + 1] = et + v0;
    if (base + 2 < n) excl[base + 2] = et + v0 + v1;
    if (base + 3 < n) excl[base + 3] = et + v0 + v1 + v2;
    if (tid == 255) bsum[blockIdx.x] = woff + x;
}

__global__ __launch_bounds__(64) void scan_b_kernel(int* __restrict__ bsum,
                                                    int* __restrict__ row_ptr, int nb, int n) {
    int lane = threadIdx.x;
    int v = (lane < nb) ? bsum[lane] : 0;
    int x = v;
    #pragma unroll
    for (int off = 1; off < 64; off <<= 1) {
        int y = __shfl_up(x, off);
        if (lane >= off) x += y;
    }
    if (lane < nb) bsum[lane] = x - v;
    if (lane == 63) row_ptr[n] = x;
}

__global__ __launch_bounds__(256) void scan_c_kernel(const int* __restrict__ excl,
                                                     const int* __restrict__ bsum,
                                                     int* __restrict__ row_ptr,
                                                     int* __restrict__ cursor, int n) {
    int base = blockIdx.x * 1024 + threadIdx.x * 4;
    int off = bsum[blockIdx.x];
    #pragma unroll
    for (int j = 0; j < 4; j++) {
        int i = base + j;
        if (i < n) {
            int r = excl[i] + off;
            row_ptr[i] = r;
            cursor[i] = r;
        }
    }
}

__global__ void scatter_kernel(const int* __restrict__ src, const int* __restrict__ dst,
                               int* __restrict__ cursor, int* __restrict__ eidx,
                               int* __restrict__ srcs) {
    int e = blockIdx.x * blockDim.x + threadIdx.x;
    if (e >= EE) return;
    int d = dst[e];
    int p = atomicAdd(&cursor[d], 1);
    eidx[p] = e;
    srcs[p] = src[e];
}

__global__ void cvt_bf16_kernel(const float* __restrict__ in, __hip_bfloat16* __restrict__ out, int n) {
    int i = blockIdx.x * blockDim.x + threadIdx.x;
    if (i < n) out[i] = __float2bfloat16(in[i]);
}

// pack fp32 weight B[K][N] into MFMA fragment-major bf16
__global__ void pack_kernel(const float* __restrict__ B, __hip_bfloat16* __restrict__ Bp,
                            int K, int N) {
    int idx = blockIdx.x * blockDim.x + threadIdx.x;
    if (idx >= K * N) return;
    int k = idx / N, n = idx % N;
    int ntile = n >> 4, ks = k >> 5, kk = k & 31;
    int lane = (n & 15) | ((kk >> 3) << 4);
    int j = kk & 7;
    int KS = K >> 5;
    Bp[((size_t)(ntile * KS + ks) * 64 + lane) * 8 + j] = __float2bfloat16(B[idx]);
}

// ---------------- MFMA GEMM (bf16 in, bf16 out) ----------------

__global__ __launch_bounds__(256) void mgemm_kernel(const __hip_bfloat16* __restrict__ A,
                                                    const __hip_bfloat16* __restrict__ Bp,
                                                    __hip_bfloat16* __restrict__ Cbf,
                                                    int M, int K, int N) {
    int w = threadIdx.x >> 6, l = threadIdx.x & 63;
    int bm = blockIdx.x * 128 + w * 32;
    int bn = blockIdx.y * 64;
    int lr = l & 15, lk = l >> 4;
    int KS = K >> 5;
    const short* Ab = (const short*)A;
    const short* Bb = (const short*)Bp;
    v4f acc[2][4];
    #pragma unroll
    for (int mi = 0; mi < 2; mi++)
        #pragma unroll
        for (int nt = 0; nt < 4; nt++) acc[mi][nt] = (v4f)(0.f);
    for (int ks = 0; ks < KS; ks++) {
        v8s a[2];
        #pragma unroll
        for (int mi = 0; mi < 2; mi++) {
            int gm = bm + mi * 16 + lr;
            a[mi] = (gm < M) ? *(const v8s*)(Ab + (size_t)gm * K + ks * 32 + lk * 8)
                             : (v8s)(short)0;
        }
        #pragma unroll
        for (int nt = 0; nt < 4; nt++) {
            int ntile = (bn >> 4) + nt;
            v8s b = *(const v8s*)(Bb + ((size_t)(ntile * KS + ks) * 64 + l) * 8);
            acc[0][nt] = __builtin_amdgcn_mfma_f32_16x16x32_bf16(a[0], b, acc[0][nt], 0, 0, 0);
            acc[1][nt] = __builtin_amdgcn_mfma_f32_16x16x32_bf16(a[1], b, acc[1][nt], 0, 0, 0);
        }
    }
    #pragma unroll
    for (int mi = 0; mi < 2; mi++) {
        #pragma unroll
        for (int nt = 0; nt < 4; nt++) {
            int gn = bn + nt * 16 + lr;
            #pragma unroll
            for (int j = 0; j < 4; j++) {
                int gm = bm + mi * 16 + lk * 4 + j;
                if (gm < M)
                    Cbf[(size_t)gm * N + gn] = __float2bfloat16(acc[mi][nt][j]);
            }
        }
    }
}

// ---------------- fused FC head via MFMA ----------------

__global__ __launch_bounds__(256) void fc_mfma_kernel(const __hip_bfloat16* __restrict__ A,
                                                      const __hip_bfloat16* __restrict__ Bp,
                                                      const float* __restrict__ fcb1,
                                                      const float* __restrict__ fcW2,
                                                      const float* __restrict__ fcb2,
                                                      float* __restrict__ out) {
    __shared__ float red[4][32];
    int w = threadIdx.x >> 6, l = threadIdx.x & 63;
    int bm = blockIdx.x * 32;
    int lr = l & 15, lk = l >> 4;
    const int K = HID2, KS = K >> 5;
    const short* Ab = (const short*)A;
    const short* Bb = (const short*)Bp;
    v4f acc[2][8];
    #pragma unroll
    for (int mi = 0; mi < 2; mi++)
        #pragma unroll
        for (int nt = 0; nt < 8; nt++) acc[mi][nt] = (v4f)(0.f);
    for (int ks = 0; ks < KS; ks++) {
        v8s a[2];
        #pragma unroll
        for (int mi = 0; mi < 2; mi++) {
            int gm = bm + mi * 16 + lr;
            a[mi] = (gm < NN) ? *(const v8s*)(Ab + (size_t)gm * K + ks * 32 + lk * 8)
                              : (v8s)(short)0;
        }
        #pragma unroll
        for (int nt = 0; nt < 8; nt++) {
            int ntile = w * 8 + nt;
            v8s b = *(const v8s*)(Bb + ((size_t)(ntile * KS + ks) * 64 + l) * 8);
            acc[0][nt] = __builtin_amdgcn_mfma_f32_16x16x32_bf16(a[0], b, acc[0][nt], 0, 0, 0);
            acc[1][nt] = __builtin_amdgcn_mfma_f32_16x16x32_bf16(a[1], b, acc[1][nt], 0, 0, 0);
        }
    }
    float p[2][4];
    #pragma unroll
    for (int mi = 0; mi < 2; mi++)
        #pragma unroll
        for (int j = 0; j < 4; j++) p[mi][j] = 0.f;
    #pragma unroll
    for (int nt = 0; nt < 8; nt++) {
        int col = w * 128 + nt * 16 + lr;
        float b1v = fcb1[col], w2v = fcW2[col];
        #pragma unroll
        for (int mi = 0; mi < 2; mi++) {
            #pragma unroll
            for (int j = 0; j < 4; j++) {
                float v = acc[mi][nt][j] + b1v;
                p[mi][j] += ((v > 0.f) ? v : 0.f) * w2v;
            }
        }
    }
    #pragma unroll
    for (int mi = 0; mi < 2; mi++)
        #pragma unroll
        for (int j = 0; j < 4; j++) {
            float v = p[mi][j];
            v += __shfl_xor(v, 1);
            v += __shfl_xor(v, 2);
            v += __shfl_xor(v, 4);
            v += __shfl_xor(v, 8);
            p[mi][j] = v;
        }
    if (lr == 0) {
        #pragma unroll
        for (int mi = 0; mi < 2; mi++)
            #pragma unroll
            for (int j = 0; j < 4; j++) red[w][mi * 16 + lk * 4 + j] = p[mi][j];
    }
    __syncthreads();
    int tid = threadIdx.x;
    if (tid < 32) {
        int gm = bm + tid;
        if (gm < NN)
            out[gm] = red[0][tid] + red[1][tid] + red[2][tid] + red[3][tid] + fcb2[0];
    }
}

// ---------------- layer 1 attention logits (bf16 input) ----------------

__global__ void att1_kernel(const __hip_bfloat16* __restrict__ h1bf,
                            const float* __restrict__ att_src,
                            const float* __restrict__ att_dst, float* __restrict__ a_s,
                            float* __restrict__ a_d) {
    int idx = blockIdx.x * blockDim.x + threadIdx.x;
    if (idx >= NN * H1) return;
    int n = idx >> 3, h = idx & 7;
    const v4u* row = (const v4u*)((const unsigned short*)h1bf + (size_t)n * HID1 + h * D1);
    float s = 0.f, d = 0.f;
    #pragma unroll
    for (int q = 0; q < 4; q++) {
        v4u v = row[q];
        #pragma unroll
        for (int k = 0; k < 4; k++) {
            float lo = __uint_as_float(v[k] << 16);
            float hi = __uint_as_float(v[k] & 0xffff0000u);
            int kk = q * 8 + k * 2;
            s += lo * att_src[h * D1 + kk] + hi * att_src[h * D1 + kk + 1];
            d += lo * att_dst[h * D1 + kk] + hi * att_dst[h * D1 + kk + 1];
        }
    }
    a_s[idx] = s;
    a_d[idx] = d;
}

// ---------------- fused layer-1 softmax + aggregation (wave per node) ----------------
// softmax phase: lane=(j,h), j=lane>>3, h=lane&7; edge (j+8k) in register k.
// agg phase: lane owns dims 4*lane..4*lane+3 (head hl=lane>>3); alpha via __shfl.

__global__ __launch_bounds__(256) void gat1_kernel(const int* __restrict__ row_ptr,
                                                   const int* __restrict__ eidx,
                                                   const int* __restrict__ srcs,
                                                   const float* __restrict__ a_s,
                                                   const float* __restrict__ a_d,
                                                   const __hip_bfloat16* __restrict__ h1bf,
                                                   const float* __restrict__ b1,
                                                   float* __restrict__ alpha1_out,
                                                   __hip_bfloat16* __restrict__ x1bf) {
    int wv = threadIdx.x >> 6, lane = threadIdx.x & 63;
    int n = blockIdx.x * 4 + wv;
    if (n >= NN) return;
    int start = row_ptr[n], end = row_ptr[n + 1];
    int cnt = end - start;
    int h = lane & 7, j = lane >> 3;
    int hl = lane >> 3;  // head for agg dims
    const unsigned short* hb = (const unsigned short*)h1bf;
    float acc0 = 0.f, acc1 = 0.f, acc2 = 0.f, acc3 = 0.f;
    if (cnt > 0 && cnt <= 64) {
        float ad = a_d[(size_t)n * 8 + h];
        float ex[8];
        int sj[8];
        #pragma unroll
        for (int k = 0; k < 8; k++) {
            int idx = j + k * 8;
            int ii = min(idx, cnt - 1);
            sj[k] = srcs[start + ii];
            float v = a_s[(size_t)sj[k] * 8 + h] + ad;
            v = (v >= 0.f) ? v : NEG_SLOPE * v;
            ex[k] = (idx < cnt) ? v : -INFINITY;
        }
        float m = ex[0];
        #pragma unroll
        for (int k = 1; k < 8; k++) m = fmaxf(m, ex[k]);
        m = fmaxf(m, __shfl_xor(m, 8));
        m = fmaxf(m, __shfl_xor(m, 16));
        m = fmaxf(m, __shfl_xor(m, 32));
        float s = 0.f;
        #pragma unroll
        for (int k = 0; k < 8; k++) {
            ex[k] = expf(ex[k] - m);
            s += ex[k];
        }
        s += __shfl_xor(s, 8);
        s += __shfl_xor(s, 16);
        s += __shfl_xor(s, 32);
        float inv = 1.f / (s + 1e-16f);
        #pragma unroll
        for (int k = 0; k < 8; k++) ex[k] *= inv;  // ex[] now alpha (0 for padded)
        // alpha1_out scatter (8 h-lanes write 32B contiguous per edge)
        #pragma unroll
        for (int k = 0; k < 8; k++) {
            int idx = j + k * 8;
            if (idx < cnt)
                alpha1_out[(size_t)eidx[start + idx] * 8 + h] = ex[k];
        }
        // aggregation: rounds of 8 edges, batched gathers
        int rounds = (cnt + 7) >> 3;
        #pragma unroll
        for (int K = 0; K < 8; K++) {
            if (K < rounds) {
                int sjt[8];
                float At[8];
                ushort4 qt[8];
                #pragma unroll
                for (int t = 0; t < 8; t++) {
                    sjt[t] = __shfl(sj[K], t * 8);           // edge K*8+t src
                    At[t] = __shfl(ex[K], t * 8 + hl);       // its alpha for head hl
                }
                #pragma unroll
                for (int t = 0; t < 8; t++)
                    qt[t] = *(const ushort4*)(hb + (size_t)sjt[t] * HID1 + lane * 4);
                #pragma unroll
                for (int t = 0; t < 8; t++) {
                    acc0 += At[t] * bf2f(qt[t].x);
                    acc1 += At[t] * bf2f(qt[t].y);
                    acc2 += At[t] * bf2f(qt[t].z);
                    acc3 += At[t] * bf2f(qt[t].w);
                }
            }
        }
    } else if (cnt > 64) {
        // fallback (degree>64): 3-pass strided softmax, inline-recomputed agg
        float ad = a_d[(size_t)n * 8 + h];
        float m = -INFINITY;
        for (int p = start + j; p < end; p += 8) {
            float v = a_s[(size_t)srcs[p] * 8 + h] + ad;
            v = (v >= 0.f) ? v : NEG_SLOPE * v;
            m = fmaxf(m, v);
        }
        m = fmaxf(m, __shfl_xor(m, 8));
        m = fmaxf(m, __shfl_xor(m, 16));
        m = fmaxf(m, __shfl_xor(m, 32));
        float s = 0.f;
        for (int p = start + j; p < end; p += 8) {
            float v = a_s[(size_t)srcs[p] * 8 + h] + ad;
            v = (v >= 0.f) ? v : NEG_SLOPE * v;
            s += expf(v - m);
        }
        s += __shfl_xor(s, 8);
        s += __shfl_xor(s, 16);
        s += __shfl_xor(s, 32);
        float inv = 1.f / (s + 1e-16f);
        for (int p = start + j; p < end; p += 8) {
            float v = a_s[(size_t)srcs[p] * 8 + h] + ad;
            v = (v >= 0.f) ? v : NEG_SLOPE * v;
            alpha1_out[(size_t)eidx[p] * 8 + h] = expf(v - m) * inv;
        }
        // agg with inline alpha recompute for head hl (m,inv,ad broadcast from lane hl)
        float mh = __shfl(m, hl);
        float invh = __shfl(inv, hl);
        float adh = __shfl(ad, hl);
        for (int p = start; p < end; p++) {
            int sp = srcs[p];
            float v = a_s[(size_t)sp * 8 + hl] + adh;
            v = (v >= 0.f) ? v : NEG_SLOPE * v;
            float al = expf(v - mh) * invh;
            ushort4 q = *(const ushort4*)(hb + (size_t)sp * HID1 + lane * 4);
            acc0 += al * bf2f(q.x);
            acc1 += al * bf2f(q.y);
            acc2 += al * bf2f(q.z);
            acc3 += al * bf2f(q.w);
        }
    }
    float4 bb = *(const float4*)(b1 + lane * 4);
    float r0 = acc0 + bb.x, r1 = acc1 + bb.y, r2 = acc2 + bb.z, r3 = acc3 + bb.w;
    r0 = (r0 > 0.f) ? r0 : expf(r0) - 1.f;
    r1 = (r1 > 0.f) ? r1 : expf(r1) - 1.f;
    r2 = (r2 > 0.f) ? r2 : expf(r2) - 1.f;
    r3 = (r3 > 0.f) ? r3 : expf(r3) - 1.f;
    ushort4 o;
    o.x = f2bf(r0); o.y = f2bf(r1); o.z = f2bf(r2); o.w = f2bf(r3);
    *(ushort4*)((unsigned short*)x1bf + (size_t)n * HID1 + lane * 4) = o;
}

// ---------------- layer 2 attention logits (1 head, bf16 input) ----------------

__global__ __launch_bounds__(64) void att2_kernel(const __hip_bfloat16* __restrict__ h2bf,
                                                  const float* __restrict__ att_src,
                                                  const float* __restrict__ att_dst,
                                                  float* __restrict__ a_s, float* __restrict__ a_d) {
    int n = blockIdx.x;
    int lane = threadIdx.x;
    const unsigned short* row = (const unsigned short*)h2bf + (size_t)n * HID2;
    unsigned int v = *(const unsigned int*)(row + lane * 2);
    float lo = __uint_as_float(v << 16);
    float hi = __uint_as_float(v & 0xffff0000u);
    float s = lo * att_src[lane * 2] + hi * att_src[lane * 2 + 1];
    float d = lo * att_dst[lane * 2] + hi * att_dst[lane * 2 + 1];
    for (int off = 32; off; off >>= 1) {
        s += __shfl_down(s, off);
        d += __shfl_down(d, off);
    }
    if (lane == 0) {
        a_s[n] = s;
        a_d[n] = d;
    }
}

// ---------------- fused layer-2 softmax + aggregation (wave per node) ----------------
// softmax: lane-per-edge. agg: r=lane>>5 edge subslot, c=lane&31 owns dims 4c..4c+3.

__global__ __launch_bounds__(256) void gat2_kernel(const int* __restrict__ row_ptr,
                                                   const int* __restrict__ eidx,
                                                   const int* __restrict__ srcs,
                                                   const float* __restrict__ a_s,
                                                   const float* __restrict__ a_d,
                                                   const __hip_bfloat16* __restrict__ h2bf,
                                                   const float* __restrict__ b2,
                                                   float* __restrict__ alpha2_out,
                                                   __hip_bfloat16* __restrict__ x2bf) {
    int wv = threadIdx.x >> 6, lane = threadIdx.x & 63;
    int n = blockIdx.x * 4 + wv;
    if (n >= NN) return;
    int start = row_ptr[n], end = row_ptr[n + 1];
    int cnt = end - start;
    int r = lane >> 5, c = lane & 31;
    const unsigned short* hb = (const unsigned short*)h2bf;
    float acc0 = 0.f, acc1 = 0.f, acc2 = 0.f, acc3 = 0.f;
    if (cnt > 0 && cnt <= 64) {
        float ad = a_d[n];
        bool act = lane < cnt;
        int ii = min(lane, cnt - 1);
        int sj = srcs[start + ii];
        float v = a_s[sj] + ad;
        v = (v >= 0.f) ? v : NEG_SLOPE * v;
        float e = act ? v : -INFINITY;
        float m = e;
        #pragma unroll
        for (int off = 1; off < 64; off <<= 1) m = fmaxf(m, __shfl_xor(m, off));
        float ex = expf(e - m);
        float s = ex;
        #pragma unroll
        for (int off = 1; off < 64; off <<= 1) s += __shfl_xor(s, off);
        float al = ex / (s + 1e-16f);  // 0 for padded lanes
        if (act) alpha2_out[eidx[start + lane]] = al;
        int rounds = (cnt + 7) >> 3;
        #pragma unroll
        for (int K = 0; K < 8; K++) {
            if (K < rounds) {
                int sjt[4];
                float At[4];
                ushort4 qt[4];
                #pragma unroll
                for (int t = 0; t < 4; t++) {
                    int je = K * 8 + t * 2 + r;
                    sjt[t] = __shfl(sj, je);
                    At[t] = __shfl(al, je);
                }
                #pragma unroll
                for (int t = 0; t < 4; t++)
                    qt[t] = *(const ushort4*)(hb + (size_t)sjt[t] * HID2 + c * 4);
                #pragma unroll
                for (int t = 0; t < 4; t++) {
                    acc0 += At[t] * bf2f(qt[t].x);
                    acc1 += At[t] * bf2f(qt[t].y);
                    acc2 += At[t] * bf2f(qt[t].z);
                    acc3 += At[t] * bf2f(qt[t].w);
                }
            }
        }
    } else if (cnt > 64) {
        float ad = a_d[n];
        float m = -INFINITY;
        for (int p = start + lane; p < end; p += 64) {
            float v = a_s[srcs[p]] + ad;
            v = (v >= 0.f) ? v : NEG_SLOPE * v;
            m = fmaxf(m, v);
        }
        for (int off = 32; off; off >>= 1) m = fmaxf(m, __shfl_xor(m, off));
        float s = 0.f;
        for (int p = start + lane; p < end; p += 64) {
            float v = a_s[srcs[p]] + ad;
            v = (v >= 0.f) ? v : NEG_SLOPE * v;
            s += expf(v - m);
        }
        for (int off = 32; off; off >>= 1) s += __shfl_xor(s, off);
        float inv = 1.f / (s + 1e-16f);
        for (int p = start + lane; p < end; p += 64) {
            float v = a_s[srcs[p]] + ad;
            v = (v >= 0.f) ? v : NEG_SLOPE * v;
            alpha2_out[eidx[p]] = expf(v - m) * inv;
        }
        // agg: m,s wave-uniform; inline recompute; subslot r takes every other edge
        for (int p = start + r; p < end; p += 2) {
            int sp = srcs[p];
            float v = a_s[sp] + ad;
            v = (v >= 0.f) ? v : NEG_SLOPE * v;
            float al = expf(v - m) * inv;
            ushort4 q = *(const ushort4*)(hb + (size_t)sp * HID2 + c * 4);
            acc0 += al * bf2f(q.x);
            acc1 += al * bf2f(q.y);
            acc2 += al * bf2f(q.z);
            acc3 += al * bf2f(q.w);
        }
    }
    acc0 += __shfl_xor(acc0, 32);
    acc1 += __shfl_xor(acc1, 32);
    acc2 += __shfl_xor(acc2, 32);
    acc3 += __shfl_xor(acc3, 32);
    if (r == 0) {
        float4 bb = *(const float4*)(b2 + c * 4);
        float r0 = acc0 + bb.x, r1 = acc1 + bb.y, r2 = acc2 + bb.z, r3 = acc3 + bb.w;
        r0 = (r0 > 0.f) ? r0 : 0.f;
        r1 = (r1 > 0.f) ? r1 : 0.f;
        r2 = (r2 > 0.f) ? r2 : 0.f;
        r3 = (r3 > 0.f) ? r3 : 0.f;
        ushort4 o;
        o.x = f2bf(r0); o.y = f2bf(r1); o.z = f2bf(r2); o.w = f2bf(r3);
        *(ushort4*)((unsigned short*)x2bf + (size_t)n * HID2 + c * 4) = o;
    }
}

// ---------------- host launch ----------------

extern "C" void kernel_launch(void* const* d_in, const int* in_sizes, int n_in,
                              void* d_out, int out_size, void* d_ws, size_t ws_size,
                              hipStream_t stream) {
    (void)in_sizes; (void)n_in; (void)out_size; (void)ws_size;
    const float* x        = (const float*)d_in[0];
    const int*   eindex   = (const int*)d_in[1];
    const float* W1       = (const float*)d_in[2];
    const float* att_src1 = (const float*)d_in[3];
    const float* att_dst1 = (const float*)d_in[4];
    const float* b1       = (const float*)d_in[5];
    const float* W2       = (const float*)d_in[6];
    const float* att_src2 = (const float*)d_in[7];
    const float* att_dst2 = (const float*)d_in[8];
    const float* b2       = (const float*)d_in[9];
    const float* fcW1     = (const float*)d_in[10];
    const float* fcb1     = (const float*)d_in[11];
    const float* fcW2     = (const float*)d_in[12];
    const float* fcb2     = (const float*)d_in[13];

    const int* src = eindex;
    const int* dst = eindex + EE;

    float* out_n      = (float*)d_out;               // [N]
    float* alpha1_out = out_n + NN;                  // [E,8]
    float* alpha2_out = alpha1_out + (size_t)EE * 8; // [E]

    char* ws = (char*)d_ws;
    size_t off = 0;
    auto alloc = [&](size_t bytes) {
        size_t o = off;
        off = (off + bytes + 255) & ~(size_t)255;
        return o;
    };
    size_t o_rowptr = alloc((NN + 1) * sizeof(int));
    size_t o_cursor = alloc(NN * sizeof(int));
    size_t o_counts = alloc(NN * sizeof(int));
    size_t o_excl   = alloc(NN * sizeof(int));
    size_t o_bsum   = alloc(64 * sizeof(int));
    size_t o_eidx   = alloc(EE * sizeof(int));
    size_t o_srcs   = alloc(EE * sizeof(int));
    size_t o_as1    = alloc((size_t)NN * H1 * sizeof(float));
    size_t o_ad1    = alloc((size_t)NN * H1 * sizeof(float));
    size_t o_h1bf   = alloc((size_t)NN * HID1 * sizeof(__hip_bfloat16));
    size_t o_xbf    = alloc((size_t)NN * IN_DIM * sizeof(__hip_bfloat16));
    size_t o_x1bf   = alloc((size_t)NN * HID1 * sizeof(__hip_bfloat16));
    size_t o_h2bf   = alloc((size_t)NN * HID2 * sizeof(__hip_bfloat16));
    size_t o_x2bf   = alloc((size_t)NN * HID2 * sizeof(__hip_bfloat16));
    size_t o_W1p    = alloc((size_t)IN_DIM * HID1 * sizeof(__hip_bfloat16));
    size_t o_W2p    = alloc((size_t)HID1 * HID2 * sizeof(__hip_bfloat16));
    size_t o_fW1p   = alloc((size_t)HID2 * FC1 * sizeof(__hip_bfloat16));

    int*   row_ptr = (int*)(ws + o_rowptr);
    int*   cursor  = (int*)(ws + o_cursor);
    int*   counts  = (int*)(ws + o_counts);
    int*   excl    = (int*)(ws + o_excl);
    int*   bsum    = (int*)(ws + o_bsum);
    int*   eidx    = (int*)(ws + o_eidx);
    int*   srcs    = (int*)(ws + o_srcs);
    float* a_s1    = (float*)(ws + o_as1);
    float* a_d1    = (float*)(ws + o_ad1);
    __hip_bfloat16* h1bf  = (__hip_bfloat16*)(ws + o_h1bf);
    __hip_bfloat16* xbf   = (__hip_bfloat16*)(ws + o_xbf);
    __hip_bfloat16* x1bf  = (__hip_bfloat16*)(ws + o_x1bf);
    __hip_bfloat16* h2bf  = (__hip_bfloat16*)(ws + o_h2bf);
    __hip_bfloat16* x2bf  = (__hip_bfloat16*)(ws + o_x2bf);
    __hip_bfloat16* W1p   = (__hip_bfloat16*)(ws + o_W1p);
    __hip_bfloat16* W2p   = (__hip_bfloat16*)(ws + o_W2p);
    __hip_bfloat16* fW1p  = (__hip_bfloat16*)(ws + o_fW1p);
    // layer-2 aliases
    float* a_s2 = a_s1;
    float* a_d2 = a_d1;

    const int SCAN_NB = (NN + 1023) / 1024;  // 49

    // ---- build CSR by dst ----
    fill_zero_int<<<(NN + 255) / 256, 256, 0, stream>>>(counts, NN);
    hist_kernel<<<(EE + 255) / 256, 256, 0, stream>>>(dst, counts);
    scan_a_kernel<<<SCAN_NB, 256, 0, stream>>>(counts, excl, bsum, NN);
    scan_b_kernel<<<1, 64, 0, stream>>>(bsum, row_ptr, SCAN_NB, NN);
    scan_c_kernel<<<SCAN_NB, 256, 0, stream>>>(excl, bsum, row_ptr, cursor, NN);
    scatter_kernel<<<(EE + 255) / 256, 256, 0, stream>>>(src, dst, cursor, eidx, srcs);

    // ---- input conversions / weight packing ----
    cvt_bf16_kernel<<<(NN * IN_DIM + 255) / 256, 256, 0, stream>>>(x, xbf, NN * IN_DIM);
    pack_kernel<<<(IN_DIM * HID1 + 255) / 256, 256, 0, stream>>>(W1, W1p, IN_DIM, HID1);
    pack_kernel<<<(HID1 * HID2 + 255) / 256, 256, 0, stream>>>(W2, W2p, HID1, HID2);
    pack_kernel<<<(HID2 * FC1 + 255) / 256, 256, 0, stream>>>(fcW1, fW1p, HID2, FC1);

    // ---- layer 1 ----
    mgemm_kernel<<<dim3((NN + 127) / 128, HID1 / 64), 256, 0, stream>>>(
        xbf, W1p, h1bf, NN, IN_DIM, HID1);
    att1_kernel<<<(NN * H1 + 255) / 256, 256, 0, stream>>>(h1bf, att_src1, att_dst1, a_s1, a_d1);
    gat1_kernel<<<(NN + 3) / 4, 256, 0, stream>>>(row_ptr, eidx, srcs, a_s1, a_d1,
                                                  h1bf, b1, alpha1_out, x1bf);

    // ---- layer 2 ----
    mgemm_kernel<<<dim3((NN + 127) / 128, HID2 / 64), 256, 0, stream>>>(
        x1bf, W2p, h2bf, NN, HID1, HID2);
    att2_kernel<<<NN, 64, 0, stream>>>(h2bf, att_src2, att_dst2, a_s2, a_d2);
    gat2_kernel<<<(NN + 3) / 4, 256, 0, stream>>>(row_ptr, eidx, srcs, a_s2, a_d2,
                                                  h2bf, b2, alpha2_out, x2bf);

    // ---- FC head ----
    fc_mfma_kernel<<<(NN + 31) / 32, 256, 0, stream>>>(x2bf, fW1p, fcb1, fcW2, fcb2, out_n);
}

// Round 9
// 325.464 us; speedup vs baseline: 1.3592x; 1.0038x over previous
//
#include <hip/hip_runtime.h>
#include <hip/hip_bf16.h>
#include <math.h>

#define NN 50000
#define EE 800000
#define IN_DIM 128
#define H1 8
#define D1 32
#define HID1 256
#define HID2 128
#define FC1 512
#define NEG_SLOPE 0.2f

typedef short v8s __attribute__((ext_vector_type(8)));
typedef float v4f __attribute__((ext_vector_type(4)));
typedef unsigned int v4u __attribute__((ext_vector_type(4)));

__device__ __forceinline__ float bf2f(unsigned short u) {
    unsigned int x = ((unsigned int)u) << 16;
    return __uint_as_float(x);
}
__device__ __forceinline__ unsigned short f2bf(float v) {
    __hip_bfloat16 h = __float2bfloat16(v);
    return *(unsigned short*)&h;
}

// ---------------- utility kernels ----------------

__global__ void fill_zero_int(int* p, int n) {
    int i = blockIdx.x * blockDim.x + threadIdx.x;
    if (i < n) p[i] = 0;
}

__global__ void hist_kernel(const int* __restrict__ dst, int* __restrict__ counts) {
    int e = blockIdx.x * blockDim.x + threadIdx.x;
    if (e < EE) atomicAdd(&counts[dst[e]], 1);
}

// ---- hierarchical exclusive scan ----

__global__ __launch_bounds__(256) void scan_a_kernel(const int* __restrict__ counts,
                                                     int* __restrict__ excl,
                                                     int* __restrict__ bsum, int n) {
    __shared__ int wsum[4];
    int tid = threadIdx.x;
    int base = blockIdx.x * 1024 + tid * 4;
    int v0 = 0, v1 = 0, v2 = 0, v3 = 0;
    if (base + 3 < n) {
        int4 t = *(const int4*)(counts + base);
        v0 = t.x; v1 = t.y; v2 = t.z; v3 = t.w;
    } else {
        if (base + 0 < n) v0 = counts[base + 0];
        if (base + 1 < n) v1 = counts[base + 1];
        if (base + 2 < n) v2 = counts[base + 2];
        if (base + 3 < n) v3 = counts[base + 3];
    }
    int tot = v0 + v1 + v2 + v3;
    int lane = tid & 63;
    int w = tid >> 6;
    int x = tot;
    #pragma unroll
    for (int off = 1; off < 64; off <<= 1) {
        int y = __shfl_up(x, off);
        if (lane >= off) x += y;
    }
    if (lane == 63) wsum[w] = x;
    __syncthreads();
    int woff = 0;
    for (int i = 0; i < w; i++) woff += wsum[i];
    int et = woff + x - tot;
    if (base + 0 < n) excl[base + 0] = et;
    if (base + 1 < n) excl[base + 1] = et + v0;
    if (base + 2 < n) excl[base + 2] = et + v0 + v1;
    if (base + 3 < n) excl[base + 3] = et + v0 + v1 + v2;
    if (tid == 255) bsum[blockIdx.x] = woff + x;
}

__global__ __launch_bounds__(64) void scan_b_kernel(int* __restrict__ bsum,
                                                    int* __restrict__ row_ptr, int nb, int n) {
    int lane = threadIdx.x;
    int v = (lane < nb) ? bsum[lane] : 0;
    int x = v;
    #pragma unroll
    for (int off = 1; off < 64; off <<= 1) {
        int y = __shfl_up(x, off);
        if (lane >= off) x += y;
    }
    if (lane < nb) bsum[lane] = x - v;
    if (lane == 63) row_ptr[n] = x;
}

__global__ __launch_bounds__(256) void scan_c_kernel(const int* __restrict__ excl,
                                                     const int* __restrict__ bsum,
                                                     int* __restrict__ row_ptr,
                                                     int* __restrict__ cursor, int n) {
    int base = blockIdx.x * 1024 + threadIdx.x * 4;
    int off = bsum[blockIdx.x];
    #pragma unroll
    for (int j = 0; j < 4; j++) {
        int i = base + j;
        if (i < n) {
            int r = excl[i] + off;
            row_ptr[i] = r;
            cursor[i] = r;
        }
    }
}

__global__ void scatter_kernel(const int* __restrict__ src, const int* __restrict__ dst,
                               int* __restrict__ cursor, int* __restrict__ eidx,
                               int* __restrict__ srcs) {
    int e = blockIdx.x * blockDim.x + threadIdx.x;
    if (e >= EE) return;
    int d = dst[e];
    int p = atomicAdd(&cursor[d], 1);
    eidx[p] = e;
    srcs[p] = src[e];
}

__global__ void cvt_bf16_kernel(const float* __restrict__ in, __hip_bfloat16* __restrict__ out, int n) {
    int i = blockIdx.x * blockDim.x + threadIdx.x;
    if (i < n) out[i] = __float2bfloat16(in[i]);
}

// pack fp32 weight B[K][N] into MFMA fragment-major bf16
__global__ void pack_kernel(const float* __restrict__ B, __hip_bfloat16* __restrict__ Bp,
                            int K, int N) {
    int idx = blockIdx.x * blockDim.x + threadIdx.x;
    if (idx >= K * N) return;
    int k = idx / N, n = idx % N;
    int ntile = n >> 4, ks = k >> 5, kk = k & 31;
    int lane = (n & 15) | ((kk >> 3) << 4);
    int j = kk & 7;
    int KS = K >> 5;
    Bp[((size_t)(ntile * KS + ks) * 64 + lane) * 8 + j] = __float2bfloat16(B[idx]);
}

// ---------------- MFMA GEMM (bf16 in, bf16 out) ----------------

__global__ __launch_bounds__(256) void mgemm_kernel(const __hip_bfloat16* __restrict__ A,
                                                    const __hip_bfloat16* __restrict__ Bp,
                                                    __hip_bfloat16* __restrict__ Cbf,
                                                    int M, int K, int N) {
    int w = threadIdx.x >> 6, l = threadIdx.x & 63;
    int bm = blockIdx.x * 128 + w * 32;
    int bn = blockIdx.y * 64;
    int lr = l & 15, lk = l >> 4;
    int KS = K >> 5;
    const short* Ab = (const short*)A;
    const short* Bb = (const short*)Bp;
    v4f acc[2][4];
    #pragma unroll
    for (int mi = 0; mi < 2; mi++)
        #pragma unroll
        for (int nt = 0; nt < 4; nt++) acc[mi][nt] = (v4f)(0.f);
    for (int ks = 0; ks < KS; ks++) {
        v8s a[2];
        #pragma unroll
        for (int mi = 0; mi < 2; mi++) {
            int gm = bm + mi * 16 + lr;
            a[mi] = (gm < M) ? *(const v8s*)(Ab + (size_t)gm * K + ks * 32 + lk * 8)
                             : (v8s)(short)0;
        }
        #pragma unroll
        for (int nt = 0; nt < 4; nt++) {
            int ntile = (bn >> 4) + nt;
            v8s b = *(const v8s*)(Bb + ((size_t)(ntile * KS + ks) * 64 + l) * 8);
            acc[0][nt] = __builtin_amdgcn_mfma_f32_16x16x32_bf16(a[0], b, acc[0][nt], 0, 0, 0);
            acc[1][nt] = __builtin_amdgcn_mfma_f32_16x16x32_bf16(a[1], b, acc[1][nt], 0, 0, 0);
        }
    }
    #pragma unroll
    for (int mi = 0; mi < 2; mi++) {
        #pragma unroll
        for (int nt = 0; nt < 4; nt++) {
            int gn = bn + nt * 16 + lr;
            #pragma unroll
            for (int j = 0; j < 4; j++) {
                int gm = bm + mi * 16 + lk * 4 + j;
                if (gm < M)
                    Cbf[(size_t)gm * N + gn] = __float2bfloat16(acc[mi][nt][j]);
            }
        }
    }
}

// ---------------- fused FC head via MFMA ----------------

__global__ __launch_bounds__(256) void fc_mfma_kernel(const __hip_bfloat16* __restrict__ A,
                                                      const __hip_bfloat16* __restrict__ Bp,
                                                      const float* __restrict__ fcb1,
                                                      const float* __restrict__ fcW2,
                                                      const float* __restrict__ fcb2,
                                                      float* __restrict__ out) {
    __shared__ float red[4][32];
    int w = threadIdx.x >> 6, l = threadIdx.x & 63;
    int bm = blockIdx.x * 32;
    int lr = l & 15, lk = l >> 4;
    const int K = HID2, KS = K >> 5;
    const short* Ab = (const short*)A;
    const short* Bb = (const short*)Bp;
    v4f acc[2][8];
    #pragma unroll
    for (int mi = 0; mi < 2; mi++)
        #pragma unroll
        for (int nt = 0; nt < 8; nt++) acc[mi][nt] = (v4f)(0.f);
    for (int ks = 0; ks < KS; ks++) {
        v8s a[2];
        #pragma unroll
        for (int mi = 0; mi < 2; mi++) {
            int gm = bm + mi * 16 + lr;
            a[mi] = (gm < NN) ? *(const v8s*)(Ab + (size_t)gm * K + ks * 32 + lk * 8)
                              : (v8s)(short)0;
        }
        #pragma unroll
        for (int nt = 0; nt < 8; nt++) {
            int ntile = w * 8 + nt;
            v8s b = *(const v8s*)(Bb + ((size_t)(ntile * KS + ks) * 64 + l) * 8);
            acc[0][nt] = __builtin_amdgcn_mfma_f32_16x16x32_bf16(a[0], b, acc[0][nt], 0, 0, 0);
            acc[1][nt] = __builtin_amdgcn_mfma_f32_16x16x32_bf16(a[1], b, acc[1][nt], 0, 0, 0);
        }
    }
    float p[2][4];
    #pragma unroll
    for (int mi = 0; mi < 2; mi++)
        #pragma unroll
        for (int j = 0; j < 4; j++) p[mi][j] = 0.f;
    #pragma unroll
    for (int nt = 0; nt < 8; nt++) {
        int col = w * 128 + nt * 16 + lr;
        float b1v = fcb1[col], w2v = fcW2[col];
        #pragma unroll
        for (int mi = 0; mi < 2; mi++) {
            #pragma unroll
            for (int j = 0; j < 4; j++) {
                float v = acc[mi][nt][j] + b1v;
                p[mi][j] += ((v > 0.f) ? v : 0.f) * w2v;
            }
        }
    }
    #pragma unroll
    for (int mi = 0; mi < 2; mi++)
        #pragma unroll
        for (int j = 0; j < 4; j++) {
            float v = p[mi][j];
            v += __shfl_xor(v, 1);
            v += __shfl_xor(v, 2);
            v += __shfl_xor(v, 4);
            v += __shfl_xor(v, 8);
            p[mi][j] = v;
        }
    if (lr == 0) {
        #pragma unroll
        for (int mi = 0; mi < 2; mi++)
            #pragma unroll
            for (int j = 0; j < 4; j++) red[w][mi * 16 + lk * 4 + j] = p[mi][j];
    }
    __syncthreads();
    int tid = threadIdx.x;
    if (tid < 32) {
        int gm = bm + tid;
        if (gm < NN)
            out[gm] = red[0][tid] + red[1][tid] + red[2][tid] + red[3][tid] + fcb2[0];
    }
}

// ---------------- layer 1 attention logits (bf16 input) ----------------

__global__ void att1_kernel(const __hip_bfloat16* __restrict__ h1bf,
                            const float* __restrict__ att_src,
                            const float* __restrict__ att_dst, float* __restrict__ a_s,
                            float* __restrict__ a_d) {
    int idx = blockIdx.x * blockDim.x + threadIdx.x;
    if (idx >= NN * H1) return;
    int n = idx >> 3, h = idx & 7;
    const v4u* row = (const v4u*)((const unsigned short*)h1bf + (size_t)n * HID1 + h * D1);
    float s = 0.f, d = 0.f;
    #pragma unroll
    for (int q = 0; q < 4; q++) {
        v4u v = row[q];
        #pragma unroll
        for (int k = 0; k < 4; k++) {
            float lo = __uint_as_float(v[k] << 16);
            float hi = __uint_as_float(v[k] & 0xffff0000u);
            int kk = q * 8 + k * 2;
            s += lo * att_src[h * D1 + kk] + hi * att_src[h * D1 + kk + 1];
            d += lo * att_dst[h * D1 + kk] + hi * att_dst[h * D1 + kk + 1];
        }
    }
    a_s[idx] = s;
    a_d[idx] = d;
}

// ---------------- fused layer-1 softmax + aggregation, degree-bucketed ----------------
// KM = number of 8-edge register slots (cnt <= 8*KM). softmax lane=(j,h); agg lane owns
// dims 4*lane..4*lane+3, head hl=lane>>3; srcs/eidx loaded once and shfl-distributed.

template <int KM>
__device__ __forceinline__ void gat1_fast(int lane, int start, int cnt,
                                          const int* __restrict__ srcs,
                                          const int* __restrict__ eidx,
                                          const float* __restrict__ a_s, float ad,
                                          const unsigned short* __restrict__ hb,
                                          float* __restrict__ alpha1_out,
                                          float& acc0, float& acc1, float& acc2, float& acc3) {
    int h = lane & 7, j = lane >> 3;
    int hl = lane >> 3;
    int cl = min(lane, cnt - 1);
    int s_all = srcs[start + cl];
    int e_all = eidx[start + cl];
    float ex[KM];
    int sj[KM];
    #pragma unroll
    for (int k = 0; k < KM; k++) {
        int idx = j + k * 8;
        sj[k] = __shfl(s_all, idx);  // == srcs[start + min(idx, cnt-1)]
        float v = a_s[(size_t)sj[k] * 8 + h] + ad;
        v = (v >= 0.f) ? v : NEG_SLOPE * v;
        ex[k] = (idx < cnt) ? v : -INFINITY;
    }
    float m = ex[0];
    #pragma unroll
    for (int k = 1; k < KM; k++) m = fmaxf(m, ex[k]);
    m = fmaxf(m, __shfl_xor(m, 8));
    m = fmaxf(m, __shfl_xor(m, 16));
    m = fmaxf(m, __shfl_xor(m, 32));
    float s = 0.f;
    #pragma unroll
    for (int k = 0; k < KM; k++) {
        ex[k] = expf(ex[k] - m);
        s += ex[k];
    }
    s += __shfl_xor(s, 8);
    s += __shfl_xor(s, 16);
    s += __shfl_xor(s, 32);
    float inv = 1.f / (s + 1e-16f);
    #pragma unroll
    for (int k = 0; k < KM; k++) ex[k] *= inv;  // ex[] now alpha (0 for padded)
    #pragma unroll
    for (int k = 0; k < KM; k++) {
        int idx = j + k * 8;
        int eo = __shfl(e_all, idx);
        if (idx < cnt) alpha1_out[(size_t)eo * 8 + h] = ex[k];
    }
    int rounds = (cnt + 7) >> 3;
    #pragma unroll
    for (int K = 0; K < KM; K++) {
        if (K < rounds) {
            int sjt[8];
            float At[8];
            ushort4 qt[8];
            #pragma unroll
            for (int t = 0; t < 8; t++) {
                sjt[t] = __shfl(sj[K], t * 8);       // edge K*8+t src
                At[t] = __shfl(ex[K], t * 8 + hl);   // its alpha for head hl
            }
            #pragma unroll
            for (int t = 0; t < 8; t++)
                qt[t] = *(const ushort4*)(hb + (size_t)sjt[t] * HID1 + lane * 4);
            #pragma unroll
            for (int t = 0; t < 8; t++) {
                acc0 += At[t] * bf2f(qt[t].x);
                acc1 += At[t] * bf2f(qt[t].y);
                acc2 += At[t] * bf2f(qt[t].z);
                acc3 += At[t] * bf2f(qt[t].w);
            }
        }
    }
}

__global__ __launch_bounds__(256) void gat1_kernel(const int* __restrict__ row_ptr,
                                                   const int* __restrict__ eidx,
                                                   const int* __restrict__ srcs,
                                                   const float* __restrict__ a_s,
                                                   const float* __restrict__ a_d,
                                                   const __hip_bfloat16* __restrict__ h1bf,
                                                   const float* __restrict__ b1,
                                                   float* __restrict__ alpha1_out,
                                                   __hip_bfloat16* __restrict__ x1bf) {
    int wv = threadIdx.x >> 6, lane = threadIdx.x & 63;
    int n = blockIdx.x * 4 + wv;
    if (n >= NN) return;
    int start = row_ptr[n], end = row_ptr[n + 1];
    int cnt = end - start;
    int h = lane & 7, j = lane >> 3;
    int hl = lane >> 3;
    const unsigned short* hb = (const unsigned short*)h1bf;
    float acc0 = 0.f, acc1 = 0.f, acc2 = 0.f, acc3 = 0.f;
    if (cnt > 0 && cnt <= 64) {
        float ad = a_d[(size_t)n * 8 + h];
        if (cnt <= 8)
            gat1_fast<1>(lane, start, cnt, srcs, eidx, a_s, ad, hb, alpha1_out, acc0, acc1, acc2, acc3);
        else if (cnt <= 16)
            gat1_fast<2>(lane, start, cnt, srcs, eidx, a_s, ad, hb, alpha1_out, acc0, acc1, acc2, acc3);
        else if (cnt <= 24)
            gat1_fast<3>(lane, start, cnt, srcs, eidx, a_s, ad, hb, alpha1_out, acc0, acc1, acc2, acc3);
        else if (cnt <= 32)
            gat1_fast<4>(lane, start, cnt, srcs, eidx, a_s, ad, hb, alpha1_out, acc0, acc1, acc2, acc3);
        else
            gat1_fast<8>(lane, start, cnt, srcs, eidx, a_s, ad, hb, alpha1_out, acc0, acc1, acc2, acc3);
    } else if (cnt > 64) {
        // fallback (degree>64): 3-pass strided softmax, inline-recomputed agg
        float ad = a_d[(size_t)n * 8 + h];
        float m = -INFINITY;
        for (int p = start + j; p < end; p += 8) {
            float v = a_s[(size_t)srcs[p] * 8 + h] + ad;
            v = (v >= 0.f) ? v : NEG_SLOPE * v;
            m = fmaxf(m, v);
        }
        m = fmaxf(m, __shfl_xor(m, 8));
        m = fmaxf(m, __shfl_xor(m, 16));
        m = fmaxf(m, __shfl_xor(m, 32));
        float s = 0.f;
        for (int p = start + j; p < end; p += 8) {
            float v = a_s[(size_t)srcs[p] * 8 + h] + ad;
            v = (v >= 0.f) ? v : NEG_SLOPE * v;
            s += expf(v - m);
        }
        s += __shfl_xor(s, 8);
        s += __shfl_xor(s, 16);
        s += __shfl_xor(s, 32);
        float inv = 1.f / (s + 1e-16f);
        for (int p = start + j; p < end; p += 8) {
            float v = a_s[(size_t)srcs[p] * 8 + h] + ad;
            v = (v >= 0.f) ? v : NEG_SLOPE * v;
            alpha1_out[(size_t)eidx[p] * 8 + h] = expf(v - m) * inv;
        }
        float mh = __shfl(m, hl);
        float invh = __shfl(inv, hl);
        float adh = __shfl(ad, hl);
        for (int p = start; p < end; p++) {
            int sp = srcs[p];
            float v = a_s[(size_t)sp * 8 + hl] + adh;
            v = (v >= 0.f) ? v : NEG_SLOPE * v;
            float al = expf(v - mh) * invh;
            ushort4 q = *(const ushort4*)(hb + (size_t)sp * HID1 + lane * 4);
            acc0 += al * bf2f(q.x);
            acc1 += al * bf2f(q.y);
            acc2 += al * bf2f(q.z);
            acc3 += al * bf2f(q.w);
        }
    }
    float4 bb = *(const float4*)(b1 + lane * 4);
    float r0 = acc0 + bb.x, r1 = acc1 + bb.y, r2 = acc2 + bb.z, r3 = acc3 + bb.w;
    r0 = (r0 > 0.f) ? r0 : expf(r0) - 1.f;
    r1 = (r1 > 0.f) ? r1 : expf(r1) - 1.f;
    r2 = (r2 > 0.f) ? r2 : expf(r2) - 1.f;
    r3 = (r3 > 0.f) ? r3 : expf(r3) - 1.f;
    ushort4 o;
    o.x = f2bf(r0); o.y = f2bf(r1); o.z = f2bf(r2); o.w = f2bf(r3);
    *(ushort4*)((unsigned short*)x1bf + (size_t)n * HID1 + lane * 4) = o;
}

// ---------------- layer 2 attention logits (1 head, bf16 input) ----------------

__global__ __launch_bounds__(64) void att2_kernel(const __hip_bfloat16* __restrict__ h2bf,
                                                  const float* __restrict__ att_src,
                                                  const float* __restrict__ att_dst,
                                                  float* __restrict__ a_s, float* __restrict__ a_d) {
    int n = blockIdx.x;
    int lane = threadIdx.x;
    const unsigned short* row = (const unsigned short*)h2bf + (size_t)n * HID2;
    unsigned int v = *(const unsigned int*)(row + lane * 2);
    float lo = __uint_as_float(v << 16);
    float hi = __uint_as_float(v & 0xffff0000u);
    float s = lo * att_src[lane * 2] + hi * att_src[lane * 2 + 1];
    float d = lo * att_dst[lane * 2] + hi * att_dst[lane * 2 + 1];
    for (int off = 32; off; off >>= 1) {
        s += __shfl_down(s, off);
        d += __shfl_down(d, off);
    }
    if (lane == 0) {
        a_s[n] = s;
        a_d[n] = d;
    }
}

// ---------------- fused layer-2 softmax + aggregation (wave per node) ----------------

__global__ __launch_bounds__(256) void gat2_kernel(const int* __restrict__ row_ptr,
                                                   const int* __restrict__ eidx,
                                                   const int* __restrict__ srcs,
                                                   const float* __restrict__ a_s,
                                                   const float* __restrict__ a_d,
                                                   const __hip_bfloat16* __restrict__ h2bf,
                                                   const float* __restrict__ b2,
                                                   float* __restrict__ alpha2_out,
                                                   __hip_bfloat16* __restrict__ x2bf) {
    int wv = threadIdx.x >> 6, lane = threadIdx.x & 63;
    int n = blockIdx.x * 4 + wv;
    if (n >= NN) return;
    int start = row_ptr[n], end = row_ptr[n + 1];
    int cnt = end - start;
    int r = lane >> 5, c = lane & 31;
    const unsigned short* hb = (const unsigned short*)h2bf;
    float acc0 = 0.f, acc1 = 0.f, acc2 = 0.f, acc3 = 0.f;
    if (cnt > 0 && cnt <= 64) {
        float ad = a_d[n];
        bool act = lane < cnt;
        int ii = min(lane, cnt - 1);
        int sj = srcs[start + ii];
        float v = a_s[sj] + ad;
        v = (v >= 0.f) ? v : NEG_SLOPE * v;
        float e = act ? v : -INFINITY;
        float m = e;
        #pragma unroll
        for (int off = 1; off < 64; off <<= 1) m = fmaxf(m, __shfl_xor(m, off));
        float ex = expf(e - m);
        float s = ex;
        #pragma unroll
        for (int off = 1; off < 64; off <<= 1) s += __shfl_xor(s, off);
        float al = ex / (s + 1e-16f);  // 0 for padded lanes
        if (act) alpha2_out[eidx[start + lane]] = al;
        int rounds = (cnt + 7) >> 3;
        #pragma unroll
        for (int K = 0; K < 8; K++) {
            if (K < rounds) {
                int sjt[4];
                float At[4];
                ushort4 qt[4];
                #pragma unroll
                for (int t = 0; t < 4; t++) {
                    int je = K * 8 + t * 2 + r;
                    sjt[t] = __shfl(sj, je);
                    At[t] = __shfl(al, je);
                }
                #pragma unroll
                for (int t = 0; t < 4; t++)
                    qt[t] = *(const ushort4*)(hb + (size_t)sjt[t] * HID2 + c * 4);
                #pragma unroll
                for (int t = 0; t < 4; t++) {
                    acc0 += At[t] * bf2f(qt[t].x);
                    acc1 += At[t] * bf2f(qt[t].y);
                    acc2 += At[t] * bf2f(qt[t].z);
                    acc3 += At[t] * bf2f(qt[t].w);
                }
            }
        }
    } else if (cnt > 64) {
        float ad = a_d[n];
        float m = -INFINITY;
        for (int p = start + lane; p < end; p += 64) {
            float v = a_s[srcs[p]] + ad;
            v = (v >= 0.f) ? v : NEG_SLOPE * v;
            m = fmaxf(m, v);
        }
        for (int off = 32; off; off >>= 1) m = fmaxf(m, __shfl_xor(m, off));
        float s = 0.f;
        for (int p = start + lane; p < end; p += 64) {
            float v = a_s[srcs[p]] + ad;
            v = (v >= 0.f) ? v : NEG_SLOPE * v;
            s += expf(v - m);
        }
        for (int off = 32; off; off >>= 1) s += __shfl_xor(s, off);
        float inv = 1.f / (s + 1e-16f);
        for (int p = start + lane; p < end; p += 64) {
            float v = a_s[srcs[p]] + ad;
            v = (v >= 0.f) ? v : NEG_SLOPE * v;
            alpha2_out[eidx[p]] = expf(v - m) * inv;
        }
        for (int p = start + r; p < end; p += 2) {
            int sp = srcs[p];
            float v = a_s[sp] + ad;
            v = (v >= 0.f) ? v : NEG_SLOPE * v;
            float al = expf(v - m) * inv;
            ushort4 q = *(const ushort4*)(hb + (size_t)sp * HID2 + c * 4);
            acc0 += al * bf2f(q.x);
            acc1 += al * bf2f(q.y);
            acc2 += al * bf2f(q.z);
            acc3 += al * bf2f(q.w);
        }
    }
    acc0 += __shfl_xor(acc0, 32);
    acc1 += __shfl_xor(acc1, 32);
    acc2 += __shfl_xor(acc2, 32);
    acc3 += __shfl_xor(acc3, 32);
    if (r == 0) {
        float4 bb = *(const float4*)(b2 + c * 4);
        float r0 = acc0 + bb.x, r1 = acc1 + bb.y, r2 = acc2 + bb.z, r3 = acc3 + bb.w;
        r0 = (r0 > 0.f) ? r0 : 0.f;
        r1 = (r1 > 0.f) ? r1 : 0.f;
        r2 = (r2 > 0.f) ? r2 : 0.f;
        r3 = (r3 > 0.f) ? r3 : 0.f;
        ushort4 o;
        o.x = f2bf(r0); o.y = f2bf(r1); o.z = f2bf(r2); o.w = f2bf(r3);
        *(ushort4*)((unsigned short*)x2bf + (size_t)n * HID2 + c * 4) = o;
    }
}

// ---------------- host launch ----------------

extern "C" void kernel_launch(void* const* d_in, const int* in_sizes, int n_in,
                              void* d_out, int out_size, void* d_ws, size_t ws_size,
                              hipStream_t stream) {
    (void)in_sizes; (void)n_in; (void)out_size; (void)ws_size;
    const float* x        = (const float*)d_in[0];
    const int*   eindex   = (const int*)d_in[1];
    const float* W1       = (const float*)d_in[2];
    const float* att_src1 = (const float*)d_in[3];
    const float* att_dst1 = (const float*)d_in[4];
    const float* b1       = (const float*)d_in[5];
    const float* W2       = (const float*)d_in[6];
    const float* att_src2 = (const float*)d_in[7];
    const float* att_dst2 = (const float*)d_in[8];
    const float* b2       = (const float*)d_in[9];
    const float* fcW1     = (const float*)d_in[10];
    const float* fcb1     = (const float*)d_in[11];
    const float* fcW2     = (const float*)d_in[12];
    const float* fcb2     = (const float*)d_in[13];

    const int* src = eindex;
    const int* dst = eindex + EE;

    float* out_n      = (float*)d_out;               // [N]
    float* alpha1_out = out_n + NN;                  // [E,8]
    float* alpha2_out = alpha1_out + (size_t)EE * 8; // [E]

    char* ws = (char*)d_ws;
    size_t off = 0;
    auto alloc = [&](size_t bytes) {
        size_t o = off;
        off = (off + bytes + 255) & ~(size_t)255;
        return o;
    };
    size_t o_rowptr = alloc((NN + 1) * sizeof(int));
    size_t o_cursor = alloc(NN * sizeof(int));
    size_t o_counts = alloc(NN * sizeof(int));
    size_t o_excl   = alloc(NN * sizeof(int));
    size_t o_bsum   = alloc(64 * sizeof(int));
    size_t o_eidx   = alloc(EE * sizeof(int));
    size_t o_srcs   = alloc(EE * sizeof(int));
    size_t o_as1    = alloc((size_t)NN * H1 * sizeof(float));
    size_t o_ad1    = alloc((size_t)NN * H1 * sizeof(float));
    size_t o_h1bf   = alloc((size_t)NN * HID1 * sizeof(__hip_bfloat16));
    size_t o_xbf    = alloc((size_t)NN * IN_DIM * sizeof(__hip_bfloat16));
    size_t o_x1bf   = alloc((size_t)NN * HID1 * sizeof(__hip_bfloat16));
    size_t o_h2bf   = alloc((size_t)NN * HID2 * sizeof(__hip_bfloat16));
    size_t o_x2bf   = alloc((size_t)NN * HID2 * sizeof(__hip_bfloat16));
    size_t o_W1p    = alloc((size_t)IN_DIM * HID1 * sizeof(__hip_bfloat16));
    size_t o_W2p    = alloc((size_t)HID1 * HID2 * sizeof(__hip_bfloat16));
    size_t o_fW1p   = alloc((size_t)HID2 * FC1 * sizeof(__hip_bfloat16));

    int*   row_ptr = (int*)(ws + o_rowptr);
    int*   cursor  = (int*)(ws + o_cursor);
    int*   counts  = (int*)(ws + o_counts);
    int*   excl    = (int*)(ws + o_excl);
    int*   bsum    = (int*)(ws + o_bsum);
    int*   eidx    = (int*)(ws + o_eidx);
    int*   srcs    = (int*)(ws + o_srcs);
    float* a_s1    = (float*)(ws + o_as1);
    float* a_d1    = (float*)(ws + o_ad1);
    __hip_bfloat16* h1bf  = (__hip_bfloat16*)(ws + o_h1bf);
    __hip_bfloat16* xbf   = (__hip_bfloat16*)(ws + o_xbf);
    __hip_bfloat16* x1bf  = (__hip_bfloat16*)(ws + o_x1bf);
    __hip_bfloat16* h2bf  = (__hip_bfloat16*)(ws + o_h2bf);
    __hip_bfloat16* x2bf  = (__hip_bfloat16*)(ws + o_x2bf);
    __hip_bfloat16* W1p   = (__hip_bfloat16*)(ws + o_W1p);
    __hip_bfloat16* W2p   = (__hip_bfloat16*)(ws + o_W2p);
    __hip_bfloat16* fW1p  = (__hip_bfloat16*)(ws + o_fW1p);
    // layer-2 aliases
    float* a_s2 = a_s1;
    float* a_d2 = a_d1;

    const int SCAN_NB = (NN + 1023) / 1024;  // 49

    // ---- build CSR by dst ----
    fill_zero_int<<<(NN + 255) / 256, 256, 0, stream>>>(counts, NN);
    hist_kernel<<<(EE + 255) / 256, 256, 0, stream>>>(dst, counts);
    scan_a_kernel<<<SCAN_NB, 256, 0, stream>>>(counts, excl, bsum, NN);
    scan_b_kernel<<<1, 64, 0, stream>>>(bsum, row_ptr, SCAN_NB, NN);
    scan_c_kernel<<<SCAN_NB, 256, 0, stream>>>(excl, bsum, row_ptr, cursor, NN);
    scatter_kernel<<<(EE + 255) / 256, 256, 0, stream>>>(src, dst, cursor, eidx, srcs);

    // ---- input conversions / weight packing ----
    cvt_bf16_kernel<<<(NN * IN_DIM + 255) / 256, 256, 0, stream>>>(x, xbf, NN * IN_DIM);
    pack_kernel<<<(IN_DIM * HID1 + 255) / 256, 256, 0, stream>>>(W1, W1p, IN_DIM, HID1);
    pack_kernel<<<(HID1 * HID2 + 255) / 256, 256, 0, stream>>>(W2, W2p, HID1, HID2);
    pack_kernel<<<(HID2 * FC1 + 255) / 256, 256, 0, stream>>>(fcW1, fW1p, HID2, FC1);

    // ---- layer 1 ----
    mgemm_kernel<<<dim3((NN + 127) / 128, HID1 / 64), 256, 0, stream>>>(
        xbf, W1p, h1bf, NN, IN_DIM, HID1);
    att1_kernel<<<(NN * H1 + 255) / 256, 256, 0, stream>>>(h1bf, att_src1, att_dst1, a_s1, a_d1);
    gat1_kernel<<<(NN + 3) / 4, 256, 0, stream>>>(row_ptr, eidx, srcs, a_s1, a_d1,
                                                  h1bf, b1, alpha1_out, x1bf);

    // ---- layer 2 ----
    mgemm_kernel<<<dim3((NN + 127) / 128, HID2 / 64), 256, 0, stream>>>(
        x1bf, W2p, h2bf, NN, HID1, HID2);
    att2_kernel<<<NN, 64, 0, stream>>>(h2bf, att_src2, att_dst2, a_s2, a_d2);
    gat2_kernel<<<(NN + 3) / 4, 256, 0, stream>>>(row_ptr, eidx, srcs, a_s2, a_d2,
                                                  h2bf, b2, alpha2_out, x2bf);

    // ---- FC head ----
    fc_mfma_kernel<<<(NN + 31) / 32, 256, 0, stream>>>(x2bf, fW1p, fcb1, fcW2, fcb2, out_n);
}

// Round 10
// 308.056 us; speedup vs baseline: 1.4360x; 1.0565x over previous
//
#include <hip/hip_runtime.h>
#include <hip/hip_bf16.h>
#include <hip/hip_fp8.h>
#include <math.h>

#define NN 50000
#define EE 800000
#define IN_DIM 128
#define H1 8
#define D1 32
#define HID1 256
#define HID2 128
#define FC1 512
#define NEG_SLOPE 0.2f

typedef short v8s __attribute__((ext_vector_type(8)));
typedef float v4f __attribute__((ext_vector_type(4)));
typedef unsigned int v4u __attribute__((ext_vector_type(4)));

__device__ __forceinline__ float bf2f(unsigned short u) {
    unsigned int x = ((unsigned int)u) << 16;
    return __uint_as_float(x);
}
__device__ __forceinline__ unsigned short f2bf(float v) {
    __hip_bfloat16 h = __float2bfloat16(v);
    return *(unsigned short*)&h;
}
__device__ __forceinline__ unsigned char f2f8(float v) {
    __hip_fp8_e4m3 t(v);
    return (unsigned char)t.__x;
}
__device__ __forceinline__ float f8tof(unsigned char u) {
    __hip_fp8_e4m3 t;
    t.__x = (__hip_fp8_storage_t)u;
    return (float)t;
}

// ---------------- utility kernels ----------------

__global__ void fill_zero_int(int* p, int n) {
    int i = blockIdx.x * blockDim.x + threadIdx.x;
    if (i < n) p[i] = 0;
}

__global__ void hist_kernel(const int* __restrict__ dst, int* __restrict__ counts) {
    int e = blockIdx.x * blockDim.x + threadIdx.x;
    if (e < EE) atomicAdd(&counts[dst[e]], 1);
}

// ---- hierarchical exclusive scan ----

__global__ __launch_bounds__(256) void scan_a_kernel(const int* __restrict__ counts,
                                                     int* __restrict__ excl,
                                                     int* __restrict__ bsum, int n) {
    __shared__ int wsum[4];
    int tid = threadIdx.x;
    int base = blockIdx.x * 1024 + tid * 4;
    int v0 = 0, v1 = 0, v2 = 0, v3 = 0;
    if (base + 3 < n) {
        int4 t = *(const int4*)(counts + base);
        v0 = t.x; v1 = t.y; v2 = t.z; v3 = t.w;
    } else {
        if (base + 0 < n) v0 = counts[base + 0];
        if (base + 1 < n) v1 = counts[base + 1];
        if (base + 2 < n) v2 = counts[base + 2];
        if (base + 3 < n) v3 = counts[base + 3];
    }
    int tot = v0 + v1 + v2 + v3;
    int lane = tid & 63;
    int w = tid >> 6;
    int x = tot;
    #pragma unroll
    for (int off = 1; off < 64; off <<= 1) {
        int y = __shfl_up(x, off);
        if (lane >= off) x += y;
    }
    if (lane == 63) wsum[w] = x;
    __syncthreads();
    int woff = 0;
    for (int i = 0; i < w; i++) woff += wsum[i];
    int et = woff + x - tot;
    if (base + 0 < n) excl[base + 0] = et;
    if (base + 1 < n) excl[base + 1] = et + v0;
    if (base + 2 < n) excl[base + 2] = et + v0 + v1;
    if (base + 3 < n) excl[base + 3] = et + v0 + v1 + v2;
    if (tid == 255) bsum[blockIdx.x] = woff + x;
}

__global__ __launch_bounds__(64) void scan_b_kernel(int* __restrict__ bsum,
                                                    int* __restrict__ row_ptr, int nb, int n) {
    int lane = threadIdx.x;
    int v = (lane < nb) ? bsum[lane] : 0;
    int x = v;
    #pragma unroll
    for (int off = 1; off < 64; off <<= 1) {
        int y = __shfl_up(x, off);
        if (lane >= off) x += y;
    }
    if (lane < nb) bsum[lane] = x - v;
    if (lane == 63) row_ptr[n] = x;
}

__global__ __launch_bounds__(256) void scan_c_kernel(const int* __restrict__ excl,
                                                     const int* __restrict__ bsum,
                                                     int* __restrict__ row_ptr,
                                                     int* __restrict__ cursor, int n) {
    int base = blockIdx.x * 1024 + threadIdx.x * 4;
    int off = bsum[blockIdx.x];
    #pragma unroll
    for (int j = 0; j < 4; j++) {
        int i = base + j;
        if (i < n) {
            int r = excl[i] + off;
            row_ptr[i] = r;
            cursor[i] = r;
        }
    }
}

__global__ void scatter_kernel(const int* __restrict__ src, const int* __restrict__ dst,
                               int* __restrict__ cursor, int* __restrict__ eidx,
                               int* __restrict__ srcs) {
    int e = blockIdx.x * blockDim.x + threadIdx.x;
    if (e >= EE) return;
    int d = dst[e];
    int p = atomicAdd(&cursor[d], 1);
    eidx[p] = e;
    srcs[p] = src[e];
}

__global__ void cvt_bf16_kernel(const float* __restrict__ in, __hip_bfloat16* __restrict__ out, int n) {
    int i = blockIdx.x * blockDim.x + threadIdx.x;
    if (i < n) out[i] = __float2bfloat16(in[i]);
}

// pack fp32 weight B[K][N] into MFMA fragment-major bf16
__global__ void pack_kernel(const float* __restrict__ B, __hip_bfloat16* __restrict__ Bp,
                            int K, int N) {
    int idx = blockIdx.x * blockDim.x + threadIdx.x;
    if (idx >= K * N) return;
    int k = idx / N, n = idx % N;
    int ntile = n >> 4, ks = k >> 5, kk = k & 31;
    int lane = (n & 15) | ((kk >> 3) << 4);
    int j = kk & 7;
    int KS = K >> 5;
    Bp[((size_t)(ntile * KS + ks) * 64 + lane) * 8 + j] = __float2bfloat16(B[idx]);
}

// ---------------- MFMA GEMM (bf16 in, bf16 out, optional fp8 copy) ----------------

__global__ __launch_bounds__(256) void mgemm_kernel(const __hip_bfloat16* __restrict__ A,
                                                    const __hip_bfloat16* __restrict__ Bp,
                                                    __hip_bfloat16* __restrict__ Cbf,
                                                    unsigned char* __restrict__ Cf8,
                                                    int M, int K, int N) {
    int w = threadIdx.x >> 6, l = threadIdx.x & 63;
    int bm = blockIdx.x * 128 + w * 32;
    int bn = blockIdx.y * 64;
    int lr = l & 15, lk = l >> 4;
    int KS = K >> 5;
    const short* Ab = (const short*)A;
    const short* Bb = (const short*)Bp;
    v4f acc[2][4];
    #pragma unroll
    for (int mi = 0; mi < 2; mi++)
        #pragma unroll
        for (int nt = 0; nt < 4; nt++) acc[mi][nt] = (v4f)(0.f);
    for (int ks = 0; ks < KS; ks++) {
        v8s a[2];
        #pragma unroll
        for (int mi = 0; mi < 2; mi++) {
            int gm = bm + mi * 16 + lr;
            a[mi] = (gm < M) ? *(const v8s*)(Ab + (size_t)gm * K + ks * 32 + lk * 8)
                             : (v8s)(short)0;
        }
        #pragma unroll
        for (int nt = 0; nt < 4; nt++) {
            int ntile = (bn >> 4) + nt;
            v8s b = *(const v8s*)(Bb + ((size_t)(ntile * KS + ks) * 64 + l) * 8);
            acc[0][nt] = __builtin_amdgcn_mfma_f32_16x16x32_bf16(a[0], b, acc[0][nt], 0, 0, 0);
            acc[1][nt] = __builtin_amdgcn_mfma_f32_16x16x32_bf16(a[1], b, acc[1][nt], 0, 0, 0);
        }
    }
    #pragma unroll
    for (int mi = 0; mi < 2; mi++) {
        #pragma unroll
        for (int nt = 0; nt < 4; nt++) {
            int gn = bn + nt * 16 + lr;
            #pragma unroll
            for (int j = 0; j < 4; j++) {
                int gm = bm + mi * 16 + lk * 4 + j;
                if (gm < M) {
                    float v = acc[mi][nt][j];
                    Cbf[(size_t)gm * N + gn] = __float2bfloat16(v);
                    if (Cf8) Cf8[(size_t)gm * N + gn] = f2f8(v);
                }
            }
        }
    }
}

// ---------------- fused FC head via MFMA ----------------

__global__ __launch_bounds__(256) void fc_mfma_kernel(const __hip_bfloat16* __restrict__ A,
                                                      const __hip_bfloat16* __restrict__ Bp,
                                                      const float* __restrict__ fcb1,
                                                      const float* __restrict__ fcW2,
                                                      const float* __restrict__ fcb2,
                                                      float* __restrict__ out) {
    __shared__ float red[4][32];
    int w = threadIdx.x >> 6, l = threadIdx.x & 63;
    int bm = blockIdx.x * 32;
    int lr = l & 15, lk = l >> 4;
    const int K = HID2, KS = K >> 5;
    const short* Ab = (const short*)A;
    const short* Bb = (const short*)Bp;
    v4f acc[2][8];
    #pragma unroll
    for (int mi = 0; mi < 2; mi++)
        #pragma unroll
        for (int nt = 0; nt < 8; nt++) acc[mi][nt] = (v4f)(0.f);
    for (int ks = 0; ks < KS; ks++) {
        v8s a[2];
        #pragma unroll
        for (int mi = 0; mi < 2; mi++) {
            int gm = bm + mi * 16 + lr;
            a[mi] = (gm < NN) ? *(const v8s*)(Ab + (size_t)gm * K + ks * 32 + lk * 8)
                              : (v8s)(short)0;
        }
        #pragma unroll
        for (int nt = 0; nt < 8; nt++) {
            int ntile = w * 8 + nt;
            v8s b = *(const v8s*)(Bb + ((size_t)(ntile * KS + ks) * 64 + l) * 8);
            acc[0][nt] = __builtin_amdgcn_mfma_f32_16x16x32_bf16(a[0], b, acc[0][nt], 0, 0, 0);
            acc[1][nt] = __builtin_amdgcn_mfma_f32_16x16x32_bf16(a[1], b, acc[1][nt], 0, 0, 0);
        }
    }
    float p[2][4];
    #pragma unroll
    for (int mi = 0; mi < 2; mi++)
        #pragma unroll
        for (int j = 0; j < 4; j++) p[mi][j] = 0.f;
    #pragma unroll
    for (int nt = 0; nt < 8; nt++) {
        int col = w * 128 + nt * 16 + lr;
        float b1v = fcb1[col], w2v = fcW2[col];
        #pragma unroll
        for (int mi = 0; mi < 2; mi++) {
            #pragma unroll
            for (int j = 0; j < 4; j++) {
                float v = acc[mi][nt][j] + b1v;
                p[mi][j] += ((v > 0.f) ? v : 0.f) * w2v;
            }
        }
    }
    #pragma unroll
    for (int mi = 0; mi < 2; mi++)
        #pragma unroll
        for (int j = 0; j < 4; j++) {
            float v = p[mi][j];
            v += __shfl_xor(v, 1);
            v += __shfl_xor(v, 2);
            v += __shfl_xor(v, 4);
            v += __shfl_xor(v, 8);
            p[mi][j] = v;
        }
    if (lr == 0) {
        #pragma unroll
        for (int mi = 0; mi < 2; mi++)
            #pragma unroll
            for (int j = 0; j < 4; j++) red[w][mi * 16 + lk * 4 + j] = p[mi][j];
    }
    __syncthreads();
    int tid = threadIdx.x;
    if (tid < 32) {
        int gm = bm + tid;
        if (gm < NN)
            out[gm] = red[0][tid] + red[1][tid] + red[2][tid] + red[3][tid] + fcb2[0];
    }
}

// ---------------- layer 1 attention logits (bf16 input) ----------------

__global__ void att1_kernel(const __hip_bfloat16* __restrict__ h1bf,
                            const float* __restrict__ att_src,
                            const float* __restrict__ att_dst, float* __restrict__ a_s,
                            float* __restrict__ a_d) {
    int idx = blockIdx.x * blockDim.x + threadIdx.x;
    if (idx >= NN * H1) return;
    int n = idx >> 3, h = idx & 7;
    const v4u* row = (const v4u*)((const unsigned short*)h1bf + (size_t)n * HID1 + h * D1);
    float s = 0.f, d = 0.f;
    #pragma unroll
    for (int q = 0; q < 4; q++) {
        v4u v = row[q];
        #pragma unroll
        for (int k = 0; k < 4; k++) {
            float lo = __uint_as_float(v[k] << 16);
            float hi = __uint_as_float(v[k] & 0xffff0000u);
            int kk = q * 8 + k * 2;
            s += lo * att_src[h * D1 + kk] + hi * att_src[h * D1 + kk + 1];
            d += lo * att_dst[h * D1 + kk] + hi * att_dst[h * D1 + kk + 1];
        }
    }
    a_s[idx] = s;
    a_d[idx] = d;
}

// ---------------- fused layer-1 softmax + aggregation, degree-bucketed, fp8 gather ----

template <int KM>
__device__ __forceinline__ void gat1_fast(int lane, int start, int cnt,
                                          const int* __restrict__ srcs,
                                          const int* __restrict__ eidx,
                                          const float* __restrict__ a_s, float ad,
                                          const unsigned char* __restrict__ hf8,
                                          float* __restrict__ alpha1_out,
                                          float& acc0, float& acc1, float& acc2, float& acc3) {
    int h = lane & 7, j = lane >> 3;
    int hl = lane >> 3;
    int cl = min(lane, cnt - 1);
    int s_all = srcs[start + cl];
    int e_all = eidx[start + cl];
    float ex[KM];
    int sj[KM];
    #pragma unroll
    for (int k = 0; k < KM; k++) {
        int idx = j + k * 8;
        sj[k] = __shfl(s_all, idx);
        float v = a_s[(size_t)sj[k] * 8 + h] + ad;
        v = (v >= 0.f) ? v : NEG_SLOPE * v;
        ex[k] = (idx < cnt) ? v : -INFINITY;
    }
    float m = ex[0];
    #pragma unroll
    for (int k = 1; k < KM; k++) m = fmaxf(m, ex[k]);
    m = fmaxf(m, __shfl_xor(m, 8));
    m = fmaxf(m, __shfl_xor(m, 16));
    m = fmaxf(m, __shfl_xor(m, 32));
    float s = 0.f;
    #pragma unroll
    for (int k = 0; k < KM; k++) {
        ex[k] = expf(ex[k] - m);
        s += ex[k];
    }
    s += __shfl_xor(s, 8);
    s += __shfl_xor(s, 16);
    s += __shfl_xor(s, 32);
    float inv = 1.f / (s + 1e-16f);
    #pragma unroll
    for (int k = 0; k < KM; k++) ex[k] *= inv;
    #pragma unroll
    for (int k = 0; k < KM; k++) {
        int idx = j + k * 8;
        int eo = __shfl(e_all, idx);
        if (idx < cnt) alpha1_out[(size_t)eo * 8 + h] = ex[k];
    }
    int rounds = (cnt + 7) >> 3;
    #pragma unroll
    for (int K = 0; K < KM; K++) {
        if (K < rounds) {
            int sjt[8];
            float At[8];
            uchar4 qt[8];
            #pragma unroll
            for (int t = 0; t < 8; t++) {
                sjt[t] = __shfl(sj[K], t * 8);
                At[t] = __shfl(ex[K], t * 8 + hl);
            }
            #pragma unroll
            for (int t = 0; t < 8; t++)
                qt[t] = *(const uchar4*)(hf8 + (size_t)sjt[t] * HID1 + lane * 4);
            #pragma unroll
            for (int t = 0; t < 8; t++) {
                acc0 += At[t] * f8tof(qt[t].x);
                acc1 += At[t] * f8tof(qt[t].y);
                acc2 += At[t] * f8tof(qt[t].z);
                acc3 += At[t] * f8tof(qt[t].w);
            }
        }
    }
}

__global__ __launch_bounds__(256) void gat1_kernel(const int* __restrict__ row_ptr,
                                                   const int* __restrict__ eidx,
                                                   const int* __restrict__ srcs,
                                                   const float* __restrict__ a_s,
                                                   const float* __restrict__ a_d,
                                                   const unsigned char* __restrict__ h1f8,
                                                   const float* __restrict__ b1,
                                                   float* __restrict__ alpha1_out,
                                                   __hip_bfloat16* __restrict__ x1bf) {
    int wv = threadIdx.x >> 6, lane = threadIdx.x & 63;
    int n = blockIdx.x * 4 + wv;
    if (n >= NN) return;
    int start = row_ptr[n], end = row_ptr[n + 1];
    int cnt = end - start;
    int h = lane & 7, j = lane >> 3;
    int hl = lane >> 3;
    float acc0 = 0.f, acc1 = 0.f, acc2 = 0.f, acc3 = 0.f;
    if (cnt > 0 && cnt <= 64) {
        float ad = a_d[(size_t)n * 8 + h];
        if (cnt <= 8)
            gat1_fast<1>(lane, start, cnt, srcs, eidx, a_s, ad, h1f8, alpha1_out, acc0, acc1, acc2, acc3);
        else if (cnt <= 16)
            gat1_fast<2>(lane, start, cnt, srcs, eidx, a_s, ad, h1f8, alpha1_out, acc0, acc1, acc2, acc3);
        else if (cnt <= 24)
            gat1_fast<3>(lane, start, cnt, srcs, eidx, a_s, ad, h1f8, alpha1_out, acc0, acc1, acc2, acc3);
        else if (cnt <= 32)
            gat1_fast<4>(lane, start, cnt, srcs, eidx, a_s, ad, h1f8, alpha1_out, acc0, acc1, acc2, acc3);
        else
            gat1_fast<8>(lane, start, cnt, srcs, eidx, a_s, ad, h1f8, alpha1_out, acc0, acc1, acc2, acc3);
    } else if (cnt > 64) {
        float ad = a_d[(size_t)n * 8 + h];
        float m = -INFINITY;
        for (int p = start + j; p < end; p += 8) {
            float v = a_s[(size_t)srcs[p] * 8 + h] + ad;
            v = (v >= 0.f) ? v : NEG_SLOPE * v;
            m = fmaxf(m, v);
        }
        m = fmaxf(m, __shfl_xor(m, 8));
        m = fmaxf(m, __shfl_xor(m, 16));
        m = fmaxf(m, __shfl_xor(m, 32));
        float s = 0.f;
        for (int p = start + j; p < end; p += 8) {
            float v = a_s[(size_t)srcs[p] * 8 + h] + ad;
            v = (v >= 0.f) ? v : NEG_SLOPE * v;
            s += expf(v - m);
        }
        s += __shfl_xor(s, 8);
        s += __shfl_xor(s, 16);
        s += __shfl_xor(s, 32);
        float inv = 1.f / (s + 1e-16f);
        for (int p = start + j; p < end; p += 8) {
            float v = a_s[(size_t)srcs[p] * 8 + h] + ad;
            v = (v >= 0.f) ? v : NEG_SLOPE * v;
            alpha1_out[(size_t)eidx[p] * 8 + h] = expf(v - m) * inv;
        }
        float mh = __shfl(m, hl);
        float invh = __shfl(inv, hl);
        float adh = __shfl(ad, hl);
        for (int p = start; p < end; p++) {
            int sp = srcs[p];
            float v = a_s[(size_t)sp * 8 + hl] + adh;
            v = (v >= 0.f) ? v : NEG_SLOPE * v;
            float al = expf(v - mh) * invh;
            uchar4 q = *(const uchar4*)(h1f8 + (size_t)sp * HID1 + lane * 4);
            acc0 += al * f8tof(q.x);
            acc1 += al * f8tof(q.y);
            acc2 += al * f8tof(q.z);
            acc3 += al * f8tof(q.w);
        }
    }
    float4 bb = *(const float4*)(b1 + lane * 4);
    float r0 = acc0 + bb.x, r1 = acc1 + bb.y, r2 = acc2 + bb.z, r3 = acc3 + bb.w;
    r0 = (r0 > 0.f) ? r0 : expf(r0) - 1.f;
    r1 = (r1 > 0.f) ? r1 : expf(r1) - 1.f;
    r2 = (r2 > 0.f) ? r2 : expf(r2) - 1.f;
    r3 = (r3 > 0.f) ? r3 : expf(r3) - 1.f;
    ushort4 o;
    o.x = f2bf(r0); o.y = f2bf(r1); o.z = f2bf(r2); o.w = f2bf(r3);
    *(ushort4*)((unsigned short*)x1bf + (size_t)n * HID1 + lane * 4) = o;
}

// ---------------- layer 2 attention logits (1 head, bf16 input) ----------------

__global__ __launch_bounds__(64) void att2_kernel(const __hip_bfloat16* __restrict__ h2bf,
                                                  const float* __restrict__ att_src,
                                                  const float* __restrict__ att_dst,
                                                  float* __restrict__ a_s, float* __restrict__ a_d) {
    int n = blockIdx.x;
    int lane = threadIdx.x;
    const unsigned short* row = (const unsigned short*)h2bf + (size_t)n * HID2;
    unsigned int v = *(const unsigned int*)(row + lane * 2);
    float lo = __uint_as_float(v << 16);
    float hi = __uint_as_float(v & 0xffff0000u);
    float s = lo * att_src[lane * 2] + hi * att_src[lane * 2 + 1];
    float d = lo * att_dst[lane * 2] + hi * att_dst[lane * 2 + 1];
    for (int off = 32; off; off >>= 1) {
        s += __shfl_down(s, off);
        d += __shfl_down(d, off);
    }
    if (lane == 0) {
        a_s[n] = s;
        a_d[n] = d;
    }
}

// ---------------- fused layer-2 softmax + aggregation (wave per node) ----------------

__global__ __launch_bounds__(256) void gat2_kernel(const int* __restrict__ row_ptr,
                                                   const int* __restrict__ eidx,
                                                   const int* __restrict__ srcs,
                                                   const float* __restrict__ a_s,
                                                   const float* __restrict__ a_d,
                                                   const __hip_bfloat16* __restrict__ h2bf,
                                                   const float* __restrict__ b2,
                                                   float* __restrict__ alpha2_out,
                                                   __hip_bfloat16* __restrict__ x2bf) {
    int wv = threadIdx.x >> 6, lane = threadIdx.x & 63;
    int n = blockIdx.x * 4 + wv;
    if (n >= NN) return;
    int start = row_ptr[n], end = row_ptr[n + 1];
    int cnt = end - start;
    int r = lane >> 5, c = lane & 31;
    const unsigned short* hb = (const unsigned short*)h2bf;
    float acc0 = 0.f, acc1 = 0.f, acc2 = 0.f, acc3 = 0.f;
    if (cnt > 0 && cnt <= 64) {
        float ad = a_d[n];
        bool act = lane < cnt;
        int ii = min(lane, cnt - 1);
        int sj = srcs[start + ii];
        float v = a_s[sj] + ad;
        v = (v >= 0.f) ? v : NEG_SLOPE * v;
        float e = act ? v : -INFINITY;
        float m = e;
        #pragma unroll
        for (int off = 1; off < 64; off <<= 1) m = fmaxf(m, __shfl_xor(m, off));
        float ex = expf(e - m);
        float s = ex;
        #pragma unroll
        for (int off = 1; off < 64; off <<= 1) s += __shfl_xor(s, off);
        float al = ex / (s + 1e-16f);
        if (act) alpha2_out[eidx[start + lane]] = al;
        int rounds = (cnt + 7) >> 3;
        #pragma unroll
        for (int K = 0; K < 8; K++) {
            if (K < rounds) {
                int sjt[4];
                float At[4];
                ushort4 qt[4];
                #pragma unroll
                for (int t = 0; t < 4; t++) {
                    int je = K * 8 + t * 2 + r;
                    sjt[t] = __shfl(sj, je);
                    At[t] = __shfl(al, je);
                }
                #pragma unroll
                for (int t = 0; t < 4; t++)
                    qt[t] = *(const ushort4*)(hb + (size_t)sjt[t] * HID2 + c * 4);
                #pragma unroll
                for (int t = 0; t < 4; t++) {
                    acc0 += At[t] * bf2f(qt[t].x);
                    acc1 += At[t] * bf2f(qt[t].y);
                    acc2 += At[t] * bf2f(qt[t].z);
                    acc3 += At[t] * bf2f(qt[t].w);
                }
            }
        }
    } else if (cnt > 64) {
        float ad = a_d[n];
        float m = -INFINITY;
        for (int p = start + lane; p < end; p += 64) {
            float v = a_s[srcs[p]] + ad;
            v = (v >= 0.f) ? v : NEG_SLOPE * v;
            m = fmaxf(m, v);
        }
        for (int off = 32; off; off >>= 1) m = fmaxf(m, __shfl_xor(m, off));
        float s = 0.f;
        for (int p = start + lane; p < end; p += 64) {
            float v = a_s[srcs[p]] + ad;
            v = (v >= 0.f) ? v : NEG_SLOPE * v;
            s += expf(v - m);
        }
        for (int off = 32; off; off >>= 1) s += __shfl_xor(s, off);
        float inv = 1.f / (s + 1e-16f);
        for (int p = start + lane; p < end; p += 64) {
            float v = a_s[srcs[p]] + ad;
            v = (v >= 0.f) ? v : NEG_SLOPE * v;
            alpha2_out[eidx[p]] = expf(v - m) * inv;
        }
        for (int p = start + r; p < end; p += 2) {
            int sp = srcs[p];
            float v = a_s[sp] + ad;
            v = (v >= 0.f) ? v : NEG_SLOPE * v;
            float al = expf(v - m) * inv;
            ushort4 q = *(const ushort4*)(hb + (size_t)sp * HID2 + c * 4);
            acc0 += al * bf2f(q.x);
            acc1 += al * bf2f(q.y);
            acc2 += al * bf2f(q.z);
            acc3 += al * bf2f(q.w);
        }
    }
    acc0 += __shfl_xor(acc0, 32);
    acc1 += __shfl_xor(acc1, 32);
    acc2 += __shfl_xor(acc2, 32);
    acc3 += __shfl_xor(acc3, 32);
    if (r == 0) {
        float4 bb = *(const float4*)(b2 + c * 4);
        float r0 = acc0 + bb.x, r1 = acc1 + bb.y, r2 = acc2 + bb.z, r3 = acc3 + bb.w;
        r0 = (r0 > 0.f) ? r0 : 0.f;
        r1 = (r1 > 0.f) ? r1 : 0.f;
        r2 = (r2 > 0.f) ? r2 : 0.f;
        r3 = (r3 > 0.f) ? r3 : 0.f;
        ushort4 o;
        o.x = f2bf(r0); o.y = f2bf(r1); o.z = f2bf(r2); o.w = f2bf(r3);
        *(ushort4*)((unsigned short*)x2bf + (size_t)n * HID2 + c * 4) = o;
    }
}

// ---------------- host launch ----------------

extern "C" void kernel_launch(void* const* d_in, const int* in_sizes, int n_in,
                              void* d_out, int out_size, void* d_ws, size_t ws_size,
                              hipStream_t stream) {
    (void)in_sizes; (void)n_in; (void)out_size; (void)ws_size;
    const float* x        = (const float*)d_in[0];
    const int*   eindex   = (const int*)d_in[1];
    const float* W1       = (const float*)d_in[2];
    const float* att_src1 = (const float*)d_in[3];
    const float* att_dst1 = (const float*)d_in[4];
    const float* b1       = (const float*)d_in[5];
    const float* W2       = (const float*)d_in[6];
    const float* att_src2 = (const float*)d_in[7];
    const float* att_dst2 = (const float*)d_in[8];
    const float* b2       = (const float*)d_in[9];
    const float* fcW1     = (const float*)d_in[10];
    const float* fcb1     = (const float*)d_in[11];
    const float* fcW2     = (const float*)d_in[12];
    const float* fcb2     = (const float*)d_in[13];

    const int* src = eindex;
    const int* dst = eindex + EE;

    float* out_n      = (float*)d_out;               // [N]
    float* alpha1_out = out_n + NN;                  // [E,8]
    float* alpha2_out = alpha1_out + (size_t)EE * 8; // [E]

    char* ws = (char*)d_ws;
    size_t off = 0;
    auto alloc = [&](size_t bytes) {
        size_t o = off;
        off = (off + bytes + 255) & ~(size_t)255;
        return o;
    };
    size_t o_rowptr = alloc((NN + 1) * sizeof(int));
    size_t o_cursor = alloc(NN * sizeof(int));
    size_t o_counts = alloc(NN * sizeof(int));
    size_t o_excl   = alloc(NN * sizeof(int));
    size_t o_bsum   = alloc(64 * sizeof(int));
    size_t o_eidx   = alloc(EE * sizeof(int));
    size_t o_srcs   = alloc(EE * sizeof(int));
    size_t o_as1    = alloc((size_t)NN * H1 * sizeof(float));
    size_t o_ad1    = alloc((size_t)NN * H1 * sizeof(float));
    size_t o_h1bf   = alloc((size_t)NN * HID1 * sizeof(__hip_bfloat16));
    size_t o_h1f8   = alloc((size_t)NN * HID1);
    size_t o_xbf    = alloc((size_t)NN * IN_DIM * sizeof(__hip_bfloat16));
    size_t o_x1bf   = alloc((size_t)NN * HID1 * sizeof(__hip_bfloat16));
    size_t o_h2bf   = alloc((size_t)NN * HID2 * sizeof(__hip_bfloat16));
    size_t o_x2bf   = alloc((size_t)NN * HID2 * sizeof(__hip_bfloat16));
    size_t o_W1p    = alloc((size_t)IN_DIM * HID1 * sizeof(__hip_bfloat16));
    size_t o_W2p    = alloc((size_t)HID1 * HID2 * sizeof(__hip_bfloat16));
    size_t o_fW1p   = alloc((size_t)HID2 * FC1 * sizeof(__hip_bfloat16));

    int*   row_ptr = (int*)(ws + o_rowptr);
    int*   cursor  = (int*)(ws + o_cursor);
    int*   counts  = (int*)(ws + o_counts);
    int*   excl    = (int*)(ws + o_excl);
    int*   bsum    = (int*)(ws + o_bsum);
    int*   eidx    = (int*)(ws + o_eidx);
    int*   srcs    = (int*)(ws + o_srcs);
    float* a_s1    = (float*)(ws + o_as1);
    float* a_d1    = (float*)(ws + o_ad1);
    __hip_bfloat16* h1bf  = (__hip_bfloat16*)(ws + o_h1bf);
    unsigned char*  h1f8  = (unsigned char*)(ws + o_h1f8);
    __hip_bfloat16* xbf   = (__hip_bfloat16*)(ws + o_xbf);
    __hip_bfloat16* x1bf  = (__hip_bfloat16*)(ws + o_x1bf);
    __hip_bfloat16* h2bf  = (__hip_bfloat16*)(ws + o_h2bf);
    __hip_bfloat16* x2bf  = (__hip_bfloat16*)(ws + o_x2bf);
    __hip_bfloat16* W1p   = (__hip_bfloat16*)(ws + o_W1p);
    __hip_bfloat16* W2p   = (__hip_bfloat16*)(ws + o_W2p);
    __hip_bfloat16* fW1p  = (__hip_bfloat16*)(ws + o_fW1p);
    // layer-2 aliases
    float* a_s2 = a_s1;
    float* a_d2 = a_d1;

    const int SCAN_NB = (NN + 1023) / 1024;  // 49

    // ---- build CSR by dst ----
    fill_zero_int<<<(NN + 255) / 256, 256, 0, stream>>>(counts, NN);
    hist_kernel<<<(EE + 255) / 256, 256, 0, stream>>>(dst, counts);
    scan_a_kernel<<<SCAN_NB, 256, 0, stream>>>(counts, excl, bsum, NN);
    scan_b_kernel<<<1, 64, 0, stream>>>(bsum, row_ptr, SCAN_NB, NN);
    scan_c_kernel<<<SCAN_NB, 256, 0, stream>>>(excl, bsum, row_ptr, cursor, NN);
    scatter_kernel<<<(EE + 255) / 256, 256, 0, stream>>>(src, dst, cursor, eidx, srcs);

    // ---- input conversions / weight packing ----
    cvt_bf16_kernel<<<(NN * IN_DIM + 255) / 256, 256, 0, stream>>>(x, xbf, NN * IN_DIM);
    pack_kernel<<<(IN_DIM * HID1 + 255) / 256, 256, 0, stream>>>(W1, W1p, IN_DIM, HID1);
    pack_kernel<<<(HID1 * HID2 + 255) / 256, 256, 0, stream>>>(W2, W2p, HID1, HID2);
    pack_kernel<<<(HID2 * FC1 + 255) / 256, 256, 0, stream>>>(fcW1, fW1p, HID2, FC1);

    // ---- layer 1 ----
    mgemm_kernel<<<dim3((NN + 127) / 128, HID1 / 64), 256, 0, stream>>>(
        xbf, W1p, h1bf, h1f8, NN, IN_DIM, HID1);
    att1_kernel<<<(NN * H1 + 255) / 256, 256, 0, stream>>>(h1bf, att_src1, att_dst1, a_s1, a_d1);
    gat1_kernel<<<(NN + 3) / 4, 256, 0, stream>>>(row_ptr, eidx, srcs, a_s1, a_d1,
                                                  h1f8, b1, alpha1_out, x1bf);

    // ---- layer 2 ----
    mgemm_kernel<<<dim3((NN + 127) / 128, HID2 / 64), 256, 0, stream>>>(
        x1bf, W2p, h2bf, nullptr, NN, HID1, HID2);
    att2_kernel<<<NN, 64, 0, stream>>>(h2bf, att_src2, att_dst2, a_s2, a_d2);
    gat2_kernel<<<(NN + 3) / 4, 256, 0, stream>>>(row_ptr, eidx, srcs, a_s2, a_d2,
                                                  h2bf, b2, alpha2_out, x2bf);

    // ---- FC head ----
    fc_mfma_kernel<<<(NN + 31) / 32, 256, 0, stream>>>(x2bf, fW1p, fcb1, fcW2, fcb2, out_n);
}

// Round 11
// 293.758 us; speedup vs baseline: 1.5059x; 1.0487x over previous
//
#include <hip/hip_runtime.h>
#include <hip/hip_bf16.h>
#include <hip/hip_fp8.h>
#include <math.h>

#define NN 50000
#define EE 800000
#define IN_DIM 128
#define H1 8
#define D1 32
#define HID1 256
#define HID2 128
#define FC1 512
#define NEG_SLOPE 0.2f

typedef short v8s __attribute__((ext_vector_type(8)));
typedef float v4f __attribute__((ext_vector_type(4)));
typedef unsigned int v4u __attribute__((ext_vector_type(4)));

__device__ __forceinline__ float bf2f(unsigned short u) {
    unsigned int x = ((unsigned int)u) << 16;
    return __uint_as_float(x);
}
__device__ __forceinline__ unsigned short f2bf(float v) {
    __hip_bfloat16 h = __float2bfloat16(v);
    return *(unsigned short*)&h;
}
__device__ __forceinline__ unsigned char f2f8(float v) {
    __hip_fp8_e4m3 t(v);
    return (unsigned char)t.__x;
}
__device__ __forceinline__ float f8tof(unsigned char u) {
    __hip_fp8_e4m3 t;
    t.__x = (__hip_fp8_storage_t)u;
    return (float)t;
}

// ---------------- utility kernels ----------------

__global__ void fill_zero_int(int* p, int n) {
    int i = blockIdx.x * blockDim.x + threadIdx.x;
    if (i < n) p[i] = 0;
}

__global__ void hist_kernel(const int* __restrict__ dst, int* __restrict__ counts) {
    int e = blockIdx.x * blockDim.x + threadIdx.x;
    if (e < EE) atomicAdd(&counts[dst[e]], 1);
}

// ---- hierarchical exclusive scan ----

__global__ __launch_bounds__(256) void scan_a_kernel(const int* __restrict__ counts,
                                                     int* __restrict__ excl,
                                                     int* __restrict__ bsum, int n) {
    __shared__ int wsum[4];
    int tid = threadIdx.x;
    int base = blockIdx.x * 1024 + tid * 4;
    int v0 = 0, v1 = 0, v2 = 0, v3 = 0;
    if (base + 3 < n) {
        int4 t = *(const int4*)(counts + base);
        v0 = t.x; v1 = t.y; v2 = t.z; v3 = t.w;
    } else {
        if (base + 0 < n) v0 = counts[base + 0];
        if (base + 1 < n) v1 = counts[base + 1];
        if (base + 2 < n) v2 = counts[base + 2];
        if (base + 3 < n) v3 = counts[base + 3];
    }
    int tot = v0 + v1 + v2 + v3;
    int lane = tid & 63;
    int w = tid >> 6;
    int x = tot;
    #pragma unroll
    for (int off = 1; off < 64; off <<= 1) {
        int y = __shfl_up(x, off);
        if (lane >= off) x += y;
    }
    if (lane == 63) wsum[w] = x;
    __syncthreads();
    int woff = 0;
    for (int i = 0; i < w; i++) woff += wsum[i];
    int et = woff + x - tot;
    if (base + 0 < n) excl[base + 0] = et;
    if (base + 1 < n) excl[base + 1] = et + v0;
    if (base + 2 < n) excl[base + 2] = et + v0 + v1;
    if (base + 3 < n) excl[base + 3] = et + v0 + v1 + v2;
    if (tid == 255) bsum[blockIdx.x] = woff + x;
}

__global__ __launch_bounds__(64) void scan_b_kernel(int* __restrict__ bsum,
                                                    int* __restrict__ row_ptr, int nb, int n) {
    int lane = threadIdx.x;
    int v = (lane < nb) ? bsum[lane] : 0;
    int x = v;
    #pragma unroll
    for (int off = 1; off < 64; off <<= 1) {
        int y = __shfl_up(x, off);
        if (lane >= off) x += y;
    }
    if (lane < nb) bsum[lane] = x - v;
    if (lane == 63) row_ptr[n] = x;
}

__global__ __launch_bounds__(256) void scan_c_kernel(const int* __restrict__ excl,
                                                     const int* __restrict__ bsum,
                                                     int* __restrict__ row_ptr,
                                                     int* __restrict__ cursor, int n) {
    int base = blockIdx.x * 1024 + threadIdx.x * 4;
    int off = bsum[blockIdx.x];
    #pragma unroll
    for (int j = 0; j < 4; j++) {
        int i = base + j;
        if (i < n) {
            int r = excl[i] + off;
            row_ptr[i] = r;
            cursor[i] = r;
        }
    }
}

__global__ void scatter_kernel(const int* __restrict__ src, const int* __restrict__ dst,
                               int* __restrict__ cursor, int* __restrict__ eidx,
                               int* __restrict__ srcs) {
    int e = blockIdx.x * blockDim.x + threadIdx.x;
    if (e >= EE) return;
    int d = dst[e];
    int p = atomicAdd(&cursor[d], 1);
    eidx[p] = e;
    srcs[p] = src[e];
}

// ---- fused prep: x->bf16 + pack W1/W2/fcW1 into MFMA fragment-major bf16 ----

__device__ __forceinline__ void pack_one(const float* __restrict__ B,
                                         __hip_bfloat16* __restrict__ Bp,
                                         int K, int N, int idx) {
    int k = idx / N, n = idx % N;
    int ntile = n >> 4, ks = k >> 5, kk = k & 31;
    int lane = (n & 15) | ((kk >> 3) << 4);
    int j = kk & 7;
    int KS = K >> 5;
    Bp[((size_t)(ntile * KS + ks) * 64 + lane) * 8 + j] = __float2bfloat16(B[idx]);
}

__global__ void prep_kernel(const float* __restrict__ x, __hip_bfloat16* __restrict__ xbf,
                            const float* __restrict__ W1, __hip_bfloat16* __restrict__ W1p,
                            const float* __restrict__ W2, __hip_bfloat16* __restrict__ W2p,
                            const float* __restrict__ fcW1, __hip_bfloat16* __restrict__ fW1p) {
    int i = blockIdx.x * blockDim.x + threadIdx.x;
    const int N0 = NN * IN_DIM;
    const int N1 = N0 + IN_DIM * HID1;
    const int N2 = N1 + HID1 * HID2;
    const int N3 = N2 + HID2 * FC1;
    if (i < N0) xbf[i] = __float2bfloat16(x[i]);
    else if (i < N1) pack_one(W1, W1p, IN_DIM, HID1, i - N0);
    else if (i < N2) pack_one(W2, W2p, HID1, HID2, i - N1);
    else if (i < N3) pack_one(fcW1, fW1p, HID2, FC1, i - N2);
}

// ---------------- MFMA GEMM (bf16 in, bf16 out, optional fp8 copy) ----------------

__global__ __launch_bounds__(256) void mgemm_kernel(const __hip_bfloat16* __restrict__ A,
                                                    const __hip_bfloat16* __restrict__ Bp,
                                                    __hip_bfloat16* __restrict__ Cbf,
                                                    unsigned char* __restrict__ Cf8,
                                                    int M, int K, int N) {
    int w = threadIdx.x >> 6, l = threadIdx.x & 63;
    int bm = blockIdx.x * 128 + w * 32;
    int bn = blockIdx.y * 64;
    int lr = l & 15, lk = l >> 4;
    int KS = K >> 5;
    const short* Ab = (const short*)A;
    const short* Bb = (const short*)Bp;
    v4f acc[2][4];
    #pragma unroll
    for (int mi = 0; mi < 2; mi++)
        #pragma unroll
        for (int nt = 0; nt < 4; nt++) acc[mi][nt] = (v4f)(0.f);
    for (int ks = 0; ks < KS; ks++) {
        v8s a[2];
        #pragma unroll
        for (int mi = 0; mi < 2; mi++) {
            int gm = bm + mi * 16 + lr;
            a[mi] = (gm < M) ? *(const v8s*)(Ab + (size_t)gm * K + ks * 32 + lk * 8)
                             : (v8s)(short)0;
        }
        #pragma unroll
        for (int nt = 0; nt < 4; nt++) {
            int ntile = (bn >> 4) + nt;
            v8s b = *(const v8s*)(Bb + ((size_t)(ntile * KS + ks) * 64 + l) * 8);
            acc[0][nt] = __builtin_amdgcn_mfma_f32_16x16x32_bf16(a[0], b, acc[0][nt], 0, 0, 0);
            acc[1][nt] = __builtin_amdgcn_mfma_f32_16x16x32_bf16(a[1], b, acc[1][nt], 0, 0, 0);
        }
    }
    #pragma unroll
    for (int mi = 0; mi < 2; mi++) {
        #pragma unroll
        for (int nt = 0; nt < 4; nt++) {
            int gn = bn + nt * 16 + lr;
            #pragma unroll
            for (int j = 0; j < 4; j++) {
                int gm = bm + mi * 16 + lk * 4 + j;
                if (gm < M) {
                    float v = acc[mi][nt][j];
                    Cbf[(size_t)gm * N + gn] = __float2bfloat16(v);
                    if (Cf8) Cf8[(size_t)gm * N + gn] = f2f8(v);
                }
            }
        }
    }
}

// ---------------- fused FC head via MFMA ----------------

__global__ __launch_bounds__(256) void fc_mfma_kernel(const __hip_bfloat16* __restrict__ A,
                                                      const __hip_bfloat16* __restrict__ Bp,
                                                      const float* __restrict__ fcb1,
                                                      const float* __restrict__ fcW2,
                                                      const float* __restrict__ fcb2,
                                                      float* __restrict__ out) {
    __shared__ float red[4][32];
    int w = threadIdx.x >> 6, l = threadIdx.x & 63;
    int bm = blockIdx.x * 32;
    int lr = l & 15, lk = l >> 4;
    const int K = HID2, KS = K >> 5;
    const short* Ab = (const short*)A;
    const short* Bb = (const short*)Bp;
    v4f acc[2][8];
    #pragma unroll
    for (int mi = 0; mi < 2; mi++)
        #pragma unroll
        for (int nt = 0; nt < 8; nt++) acc[mi][nt] = (v4f)(0.f);
    for (int ks = 0; ks < KS; ks++) {
        v8s a[2];
        #pragma unroll
        for (int mi = 0; mi < 2; mi++) {
            int gm = bm + mi * 16 + lr;
            a[mi] = (gm < NN) ? *(const v8s*)(Ab + (size_t)gm * K + ks * 32 + lk * 8)
                              : (v8s)(short)0;
        }
        #pragma unroll
        for (int nt = 0; nt < 8; nt++) {
            int ntile = w * 8 + nt;
            v8s b = *(const v8s*)(Bb + ((size_t)(ntile * KS + ks) * 64 + l) * 8);
            acc[0][nt] = __builtin_amdgcn_mfma_f32_16x16x32_bf16(a[0], b, acc[0][nt], 0, 0, 0);
            acc[1][nt] = __builtin_amdgcn_mfma_f32_16x16x32_bf16(a[1], b, acc[1][nt], 0, 0, 0);
        }
    }
    float p[2][4];
    #pragma unroll
    for (int mi = 0; mi < 2; mi++)
        #pragma unroll
        for (int j = 0; j < 4; j++) p[mi][j] = 0.f;
    #pragma unroll
    for (int nt = 0; nt < 8; nt++) {
        int col = w * 128 + nt * 16 + lr;
        float b1v = fcb1[col], w2v = fcW2[col];
        #pragma unroll
        for (int mi = 0; mi < 2; mi++) {
            #pragma unroll
            for (int j = 0; j < 4; j++) {
                float v = acc[mi][nt][j] + b1v;
                p[mi][j] += ((v > 0.f) ? v : 0.f) * w2v;
            }
        }
    }
    #pragma unroll
    for (int mi = 0; mi < 2; mi++)
        #pragma unroll
        for (int j = 0; j < 4; j++) {
            float v = p[mi][j];
            v += __shfl_xor(v, 1);
            v += __shfl_xor(v, 2);
            v += __shfl_xor(v, 4);
            v += __shfl_xor(v, 8);
            p[mi][j] = v;
        }
    if (lr == 0) {
        #pragma unroll
        for (int mi = 0; mi < 2; mi++)
            #pragma unroll
            for (int j = 0; j < 4; j++) red[w][mi * 16 + lk * 4 + j] = p[mi][j];
    }
    __syncthreads();
    int tid = threadIdx.x;
    if (tid < 32) {
        int gm = bm + tid;
        if (gm < NN)
            out[gm] = red[0][tid] + red[1][tid] + red[2][tid] + red[3][tid] + fcb2[0];
    }
}

// ---------------- layer 1 attention logits (bf16 input) ----------------

__global__ void att1_kernel(const __hip_bfloat16* __restrict__ h1bf,
                            const float* __restrict__ att_src,
                            const float* __restrict__ att_dst, float* __restrict__ a_s,
                            float* __restrict__ a_d) {
    int idx = blockIdx.x * blockDim.x + threadIdx.x;
    if (idx >= NN * H1) return;
    int n = idx >> 3, h = idx & 7;
    const v4u* row = (const v4u*)((const unsigned short*)h1bf + (size_t)n * HID1 + h * D1);
    float s = 0.f, d = 0.f;
    #pragma unroll
    for (int q = 0; q < 4; q++) {
        v4u v = row[q];
        #pragma unroll
        for (int k = 0; k < 4; k++) {
            float lo = __uint_as_float(v[k] << 16);
            float hi = __uint_as_float(v[k] & 0xffff0000u);
            int kk = q * 8 + k * 2;
            s += lo * att_src[h * D1 + kk] + hi * att_src[h * D1 + kk + 1];
            d += lo * att_dst[h * D1 + kk] + hi * att_dst[h * D1 + kk + 1];
        }
    }
    a_s[idx] = s;
    a_d[idx] = d;
}

// ---------------- fused layer-1 softmax + aggregation, degree-bucketed, fp8 gather ----
// packed shuffle: word = (src<<16) | bf16(alpha) — one shfl feeds both agg operands.

template <int KM>
__device__ __forceinline__ void gat1_fast(int lane, int start, int cnt,
                                          const int* __restrict__ srcs,
                                          const int* __restrict__ eidx,
                                          const float* __restrict__ a_s, float ad,
                                          const unsigned char* __restrict__ hf8,
                                          float* __restrict__ alpha1_out,
                                          float& acc0, float& acc1, float& acc2, float& acc3) {
    int h = lane & 7, j = lane >> 3;
    int hl = lane >> 3;
    int cl = min(lane, cnt - 1);
    int s_all = srcs[start + cl];
    int e_all = eidx[start + cl];
    float ex[KM];
    int sj[KM];
    #pragma unroll
    for (int k = 0; k < KM; k++) {
        int idx = j + k * 8;
        sj[k] = __shfl(s_all, idx);
        float v = a_s[(size_t)sj[k] * 8 + h] + ad;
        v = (v >= 0.f) ? v : NEG_SLOPE * v;
        ex[k] = (idx < cnt) ? v : -INFINITY;
    }
    float m = ex[0];
    #pragma unroll
    for (int k = 1; k < KM; k++) m = fmaxf(m, ex[k]);
    m = fmaxf(m, __shfl_xor(m, 8));
    m = fmaxf(m, __shfl_xor(m, 16));
    m = fmaxf(m, __shfl_xor(m, 32));
    float s = 0.f;
    #pragma unroll
    for (int k = 0; k < KM; k++) {
        ex[k] = expf(ex[k] - m);
        s += ex[k];
    }
    s += __shfl_xor(s, 8);
    s += __shfl_xor(s, 16);
    s += __shfl_xor(s, 32);
    float inv = 1.f / (s + 1e-16f);
    #pragma unroll
    for (int k = 0; k < KM; k++) ex[k] *= inv;
    #pragma unroll
    for (int k = 0; k < KM; k++) {
        int idx = j + k * 8;
        int eo = __shfl(e_all, idx);
        if (idx < cnt) alpha1_out[(size_t)eo * 8 + h] = ex[k];
    }
    // pack src + bf16(alpha) for single-shfl broadcast
    unsigned int pk[KM];
    #pragma unroll
    for (int k = 0; k < KM; k++)
        pk[k] = ((unsigned int)sj[k] << 16) | (unsigned int)f2bf(ex[k]);
    int rounds = (cnt + 7) >> 3;
    #pragma unroll
    for (int K = 0; K < KM; K++) {
        if (K < rounds) {
            int sjt[8];
            float At[8];
            uchar4 qt[8];
            #pragma unroll
            for (int t = 0; t < 8; t++) {
                unsigned int wv = (unsigned int)__shfl((int)pk[K], t * 8 + hl);
                sjt[t] = (int)(wv >> 16);
                At[t] = bf2f((unsigned short)wv);
            }
            #pragma unroll
            for (int t = 0; t < 8; t++)
                qt[t] = *(const uchar4*)(hf8 + (size_t)sjt[t] * HID1 + lane * 4);
            #pragma unroll
            for (int t = 0; t < 8; t++) {
                acc0 += At[t] * f8tof(qt[t].x);
                acc1 += At[t] * f8tof(qt[t].y);
                acc2 += At[t] * f8tof(qt[t].z);
                acc3 += At[t] * f8tof(qt[t].w);
            }
        }
    }
}

__global__ __launch_bounds__(256) void gat1_kernel(const int* __restrict__ row_ptr,
                                                   const int* __restrict__ eidx,
                                                   const int* __restrict__ srcs,
                                                   const float* __restrict__ a_s,
                                                   const float* __restrict__ a_d,
                                                   const unsigned char* __restrict__ h1f8,
                                                   const float* __restrict__ b1,
                                                   float* __restrict__ alpha1_out,
                                                   __hip_bfloat16* __restrict__ x1bf) {
    int wv = threadIdx.x >> 6, lane = threadIdx.x & 63;
    int n = blockIdx.x * 4 + wv;
    if (n >= NN) return;
    int start = row_ptr[n], end = row_ptr[n + 1];
    int cnt = end - start;
    int h = lane & 7, j = lane >> 3;
    int hl = lane >> 3;
    float acc0 = 0.f, acc1 = 0.f, acc2 = 0.f, acc3 = 0.f;
    if (cnt > 0 && cnt <= 64) {
        float ad = a_d[(size_t)n * 8 + h];
        if (cnt <= 8)
            gat1_fast<1>(lane, start, cnt, srcs, eidx, a_s, ad, h1f8, alpha1_out, acc0, acc1, acc2, acc3);
        else if (cnt <= 16)
            gat1_fast<2>(lane, start, cnt, srcs, eidx, a_s, ad, h1f8, alpha1_out, acc0, acc1, acc2, acc3);
        else if (cnt <= 24)
            gat1_fast<3>(lane, start, cnt, srcs, eidx, a_s, ad, h1f8, alpha1_out, acc0, acc1, acc2, acc3);
        else if (cnt <= 32)
            gat1_fast<4>(lane, start, cnt, srcs, eidx, a_s, ad, h1f8, alpha1_out, acc0, acc1, acc2, acc3);
        else
            gat1_fast<8>(lane, start, cnt, srcs, eidx, a_s, ad, h1f8, alpha1_out, acc0, acc1, acc2, acc3);
    } else if (cnt > 64) {
        float ad = a_d[(size_t)n * 8 + h];
        float m = -INFINITY;
        for (int p = start + j; p < end; p += 8) {
            float v = a_s[(size_t)srcs[p] * 8 + h] + ad;
            v = (v >= 0.f) ? v : NEG_SLOPE * v;
            m = fmaxf(m, v);
        }
        m = fmaxf(m, __shfl_xor(m, 8));
        m = fmaxf(m, __shfl_xor(m, 16));
        m = fmaxf(m, __shfl_xor(m, 32));
        float s = 0.f;
        for (int p = start + j; p < end; p += 8) {
            float v = a_s[(size_t)srcs[p] * 8 + h] + ad;
            v = (v >= 0.f) ? v : NEG_SLOPE * v;
            s += expf(v - m);
        }
        s += __shfl_xor(s, 8);
        s += __shfl_xor(s, 16);
        s += __shfl_xor(s, 32);
        float inv = 1.f / (s + 1e-16f);
        for (int p = start + j; p < end; p += 8) {
            float v = a_s[(size_t)srcs[p] * 8 + h] + ad;
            v = (v >= 0.f) ? v : NEG_SLOPE * v;
            alpha1_out[(size_t)eidx[p] * 8 + h] = expf(v - m) * inv;
        }
        float mh = __shfl(m, hl);
        float invh = __shfl(inv, hl);
        float adh = __shfl(ad, hl);
        for (int p = start; p < end; p++) {
            int sp = srcs[p];
            float v = a_s[(size_t)sp * 8 + hl] + adh;
            v = (v >= 0.f) ? v : NEG_SLOPE * v;
            float al = expf(v - mh) * invh;
            uchar4 q = *(const uchar4*)(h1f8 + (size_t)sp * HID1 + lane * 4);
            acc0 += al * f8tof(q.x);
            acc1 += al * f8tof(q.y);
            acc2 += al * f8tof(q.z);
            acc3 += al * f8tof(q.w);
        }
    }
    float4 bb = *(const float4*)(b1 + lane * 4);
    float r0 = acc0 + bb.x, r1 = acc1 + bb.y, r2 = acc2 + bb.z, r3 = acc3 + bb.w;
    r0 = (r0 > 0.f) ? r0 : expf(r0) - 1.f;
    r1 = (r1 > 0.f) ? r1 : expf(r1) - 1.f;
    r2 = (r2 > 0.f) ? r2 : expf(r2) - 1.f;
    r3 = (r3 > 0.f) ? r3 : expf(r3) - 1.f;
    ushort4 o;
    o.x = f2bf(r0); o.y = f2bf(r1); o.z = f2bf(r2); o.w = f2bf(r3);
    *(ushort4*)((unsigned short*)x1bf + (size_t)n * HID1 + lane * 4) = o;
}

// ---------------- layer 2 attention logits (1 head, bf16 input) ----------------

__global__ __launch_bounds__(64) void att2_kernel(const __hip_bfloat16* __restrict__ h2bf,
                                                  const float* __restrict__ att_src,
                                                  const float* __restrict__ att_dst,
                                                  float* __restrict__ a_s, float* __restrict__ a_d) {
    int n = blockIdx.x;
    int lane = threadIdx.x;
    const unsigned short* row = (const unsigned short*)h2bf + (size_t)n * HID2;
    unsigned int v = *(const unsigned int*)(row + lane * 2);
    float lo = __uint_as_float(v << 16);
    float hi = __uint_as_float(v & 0xffff0000u);
    float s = lo * att_src[lane * 2] + hi * att_src[lane * 2 + 1];
    float d = lo * att_dst[lane * 2] + hi * att_dst[lane * 2 + 1];
    for (int off = 32; off; off >>= 1) {
        s += __shfl_down(s, off);
        d += __shfl_down(d, off);
    }
    if (lane == 0) {
        a_s[n] = s;
        a_d[n] = d;
    }
}

// ---------------- fused layer-2 softmax + aggregation (fp8 gather, packed shfl) ------

__global__ __launch_bounds__(256) void gat2_kernel(const int* __restrict__ row_ptr,
                                                   const int* __restrict__ eidx,
                                                   const int* __restrict__ srcs,
                                                   const float* __restrict__ a_s,
                                                   const float* __restrict__ a_d,
                                                   const unsigned char* __restrict__ h2f8,
                                                   const float* __restrict__ b2,
                                                   float* __restrict__ alpha2_out,
                                                   __hip_bfloat16* __restrict__ x2bf) {
    int wv = threadIdx.x >> 6, lane = threadIdx.x & 63;
    int n = blockIdx.x * 4 + wv;
    if (n >= NN) return;
    int start = row_ptr[n], end = row_ptr[n + 1];
    int cnt = end - start;
    int r = lane >> 5, c = lane & 31;
    float acc0 = 0.f, acc1 = 0.f, acc2 = 0.f, acc3 = 0.f;
    if (cnt > 0 && cnt <= 64) {
        float ad = a_d[n];
        bool act = lane < cnt;
        int ii = min(lane, cnt - 1);
        int sj = srcs[start + ii];
        float v = a_s[sj] + ad;
        v = (v >= 0.f) ? v : NEG_SLOPE * v;
        float e = act ? v : -INFINITY;
        float m = e;
        #pragma unroll
        for (int off = 1; off < 64; off <<= 1) m = fmaxf(m, __shfl_xor(m, off));
        float ex = expf(e - m);
        float s = ex;
        #pragma unroll
        for (int off = 1; off < 64; off <<= 1) s += __shfl_xor(s, off);
        float al = ex / (s + 1e-16f);
        if (act) alpha2_out[eidx[start + lane]] = al;
        unsigned int pk = ((unsigned int)sj << 16) | (unsigned int)f2bf(al);
        int rounds = (cnt + 7) >> 3;
        #pragma unroll
        for (int K = 0; K < 8; K++) {
            if (K < rounds) {
                int sjt[4];
                float At[4];
                uchar4 qt[4];
                #pragma unroll
                for (int t = 0; t < 4; t++) {
                    int je = K * 8 + t * 2 + r;
                    unsigned int wq = (unsigned int)__shfl((int)pk, je);
                    sjt[t] = (int)(wq >> 16);
                    At[t] = bf2f((unsigned short)wq);
                }
                #pragma unroll
                for (int t = 0; t < 4; t++)
                    qt[t] = *(const uchar4*)(h2f8 + (size_t)sjt[t] * HID2 + c * 4);
                #pragma unroll
                for (int t = 0; t < 4; t++) {
                    acc0 += At[t] * f8tof(qt[t].x);
                    acc1 += At[t] * f8tof(qt[t].y);
                    acc2 += At[t] * f8tof(qt[t].z);
                    acc3 += At[t] * f8tof(qt[t].w);
                }
            }
        }
    } else if (cnt > 64) {
        float ad = a_d[n];
        float m = -INFINITY;
        for (int p = start + lane; p < end; p += 64) {
            float v = a_s[srcs[p]] + ad;
            v = (v >= 0.f) ? v : NEG_SLOPE * v;
            m = fmaxf(m, v);
        }
        for (int off = 32; off; off >>= 1) m = fmaxf(m, __shfl_xor(m, off));
        float s = 0.f;
        for (int p = start + lane; p < end; p += 64) {
            float v = a_s[srcs[p]] + ad;
            v = (v >= 0.f) ? v : NEG_SLOPE * v;
            s += expf(v - m);
        }
        for (int off = 32; off; off >>= 1) s += __shfl_xor(s, off);
        float inv = 1.f / (s + 1e-16f);
        for (int p = start + lane; p < end; p += 64) {
            float v = a_s[srcs[p]] + ad;
            v = (v >= 0.f) ? v : NEG_SLOPE * v;
            alpha2_out[eidx[p]] = expf(v - m) * inv;
        }
        for (int p = start + r; p < end; p += 2) {
            int sp = srcs[p];
            float v = a_s[sp] + ad;
            v = (v >= 0.f) ? v : NEG_SLOPE * v;
            float al = expf(v - m) * inv;
            uchar4 q = *(const uchar4*)(h2f8 + (size_t)sp * HID2 + c * 4);
            acc0 += al * f8tof(q.x);
            acc1 += al * f8tof(q.y);
            acc2 += al * f8tof(q.z);
            acc3 += al * f8tof(q.w);
        }
    }
    acc0 += __shfl_xor(acc0, 32);
    acc1 += __shfl_xor(acc1, 32);
    acc2 += __shfl_xor(acc2, 32);
    acc3 += __shfl_xor(acc3, 32);
    if (r == 0) {
        float4 bb = *(const float4*)(b2 + c * 4);
        float r0 = acc0 + bb.x, r1 = acc1 + bb.y, r2 = acc2 + bb.z, r3 = acc3 + bb.w;
        r0 = (r0 > 0.f) ? r0 : 0.f;
        r1 = (r1 > 0.f) ? r1 : 0.f;
        r2 = (r2 > 0.f) ? r2 : 0.f;
        r3 = (r3 > 0.f) ? r3 : 0.f;
        ushort4 o;
        o.x = f2bf(r0); o.y = f2bf(r1); o.z = f2bf(r2); o.w = f2bf(r3);
        *(ushort4*)((unsigned short*)x2bf + (size_t)n * HID2 + c * 4) = o;
    }
}

// ---------------- host launch ----------------

extern "C" void kernel_launch(void* const* d_in, const int* in_sizes, int n_in,
                              void* d_out, int out_size, void* d_ws, size_t ws_size,
                              hipStream_t stream) {
    (void)in_sizes; (void)n_in; (void)out_size; (void)ws_size;
    const float* x        = (const float*)d_in[0];
    const int*   eindex   = (const int*)d_in[1];
    const float* W1       = (const float*)d_in[2];
    const float* att_src1 = (const float*)d_in[3];
    const float* att_dst1 = (const float*)d_in[4];
    const float* b1       = (const float*)d_in[5];
    const float* W2       = (const float*)d_in[6];
    const float* att_src2 = (const float*)d_in[7];
    const float* att_dst2 = (const float*)d_in[8];
    const float* b2       = (const float*)d_in[9];
    const float* fcW1     = (const float*)d_in[10];
    const float* fcb1     = (const float*)d_in[11];
    const float* fcW2     = (const float*)d_in[12];
    const float* fcb2     = (const float*)d_in[13];

    const int* src = eindex;
    const int* dst = eindex + EE;

    float* out_n      = (float*)d_out;               // [N]
    float* alpha1_out = out_n + NN;                  // [E,8]
    float* alpha2_out = alpha1_out + (size_t)EE * 8; // [E]

    char* ws = (char*)d_ws;
    size_t off = 0;
    auto alloc = [&](size_t bytes) {
        size_t o = off;
        off = (off + bytes + 255) & ~(size_t)255;
        return o;
    };
    size_t o_rowptr = alloc((NN + 1) * sizeof(int));
    size_t o_cursor = alloc(NN * sizeof(int));
    size_t o_counts = alloc(NN * sizeof(int));
    size_t o_excl   = alloc(NN * sizeof(int));
    size_t o_bsum   = alloc(64 * sizeof(int));
    size_t o_eidx   = alloc(EE * sizeof(int));
    size_t o_srcs   = alloc(EE * sizeof(int));
    size_t o_as1    = alloc((size_t)NN * H1 * sizeof(float));
    size_t o_ad1    = alloc((size_t)NN * H1 * sizeof(float));
    size_t o_h1bf   = alloc((size_t)NN * HID1 * sizeof(__hip_bfloat16));
    size_t o_h1f8   = alloc((size_t)NN * HID1);
    size_t o_xbf    = alloc((size_t)NN * IN_DIM * sizeof(__hip_bfloat16));
    size_t o_x1bf   = alloc((size_t)NN * HID1 * sizeof(__hip_bfloat16));
    size_t o_h2bf   = alloc((size_t)NN * HID2 * sizeof(__hip_bfloat16));
    size_t o_h2f8   = alloc((size_t)NN * HID2);
    size_t o_x2bf   = alloc((size_t)NN * HID2 * sizeof(__hip_bfloat16));
    size_t o_W1p    = alloc((size_t)IN_DIM * HID1 * sizeof(__hip_bfloat16));
    size_t o_W2p    = alloc((size_t)HID1 * HID2 * sizeof(__hip_bfloat16));
    size_t o_fW1p   = alloc((size_t)HID2 * FC1 * sizeof(__hip_bfloat16));

    int*   row_ptr = (int*)(ws + o_rowptr);
    int*   cursor  = (int*)(ws + o_cursor);
    int*   counts  = (int*)(ws + o_counts);
    int*   excl    = (int*)(ws + o_excl);
    int*   bsum    = (int*)(ws + o_bsum);
    int*   eidx    = (int*)(ws + o_eidx);
    int*   srcs    = (int*)(ws + o_srcs);
    float* a_s1    = (float*)(ws + o_as1);
    float* a_d1    = (float*)(ws + o_ad1);
    __hip_bfloat16* h1bf  = (__hip_bfloat16*)(ws + o_h1bf);
    unsigned char*  h1f8  = (unsigned char*)(ws + o_h1f8);
    __hip_bfloat16* xbf   = (__hip_bfloat16*)(ws + o_xbf);
    __hip_bfloat16* x1bf  = (__hip_bfloat16*)(ws + o_x1bf);
    __hip_bfloat16* h2bf  = (__hip_bfloat16*)(ws + o_h2bf);
    unsigned char*  h2f8  = (unsigned char*)(ws + o_h2f8);
    __hip_bfloat16* x2bf  = (__hip_bfloat16*)(ws + o_x2bf);
    __hip_bfloat16* W1p   = (__hip_bfloat16*)(ws + o_W1p);
    __hip_bfloat16* W2p   = (__hip_bfloat16*)(ws + o_W2p);
    __hip_bfloat16* fW1p  = (__hip_bfloat16*)(ws + o_fW1p);
    // layer-2 aliases
    float* a_s2 = a_s1;
    float* a_d2 = a_d1;

    const int SCAN_NB = (NN + 1023) / 1024;  // 49
    const int PREP_N = NN * IN_DIM + IN_DIM * HID1 + HID1 * HID2 + HID2 * FC1;

    // ---- build CSR by dst ----
    fill_zero_int<<<(NN + 255) / 256, 256, 0, stream>>>(counts, NN);
    hist_kernel<<<(EE + 255) / 256, 256, 0, stream>>>(dst, counts);
    scan_a_kernel<<<SCAN_NB, 256, 0, stream>>>(counts, excl, bsum, NN);
    scan_b_kernel<<<1, 64, 0, stream>>>(bsum, row_ptr, SCAN_NB, NN);
    scan_c_kernel<<<SCAN_NB, 256, 0, stream>>>(excl, bsum, row_ptr, cursor, NN);
    scatter_kernel<<<(EE + 255) / 256, 256, 0, stream>>>(src, dst, cursor, eidx, srcs);

    // ---- fused input conversion / weight packing ----
    prep_kernel<<<(PREP_N + 255) / 256, 256, 0, stream>>>(x, xbf, W1, W1p, W2, W2p, fcW1, fW1p);

    // ---- layer 1 ----
    mgemm_kernel<<<dim3((NN + 127) / 128, HID1 / 64), 256, 0, stream>>>(
        xbf, W1p, h1bf, h1f8, NN, IN_DIM, HID1);
    att1_kernel<<<(NN * H1 + 255) / 256, 256, 0, stream>>>(h1bf, att_src1, att_dst1, a_s1, a_d1);
    gat1_kernel<<<(NN + 3) / 4, 256, 0, stream>>>(row_ptr, eidx, srcs, a_s1, a_d1,
                                                  h1f8, b1, alpha1_out, x1bf);

    // ---- layer 2 ----
    mgemm_kernel<<<dim3((NN + 127) / 128, HID2 / 64), 256, 0, stream>>>(
        x1bf, W2p, h2bf, h2f8, NN, HID1, HID2);
    att2_kernel<<<NN, 64, 0, stream>>>(h2bf, att_src2, att_dst2, a_s2, a_d2);
    gat2_kernel<<<(NN + 3) / 4, 256, 0, stream>>>(row_ptr, eidx, srcs, a_s2, a_d2,
                                                  h2f8, b2, alpha2_out, x2bf);

    // ---- FC head ----
    fc_mfma_kernel<<<(NN + 31) / 32, 256, 0, stream>>>(x2bf, fW1p, fcb1, fcW2, fcb2, out_n);
}

// Round 12
// 279.751 us; speedup vs baseline: 1.5813x; 1.0501x over previous
//
#include <hip/hip_runtime.h>
#include <hip/hip_bf16.h>
#include <hip/hip_fp8.h>
#include <math.h>

#define NN 50000
#define EE 800000
#define IN_DIM 128
#define H1 8
#define D1 32
#define HID1 256
#define HID2 128
#define FC1 512
#define NEG_SLOPE 0.2f

typedef short v8s __attribute__((ext_vector_type(8)));
typedef float v4f __attribute__((ext_vector_type(4)));
typedef float v2f __attribute__((ext_vector_type(2)));
typedef unsigned int v4u __attribute__((ext_vector_type(4)));

__device__ __forceinline__ float bf2f(unsigned short u) {
    unsigned int x = ((unsigned int)u) << 16;
    return __uint_as_float(x);
}
__device__ __forceinline__ unsigned short f2bf(float v) {
    __hip_bfloat16 h = __float2bfloat16(v);
    return *(unsigned short*)&h;
}
__device__ __forceinline__ unsigned char f2f8(float v) {
    __hip_fp8_e4m3 t(v);
    return (unsigned char)t.__x;
}
__device__ __forceinline__ float f8tof(unsigned char u) {
    __hip_fp8_e4m3 t;
    t.__x = (__hip_fp8_storage_t)u;
    return (float)t;
}

// unpack 4 fp8 (one 32-bit word) -> 4 floats, hardware packed cvt when available
__device__ __forceinline__ void f8x4(unsigned int w, float& f0, float& f1, float& f2, float& f3) {
#if __has_builtin(__builtin_amdgcn_cvt_pk_f32_fp8)
    v2f lo = __builtin_amdgcn_cvt_pk_f32_fp8((int)w, false);
    v2f hi = __builtin_amdgcn_cvt_pk_f32_fp8((int)w, true);
    f0 = lo[0]; f1 = lo[1]; f2 = hi[0]; f3 = hi[1];
#else
    f0 = f8tof((unsigned char)(w & 0xff));
    f1 = f8tof((unsigned char)((w >> 8) & 0xff));
    f2 = f8tof((unsigned char)((w >> 16) & 0xff));
    f3 = f8tof((unsigned char)(w >> 24));
#endif
}

// ---------------- utility kernels ----------------

__global__ void fill_zero_int(int* p, int n) {
    int i = blockIdx.x * blockDim.x + threadIdx.x;
    if (i < n) p[i] = 0;
}

__global__ void hist_kernel(const int* __restrict__ dst, int* __restrict__ counts) {
    int e = blockIdx.x * blockDim.x + threadIdx.x;
    if (e < EE) atomicAdd(&counts[dst[e]], 1);
}

// ---- hierarchical exclusive scan ----

__global__ __launch_bounds__(256) void scan_a_kernel(const int* __restrict__ counts,
                                                     int* __restrict__ excl,
                                                     int* __restrict__ bsum, int n) {
    __shared__ int wsum[4];
    int tid = threadIdx.x;
    int base = blockIdx.x * 1024 + tid * 4;
    int v0 = 0, v1 = 0, v2 = 0, v3 = 0;
    if (base + 3 < n) {
        int4 t = *(const int4*)(counts + base);
        v0 = t.x; v1 = t.y; v2 = t.z; v3 = t.w;
    } else {
        if (base + 0 < n) v0 = counts[base + 0];
        if (base + 1 < n) v1 = counts[base + 1];
        if (base + 2 < n) v2 = counts[base + 2];
        if (base + 3 < n) v3 = counts[base + 3];
    }
    int tot = v0 + v1 + v2 + v3;
    int lane = tid & 63;
    int w = tid >> 6;
    int x = tot;
    #pragma unroll
    for (int off = 1; off < 64; off <<= 1) {
        int y = __shfl_up(x, off);
        if (lane >= off) x += y;
    }
    if (lane == 63) wsum[w] = x;
    __syncthreads();
    int woff = 0;
    for (int i = 0; i < w; i++) woff += wsum[i];
    int et = woff + x - tot;
    if (base + 0 < n) excl[base + 0] = et;
    if (base + 1 < n) excl[base + 1] = et + v0;
    if (base + 2 < n) excl[base + 2] = et + v0 + v1;
    if (base + 3 < n) excl[base + 3] = et + v0 + v1 + v2;
    if (tid == 255) bsum[blockIdx.x] = woff + x;
}

__global__ __launch_bounds__(64) void scan_b_kernel(int* __restrict__ bsum,
                                                    int* __restrict__ row_ptr, int nb, int n) {
    int lane = threadIdx.x;
    int v = (lane < nb) ? bsum[lane] : 0;
    int x = v;
    #pragma unroll
    for (int off = 1; off < 64; off <<= 1) {
        int y = __shfl_up(x, off);
        if (lane >= off) x += y;
    }
    if (lane < nb) bsum[lane] = x - v;
    if (lane == 63) row_ptr[n] = x;
}

__global__ __launch_bounds__(256) void scan_c_kernel(const int* __restrict__ excl,
                                                     const int* __restrict__ bsum,
                                                     int* __restrict__ row_ptr,
                                                     int* __restrict__ cursor, int n) {
    int base = blockIdx.x * 1024 + threadIdx.x * 4;
    int off = bsum[blockIdx.x];
    #pragma unroll
    for (int j = 0; j < 4; j++) {
        int i = base + j;
        if (i < n) {
            int r = excl[i] + off;
            row_ptr[i] = r;
            cursor[i] = r;
        }
    }
}

__global__ void scatter_kernel(const int* __restrict__ src, const int* __restrict__ dst,
                               int* __restrict__ cursor, int* __restrict__ eidx,
                               int* __restrict__ srcs) {
    int e = blockIdx.x * blockDim.x + threadIdx.x;
    if (e >= EE) return;
    int d = dst[e];
    int p = atomicAdd(&cursor[d], 1);
    eidx[p] = e;
    srcs[p] = src[e];
}

// ---- fused prep: x->bf16 + pack W1/W2/fcW1 into MFMA fragment-major bf16 ----

__device__ __forceinline__ void pack_one(const float* __restrict__ B,
                                         __hip_bfloat16* __restrict__ Bp,
                                         int K, int N, int idx) {
    int k = idx / N, n = idx % N;
    int ntile = n >> 4, ks = k >> 5, kk = k & 31;
    int lane = (n & 15) | ((kk >> 3) << 4);
    int j = kk & 7;
    int KS = K >> 5;
    Bp[((size_t)(ntile * KS + ks) * 64 + lane) * 8 + j] = __float2bfloat16(B[idx]);
}

__global__ void prep_kernel(const float* __restrict__ x, __hip_bfloat16* __restrict__ xbf,
                            const float* __restrict__ W1, __hip_bfloat16* __restrict__ W1p,
                            const float* __restrict__ W2, __hip_bfloat16* __restrict__ W2p,
                            const float* __restrict__ fcW1, __hip_bfloat16* __restrict__ fW1p) {
    int i = blockIdx.x * blockDim.x + threadIdx.x;
    const int N0 = NN * IN_DIM;
    const int N1 = N0 + IN_DIM * HID1;
    const int N2 = N1 + HID1 * HID2;
    const int N3 = N2 + HID2 * FC1;
    if (i < N0) xbf[i] = __float2bfloat16(x[i]);
    else if (i < N1) pack_one(W1, W1p, IN_DIM, HID1, i - N0);
    else if (i < N2) pack_one(W2, W2p, HID1, HID2, i - N1);
    else if (i < N3) pack_one(fcW1, fW1p, HID2, FC1, i - N2);
}

// ---------------- MFMA GEMM (bf16 in, fp8 out) ----------------

__global__ __launch_bounds__(256) void mgemm_kernel(const __hip_bfloat16* __restrict__ A,
                                                    const __hip_bfloat16* __restrict__ Bp,
                                                    unsigned char* __restrict__ Cf8,
                                                    int M, int K, int N) {
    int w = threadIdx.x >> 6, l = threadIdx.x & 63;
    int bm = blockIdx.x * 128 + w * 32;
    int bn = blockIdx.y * 64;
    int lr = l & 15, lk = l >> 4;
    int KS = K >> 5;
    const short* Ab = (const short*)A;
    const short* Bb = (const short*)Bp;
    v4f acc[2][4];
    #pragma unroll
    for (int mi = 0; mi < 2; mi++)
        #pragma unroll
        for (int nt = 0; nt < 4; nt++) acc[mi][nt] = (v4f)(0.f);
    for (int ks = 0; ks < KS; ks++) {
        v8s a[2];
        #pragma unroll
        for (int mi = 0; mi < 2; mi++) {
            int gm = bm + mi * 16 + lr;
            a[mi] = (gm < M) ? *(const v8s*)(Ab + (size_t)gm * K + ks * 32 + lk * 8)
                             : (v8s)(short)0;
        }
        #pragma unroll
        for (int nt = 0; nt < 4; nt++) {
            int ntile = (bn >> 4) + nt;
            v8s b = *(const v8s*)(Bb + ((size_t)(ntile * KS + ks) * 64 + l) * 8);
            acc[0][nt] = __builtin_amdgcn_mfma_f32_16x16x32_bf16(a[0], b, acc[0][nt], 0, 0, 0);
            acc[1][nt] = __builtin_amdgcn_mfma_f32_16x16x32_bf16(a[1], b, acc[1][nt], 0, 0, 0);
        }
    }
    #pragma unroll
    for (int mi = 0; mi < 2; mi++) {
        #pragma unroll
        for (int nt = 0; nt < 4; nt++) {
            int gn = bn + nt * 16 + lr;
            #pragma unroll
            for (int j = 0; j < 4; j++) {
                int gm = bm + mi * 16 + lk * 4 + j;
                if (gm < M)
                    Cf8[(size_t)gm * N + gn] = f2f8(acc[mi][nt][j]);
            }
        }
    }
}

// ---------------- fused FC head via MFMA ----------------

__global__ __launch_bounds__(256) void fc_mfma_kernel(const __hip_bfloat16* __restrict__ A,
                                                      const __hip_bfloat16* __restrict__ Bp,
                                                      const float* __restrict__ fcb1,
                                                      const float* __restrict__ fcW2,
                                                      const float* __restrict__ fcb2,
                                                      float* __restrict__ out) {
    __shared__ float red[4][32];
    int w = threadIdx.x >> 6, l = threadIdx.x & 63;
    int bm = blockIdx.x * 32;
    int lr = l & 15, lk = l >> 4;
    const int K = HID2, KS = K >> 5;
    const short* Ab = (const short*)A;
    const short* Bb = (const short*)Bp;
    v4f acc[2][8];
    #pragma unroll
    for (int mi = 0; mi < 2; mi++)
        #pragma unroll
        for (int nt = 0; nt < 8; nt++) acc[mi][nt] = (v4f)(0.f);
    for (int ks = 0; ks < KS; ks++) {
        v8s a[2];
        #pragma unroll
        for (int mi = 0; mi < 2; mi++) {
            int gm = bm + mi * 16 + lr;
            a[mi] = (gm < NN) ? *(const v8s*)(Ab + (size_t)gm * K + ks * 32 + lk * 8)
                              : (v8s)(short)0;
        }
        #pragma unroll
        for (int nt = 0; nt < 8; nt++) {
            int ntile = w * 8 + nt;
            v8s b = *(const v8s*)(Bb + ((size_t)(ntile * KS + ks) * 64 + l) * 8);
            acc[0][nt] = __builtin_amdgcn_mfma_f32_16x16x32_bf16(a[0], b, acc[0][nt], 0, 0, 0);
            acc[1][nt] = __builtin_amdgcn_mfma_f32_16x16x32_bf16(a[1], b, acc[1][nt], 0, 0, 0);
        }
    }
    float p[2][4];
    #pragma unroll
    for (int mi = 0; mi < 2; mi++)
        #pragma unroll
        for (int j = 0; j < 4; j++) p[mi][j] = 0.f;
    #pragma unroll
    for (int nt = 0; nt < 8; nt++) {
        int col = w * 128 + nt * 16 + lr;
        float b1v = fcb1[col], w2v = fcW2[col];
        #pragma unroll
        for (int mi = 0; mi < 2; mi++) {
            #pragma unroll
            for (int j = 0; j < 4; j++) {
                float v = acc[mi][nt][j] + b1v;
                p[mi][j] += ((v > 0.f) ? v : 0.f) * w2v;
            }
        }
    }
    #pragma unroll
    for (int mi = 0; mi < 2; mi++)
        #pragma unroll
        for (int j = 0; j < 4; j++) {
            float v = p[mi][j];
            v += __shfl_xor(v, 1);
            v += __shfl_xor(v, 2);
            v += __shfl_xor(v, 4);
            v += __shfl_xor(v, 8);
            p[mi][j] = v;
        }
    if (lr == 0) {
        #pragma unroll
        for (int mi = 0; mi < 2; mi++)
            #pragma unroll
            for (int j = 0; j < 4; j++) red[w][mi * 16 + lk * 4 + j] = p[mi][j];
    }
    __syncthreads();
    int tid = threadIdx.x;
    if (tid < 32) {
        int gm = bm + tid;
        if (gm < NN)
            out[gm] = red[0][tid] + red[1][tid] + red[2][tid] + red[3][tid] + fcb2[0];
    }
}

// ---------------- layer 1 attention logits (fp8 input, packed cvt) ----------------

__global__ void att1_kernel(const unsigned char* __restrict__ h1f8,
                            const float* __restrict__ att_src,
                            const float* __restrict__ att_dst, float* __restrict__ a_s,
                            float* __restrict__ a_d) {
    int idx = blockIdx.x * blockDim.x + threadIdx.x;
    if (idx >= NN * H1) return;
    int n = idx >> 3, h = idx & 7;
    const v4u* row = (const v4u*)(h1f8 + (size_t)n * HID1 + h * D1);
    float s = 0.f, d = 0.f;
    #pragma unroll
    for (int q = 0; q < 2; q++) {
        v4u v = row[q];
        #pragma unroll
        for (int k = 0; k < 4; k++) {
            float f0, f1, f2, f3;
            f8x4(v[k], f0, f1, f2, f3);
            int kk = q * 16 + k * 4;
            s += f0 * att_src[h * D1 + kk] + f1 * att_src[h * D1 + kk + 1]
               + f2 * att_src[h * D1 + kk + 2] + f3 * att_src[h * D1 + kk + 3];
            d += f0 * att_dst[h * D1 + kk] + f1 * att_dst[h * D1 + kk + 1]
               + f2 * att_dst[h * D1 + kk + 2] + f3 * att_dst[h * D1 + kk + 3];
        }
    }
    a_s[idx] = s;
    a_d[idx] = d;
}

// ---------------- fused layer-1 softmax + aggregation, degree-bucketed, fp8 gather ----

template <int KM>
__device__ __forceinline__ void gat1_fast(int lane, int start, int cnt,
                                          const int* __restrict__ srcs,
                                          const int* __restrict__ eidx,
                                          const float* __restrict__ a_s, float ad,
                                          const unsigned char* __restrict__ hf8,
                                          float* __restrict__ alpha1_out,
                                          float& acc0, float& acc1, float& acc2, float& acc3) {
    int h = lane & 7, j = lane >> 3;
    int hl = lane >> 3;
    int cl = min(lane, cnt - 1);
    int s_all = srcs[start + cl];
    int e_all = eidx[start + cl];
    float ex[KM];
    int sj[KM];
    #pragma unroll
    for (int k = 0; k < KM; k++) {
        int idx = j + k * 8;
        sj[k] = __shfl(s_all, idx);
        float v = a_s[(size_t)sj[k] * 8 + h] + ad;
        v = (v >= 0.f) ? v : NEG_SLOPE * v;
        ex[k] = (idx < cnt) ? v : -INFINITY;
    }
    float m = ex[0];
    #pragma unroll
    for (int k = 1; k < KM; k++) m = fmaxf(m, ex[k]);
    m = fmaxf(m, __shfl_xor(m, 8));
    m = fmaxf(m, __shfl_xor(m, 16));
    m = fmaxf(m, __shfl_xor(m, 32));
    float s = 0.f;
    #pragma unroll
    for (int k = 0; k < KM; k++) {
        ex[k] = expf(ex[k] - m);
        s += ex[k];
    }
    s += __shfl_xor(s, 8);
    s += __shfl_xor(s, 16);
    s += __shfl_xor(s, 32);
    float inv = 1.f / (s + 1e-16f);
    #pragma unroll
    for (int k = 0; k < KM; k++) ex[k] *= inv;
    #pragma unroll
    for (int k = 0; k < KM; k++) {
        int idx = j + k * 8;
        int eo = __shfl(e_all, idx);
        if (idx < cnt) alpha1_out[(size_t)eo * 8 + h] = ex[k];
    }
    unsigned int pk[KM];
    #pragma unroll
    for (int k = 0; k < KM; k++)
        pk[k] = ((unsigned int)sj[k] << 16) | (unsigned int)f2bf(ex[k]);
    int rounds = (cnt + 7) >> 3;
    #pragma unroll
    for (int K = 0; K < KM; K++) {
        if (K < rounds) {
            int sjt[8];
            float At[8];
            unsigned int qt[8];
            #pragma unroll
            for (int t = 0; t < 8; t++) {
                unsigned int wv = (unsigned int)__shfl((int)pk[K], t * 8 + hl);
                sjt[t] = (int)(wv >> 16);
                At[t] = bf2f((unsigned short)wv);
            }
            #pragma unroll
            for (int t = 0; t < 8; t++)
                qt[t] = *(const unsigned int*)(hf8 + (size_t)sjt[t] * HID1 + lane * 4);
            #pragma unroll
            for (int t = 0; t < 8; t++) {
                float f0, f1, f2, f3;
                f8x4(qt[t], f0, f1, f2, f3);
                acc0 += At[t] * f0;
                acc1 += At[t] * f1;
                acc2 += At[t] * f2;
                acc3 += At[t] * f3;
            }
        }
    }
}

__global__ __launch_bounds__(256) void gat1_kernel(const int* __restrict__ row_ptr,
                                                   const int* __restrict__ eidx,
                                                   const int* __restrict__ srcs,
                                                   const float* __restrict__ a_s,
                                                   const float* __restrict__ a_d,
                                                   const unsigned char* __restrict__ h1f8,
                                                   const float* __restrict__ b1,
                                                   float* __restrict__ alpha1_out,
                                                   __hip_bfloat16* __restrict__ x1bf) {
    int wv = threadIdx.x >> 6, lane = threadIdx.x & 63;
    int n = blockIdx.x * 4 + wv;
    if (n >= NN) return;
    int start = row_ptr[n], end = row_ptr[n + 1];
    int cnt = end - start;
    int h = lane & 7, j = lane >> 3;
    int hl = lane >> 3;
    float acc0 = 0.f, acc1 = 0.f, acc2 = 0.f, acc3 = 0.f;
    if (cnt > 0 && cnt <= 64) {
        float ad = a_d[(size_t)n * 8 + h];
        if (cnt <= 8)
            gat1_fast<1>(lane, start, cnt, srcs, eidx, a_s, ad, h1f8, alpha1_out, acc0, acc1, acc2, acc3);
        else if (cnt <= 16)
            gat1_fast<2>(lane, start, cnt, srcs, eidx, a_s, ad, h1f8, alpha1_out, acc0, acc1, acc2, acc3);
        else if (cnt <= 24)
            gat1_fast<3>(lane, start, cnt, srcs, eidx, a_s, ad, h1f8, alpha1_out, acc0, acc1, acc2, acc3);
        else if (cnt <= 32)
            gat1_fast<4>(lane, start, cnt, srcs, eidx, a_s, ad, h1f8, alpha1_out, acc0, acc1, acc2, acc3);
        else
            gat1_fast<8>(lane, start, cnt, srcs, eidx, a_s, ad, h1f8, alpha1_out, acc0, acc1, acc2, acc3);
    } else if (cnt > 64) {
        float ad = a_d[(size_t)n * 8 + h];
        float m = -INFINITY;
        for (int p = start + j; p < end; p += 8) {
            float v = a_s[(size_t)srcs[p] * 8 + h] + ad;
            v = (v >= 0.f) ? v : NEG_SLOPE * v;
            m = fmaxf(m, v);
        }
        m = fmaxf(m, __shfl_xor(m, 8));
        m = fmaxf(m, __shfl_xor(m, 16));
        m = fmaxf(m, __shfl_xor(m, 32));
        float s = 0.f;
        for (int p = start + j; p < end; p += 8) {
            float v = a_s[(size_t)srcs[p] * 8 + h] + ad;
            v = (v >= 0.f) ? v : NEG_SLOPE * v;
            s += expf(v - m);
        }
        s += __shfl_xor(s, 8);
        s += __shfl_xor(s, 16);
        s += __shfl_xor(s, 32);
        float inv = 1.f / (s + 1e-16f);
        for (int p = start + j; p < end; p += 8) {
            float v = a_s[(size_t)srcs[p] * 8 + h] + ad;
            v = (v >= 0.f) ? v : NEG_SLOPE * v;
            alpha1_out[(size_t)eidx[p] * 8 + h] = expf(v - m) * inv;
        }
        float mh = __shfl(m, hl);
        float invh = __shfl(inv, hl);
        float adh = __shfl(ad, hl);
        for (int p = start; p < end; p++) {
            int sp = srcs[p];
            float v = a_s[(size_t)sp * 8 + hl] + adh;
            v = (v >= 0.f) ? v : NEG_SLOPE * v;
            float al = expf(v - mh) * invh;
            unsigned int q = *(const unsigned int*)(h1f8 + (size_t)sp * HID1 + lane * 4);
            float f0, f1, f2, f3;
            f8x4(q, f0, f1, f2, f3);
            acc0 += al * f0;
            acc1 += al * f1;
            acc2 += al * f2;
            acc3 += al * f3;
        }
    }
    float4 bb = *(const float4*)(b1 + lane * 4);
    float r0 = acc0 + bb.x, r1 = acc1 + bb.y, r2 = acc2 + bb.z, r3 = acc3 + bb.w;
    r0 = (r0 > 0.f) ? r0 : expf(r0) - 1.f;
    r1 = (r1 > 0.f) ? r1 : expf(r1) - 1.f;
    r2 = (r2 > 0.f) ? r2 : expf(r2) - 1.f;
    r3 = (r3 > 0.f) ? r3 : expf(r3) - 1.f;
    ushort4 o;
    o.x = f2bf(r0); o.y = f2bf(r1); o.z = f2bf(r2); o.w = f2bf(r3);
    *(ushort4*)((unsigned short*)x1bf + (size_t)n * HID1 + lane * 4) = o;
}

// ---------------- layer 2 attention logits (1 head, fp8 input) ----------------

__global__ __launch_bounds__(64) void att2_kernel(const unsigned char* __restrict__ h2f8,
                                                  const float* __restrict__ att_src,
                                                  const float* __restrict__ att_dst,
                                                  float* __restrict__ a_s, float* __restrict__ a_d) {
    int n = blockIdx.x;
    int lane = threadIdx.x;
    const unsigned char* row = h2f8 + (size_t)n * HID2;
    unsigned short us = *(const unsigned short*)(row + lane * 2);
    float f0, f1, f2, f3;
    f8x4((unsigned int)us, f0, f1, f2, f3);  // f0,f1 valid (low 2 bytes)
    float s = f0 * att_src[lane * 2] + f1 * att_src[lane * 2 + 1];
    float d = f0 * att_dst[lane * 2] + f1 * att_dst[lane * 2 + 1];
    for (int off = 32; off; off >>= 1) {
        s += __shfl_down(s, off);
        d += __shfl_down(d, off);
    }
    if (lane == 0) {
        a_s[n] = s;
        a_d[n] = d;
    }
}

// ---------------- fused layer-2 softmax + aggregation (fp8 gather, packed shfl) ------

__global__ __launch_bounds__(256) void gat2_kernel(const int* __restrict__ row_ptr,
                                                   const int* __restrict__ eidx,
                                                   const int* __restrict__ srcs,
                                                   const float* __restrict__ a_s,
                                                   const float* __restrict__ a_d,
                                                   const unsigned char* __restrict__ h2f8,
                                                   const float* __restrict__ b2,
                                                   float* __restrict__ alpha2_out,
                                                   __hip_bfloat16* __restrict__ x2bf) {
    int wv = threadIdx.x >> 6, lane = threadIdx.x & 63;
    int n = blockIdx.x * 4 + wv;
    if (n >= NN) return;
    int start = row_ptr[n], end = row_ptr[n + 1];
    int cnt = end - start;
    int r = lane >> 5, c = lane & 31;
    float acc0 = 0.f, acc1 = 0.f, acc2 = 0.f, acc3 = 0.f;
    if (cnt > 0 && cnt <= 64) {
        float ad = a_d[n];
        bool act = lane < cnt;
        int ii = min(lane, cnt - 1);
        int sj = srcs[start + ii];
        float v = a_s[sj] + ad;
        v = (v >= 0.f) ? v : NEG_SLOPE * v;
        float e = act ? v : -INFINITY;
        float m = e;
        #pragma unroll
        for (int off = 1; off < 64; off <<= 1) m = fmaxf(m, __shfl_xor(m, off));
        float ex = expf(e - m);
        float s = ex;
        #pragma unroll
        for (int off = 1; off < 64; off <<= 1) s += __shfl_xor(s, off);
        float al = ex / (s + 1e-16f);
        if (act) alpha2_out[eidx[start + lane]] = al;
        unsigned int pk = ((unsigned int)sj << 16) | (unsigned int)f2bf(al);
        int rounds = (cnt + 7) >> 3;
        #pragma unroll
        for (int K = 0; K < 8; K++) {
            if (K < rounds) {
                int sjt[4];
                float At[4];
                unsigned int qt[4];
                #pragma unroll
                for (int t = 0; t < 4; t++) {
                    int je = K * 8 + t * 2 + r;
                    unsigned int wq = (unsigned int)__shfl((int)pk, je);
                    sjt[t] = (int)(wq >> 16);
                    At[t] = bf2f((unsigned short)wq);
                }
                #pragma unroll
                for (int t = 0; t < 4; t++)
                    qt[t] = *(const unsigned int*)(h2f8 + (size_t)sjt[t] * HID2 + c * 4);
                #pragma unroll
                for (int t = 0; t < 4; t++) {
                    float f0, f1, f2, f3;
                    f8x4(qt[t], f0, f1, f2, f3);
                    acc0 += At[t] * f0;
                    acc1 += At[t] * f1;
                    acc2 += At[t] * f2;
                    acc3 += At[t] * f3;
                }
            }
        }
    } else if (cnt > 64) {
        float ad = a_d[n];
        float m = -INFINITY;
        for (int p = start + lane; p < end; p += 64) {
            float v = a_s[srcs[p]] + ad;
            v = (v >= 0.f) ? v : NEG_SLOPE * v;
            m = fmaxf(m, v);
        }
        for (int off = 32; off; off >>= 1) m = fmaxf(m, __shfl_xor(m, off));
        float s = 0.f;
        for (int p = start + lane; p < end; p += 64) {
            float v = a_s[srcs[p]] + ad;
            v = (v >= 0.f) ? v : NEG_SLOPE * v;
            s += expf(v - m);
        }
        for (int off = 32; off; off >>= 1) s += __shfl_xor(s, off);
        float inv = 1.f / (s + 1e-16f);
        for (int p = start + lane; p < end; p += 64) {
            float v = a_s[srcs[p]] + ad;
            v = (v >= 0.f) ? v : NEG_SLOPE * v;
            alpha2_out[eidx[p]] = expf(v - m) * inv;
        }
        for (int p = start + r; p < end; p += 2) {
            int sp = srcs[p];
            float v = a_s[sp] + ad;
            v = (v >= 0.f) ? v : NEG_SLOPE * v;
            float al = expf(v - m) * inv;
            unsigned int q = *(const unsigned int*)(h2f8 + (size_t)sp * HID2 + c * 4);
            float f0, f1, f2, f3;
            f8x4(q, f0, f1, f2, f3);
            acc0 += al * f0;
            acc1 += al * f1;
            acc2 += al * f2;
            acc3 += al * f3;
        }
    }
    acc0 += __shfl_xor(acc0, 32);
    acc1 += __shfl_xor(acc1, 32);
    acc2 += __shfl_xor(acc2, 32);
    acc3 += __shfl_xor(acc3, 32);
    if (r == 0) {
        float4 bb = *(const float4*)(b2 + c * 4);
        float r0 = acc0 + bb.x, r1 = acc1 + bb.y, r2 = acc2 + bb.z, r3 = acc3 + bb.w;
        r0 = (r0 > 0.f) ? r0 : 0.f;
        r1 = (r1 > 0.f) ? r1 : 0.f;
        r2 = (r2 > 0.f) ? r2 : 0.f;
        r3 = (r3 > 0.f) ? r3 : 0.f;
        ushort4 o;
        o.x = f2bf(r0); o.y = f2bf(r1); o.z = f2bf(r2); o.w = f2bf(r3);
        *(ushort4*)((unsigned short*)x2bf + (size_t)n * HID2 + c * 4) = o;
    }
}

// ---------------- host launch ----------------

extern "C" void kernel_launch(void* const* d_in, const int* in_sizes, int n_in,
                              void* d_out, int out_size, void* d_ws, size_t ws_size,
                              hipStream_t stream) {
    (void)in_sizes; (void)n_in; (void)out_size; (void)ws_size;
    const float* x        = (const float*)d_in[0];
    const int*   eindex   = (const int*)d_in[1];
    const float* W1       = (const float*)d_in[2];
    const float* att_src1 = (const float*)d_in[3];
    const float* att_dst1 = (const float*)d_in[4];
    const float* b1       = (const float*)d_in[5];
    const float* W2       = (const float*)d_in[6];
    const float* att_src2 = (const float*)d_in[7];
    const float* att_dst2 = (const float*)d_in[8];
    const float* b2       = (const float*)d_in[9];
    const float* fcW1     = (const float*)d_in[10];
    const float* fcb1     = (const float*)d_in[11];
    const float* fcW2     = (const float*)d_in[12];
    const float* fcb2     = (const float*)d_in[13];

    const int* src = eindex;
    const int* dst = eindex + EE;

    float* out_n      = (float*)d_out;               // [N]
    float* alpha1_out = out_n + NN;                  // [E,8]
    float* alpha2_out = alpha1_out + (size_t)EE * 8; // [E]

    char* ws = (char*)d_ws;
    size_t off = 0;
    auto alloc = [&](size_t bytes) {
        size_t o = off;
        off = (off + bytes + 255) & ~(size_t)255;
        return o;
    };
    size_t o_rowptr = alloc((NN + 1) * sizeof(int));
    size_t o_cursor = alloc(NN * sizeof(int));
    size_t o_counts = alloc(NN * sizeof(int));
    size_t o_excl   = alloc(NN * sizeof(int));
    size_t o_bsum   = alloc(64 * sizeof(int));
    size_t o_eidx   = alloc(EE * sizeof(int));
    size_t o_srcs   = alloc(EE * sizeof(int));
    size_t o_as1    = alloc((size_t)NN * H1 * sizeof(float));
    size_t o_ad1    = alloc((size_t)NN * H1 * sizeof(float));
    size_t o_h1f8   = alloc((size_t)NN * HID1);
    size_t o_xbf    = alloc((size_t)NN * IN_DIM * sizeof(__hip_bfloat16));
    size_t o_x1bf   = alloc((size_t)NN * HID1 * sizeof(__hip_bfloat16));
    size_t o_h2f8   = alloc((size_t)NN * HID2);
    size_t o_x2bf   = alloc((size_t)NN * HID2 * sizeof(__hip_bfloat16));
    size_t o_W1p    = alloc((size_t)IN_DIM * HID1 * sizeof(__hip_bfloat16));
    size_t o_W2p    = alloc((size_t)HID1 * HID2 * sizeof(__hip_bfloat16));
    size_t o_fW1p   = alloc((size_t)HID2 * FC1 * sizeof(__hip_bfloat16));

    int*   row_ptr = (int*)(ws + o_rowptr);
    int*   cursor  = (int*)(ws + o_cursor);
    int*   counts  = (int*)(ws + o_counts);
    int*   excl    = (int*)(ws + o_excl);
    int*   bsum    = (int*)(ws + o_bsum);
    int*   eidx    = (int*)(ws + o_eidx);
    int*   srcs    = (int*)(ws + o_srcs);
    float* a_s1    = (float*)(ws + o_as1);
    float* a_d1    = (float*)(ws + o_ad1);
    unsigned char*  h1f8  = (unsigned char*)(ws + o_h1f8);
    __hip_bfloat16* xbf   = (__hip_bfloat16*)(ws + o_xbf);
    __hip_bfloat16* x1bf  = (__hip_bfloat16*)(ws + o_x1bf);
    unsigned char*  h2f8  = (unsigned char*)(ws + o_h2f8);
    __hip_bfloat16* x2bf  = (__hip_bfloat16*)(ws + o_x2bf);
    __hip_bfloat16* W1p   = (__hip_bfloat16*)(ws + o_W1p);
    __hip_bfloat16* W2p   = (__hip_bfloat16*)(ws + o_W2p);
    __hip_bfloat16* fW1p  = (__hip_bfloat16*)(ws + o_fW1p);
    // layer-2 aliases
    float* a_s2 = a_s1;
    float* a_d2 = a_d1;

    const int SCAN_NB = (NN + 1023) / 1024;  // 49
    const int PREP_N = NN * IN_DIM + IN_DIM * HID1 + HID1 * HID2 + HID2 * FC1;

    // ---- build CSR by dst ----
    fill_zero_int<<<(NN + 255) / 256, 256, 0, stream>>>(counts, NN);
    hist_kernel<<<(EE + 255) / 256, 256, 0, stream>>>(dst, counts);
    scan_a_kernel<<<SCAN_NB, 256, 0, stream>>>(counts, excl, bsum, NN);
    scan_b_kernel<<<1, 64, 0, stream>>>(bsum, row_ptr, SCAN_NB, NN);
    scan_c_kernel<<<SCAN_NB, 256, 0, stream>>>(excl, bsum, row_ptr, cursor, NN);
    scatter_kernel<<<(EE + 255) / 256, 256, 0, stream>>>(src, dst, cursor, eidx, srcs);

    // ---- fused input conversion / weight packing ----
    prep_kernel<<<(PREP_N + 255) / 256, 256, 0, stream>>>(x, xbf, W1, W1p, W2, W2p, fcW1, fW1p);

    // ---- layer 1 ----
    mgemm_kernel<<<dim3((NN + 127) / 128, HID1 / 64), 256, 0, stream>>>(
        xbf, W1p, h1f8, NN, IN_DIM, HID1);
    att1_kernel<<<(NN * H1 + 255) / 256, 256, 0, stream>>>(h1f8, att_src1, att_dst1, a_s1, a_d1);
    gat1_kernel<<<(NN + 3) / 4, 256, 0, stream>>>(row_ptr, eidx, srcs, a_s1, a_d1,
                                                  h1f8, b1, alpha1_out, x1bf);

    // ---- layer 2 ----
    mgemm_kernel<<<dim3((NN + 127) / 128, HID2 / 64), 256, 0, stream>>>(
        x1bf, W2p, h2f8, NN, HID1, HID2);
    att2_kernel<<<NN, 64, 0, stream>>>(h2f8, att_src2, att_dst2, a_s2, a_d2);
    gat2_kernel<<<(NN + 3) / 4, 256, 0, stream>>>(row_ptr, eidx, srcs, a_s2, a_d2,
                                                  h2f8, b2, alpha2_out, x2bf);

    // ---- FC head ----
    fc_mfma_kernel<<<(NN + 31) / 32, 256, 0, stream>>>(x2bf, fW1p, fcb1, fcW2, fcb2, out_n);
}

// Round 13
// 266.418 us; speedup vs baseline: 1.6604x; 1.0500x over previous
//
#include <hip/hip_runtime.h>
#include <hip/hip_bf16.h>
#include <hip/hip_fp8.h>
#include <math.h>

#define NN 50000
#define EE 800000
#define IN_DIM 128
#define H1 8
#define D1 32
#define HID1 256
#define HID2 128
#define FC1 512
#define NEG_SLOPE 0.2f

typedef short v8s __attribute__((ext_vector_type(8)));
typedef float v4f __attribute__((ext_vector_type(4)));
typedef float v2f __attribute__((ext_vector_type(2)));
typedef unsigned int v4u __attribute__((ext_vector_type(4)));

__device__ __forceinline__ float bf2f(unsigned short u) {
    unsigned int x = ((unsigned int)u) << 16;
    return __uint_as_float(x);
}
__device__ __forceinline__ unsigned short f2bf(float v) {
    __hip_bfloat16 h = __float2bfloat16(v);
    return *(unsigned short*)&h;
}
__device__ __forceinline__ unsigned char f2f8(float v) {
    __hip_fp8_e4m3 t(v);
    return (unsigned char)t.__x;
}
__device__ __forceinline__ float f8tof(unsigned char u) {
    __hip_fp8_e4m3 t;
    t.__x = (__hip_fp8_storage_t)u;
    return (float)t;
}

__device__ __forceinline__ void f8x4(unsigned int w, float& f0, float& f1, float& f2, float& f3) {
#if __has_builtin(__builtin_amdgcn_cvt_pk_f32_fp8)
    v2f lo = __builtin_amdgcn_cvt_pk_f32_fp8((int)w, false);
    v2f hi = __builtin_amdgcn_cvt_pk_f32_fp8((int)w, true);
    f0 = lo[0]; f1 = lo[1]; f2 = hi[0]; f3 = hi[1];
#else
    f0 = f8tof((unsigned char)(w & 0xff));
    f1 = f8tof((unsigned char)((w >> 8) & 0xff));
    f2 = f8tof((unsigned char)((w >> 16) & 0xff));
    f3 = f8tof((unsigned char)(w >> 24));
#endif
}

// ---------------- CSR build ----------------

__global__ void hist_kernel(const int* __restrict__ dst, int* __restrict__ counts) {
    int e = blockIdx.x * blockDim.x + threadIdx.x;
    if (e < EE) atomicAdd(&counts[dst[e]], 1);
}

__global__ __launch_bounds__(256) void scan_a_kernel(const int* __restrict__ counts,
                                                     int* __restrict__ excl,
                                                     int* __restrict__ bsum, int n) {
    __shared__ int wsum[4];
    int tid = threadIdx.x;
    int base = blockIdx.x * 1024 + tid * 4;
    int v0 = 0, v1 = 0, v2 = 0, v3 = 0;
    if (base + 3 < n) {
        int4 t = *(const int4*)(counts + base);
        v0 = t.x; v1 = t.y; v2 = t.z; v3 = t.w;
    } else {
        if (base + 0 < n) v0 = counts[base + 0];
        if (base + 1 < n) v1 = counts[base + 1];
        if (base + 2 < n) v2 = counts[base + 2];
        if (base + 3 < n) v3 = counts[base + 3];
    }
    int tot = v0 + v1 + v2 + v3;
    int lane = tid & 63;
    int w = tid >> 6;
    int x = tot;
    #pragma unroll
    for (int off = 1; off < 64; off <<= 1) {
        int y = __shfl_up(x, off);
        if (lane >= off) x += y;
    }
    if (lane == 63) wsum[w] = x;
    __syncthreads();
    int woff = 0;
    for (int i = 0; i < w; i++) woff += wsum[i];
    int et = woff + x - tot;
    if (base + 0 < n) excl[base + 0] = et;
    if (base + 1 < n) excl[base + 1] = et + v0;
    if (base + 2 < n) excl[base + 2] = et + v0 + v1;
    if (base + 3 < n) excl[base + 3] = et + v0 + v1 + v2;
    if (tid == 255) bsum[blockIdx.x] = woff + x;
}

__global__ __launch_bounds__(64) void scan_b_kernel(int* __restrict__ bsum,
                                                    int* __restrict__ row_ptr, int nb, int n) {
    int lane = threadIdx.x;
    int v = (lane < nb) ? bsum[lane] : 0;
    int x = v;
    #pragma unroll
    for (int off = 1; off < 64; off <<= 1) {
        int y = __shfl_up(x, off);
        if (lane >= off) x += y;
    }
    if (lane < nb) bsum[lane] = x - v;
    if (lane == 63) row_ptr[n] = x;
}

__global__ __launch_bounds__(256) void scan_c_kernel(const int* __restrict__ excl,
                                                     const int* __restrict__ bsum,
                                                     int* __restrict__ row_ptr,
                                                     int* __restrict__ cursor, int n) {
    int base = blockIdx.x * 1024 + threadIdx.x * 4;
    int off = bsum[blockIdx.x];
    #pragma unroll
    for (int j = 0; j < 4; j++) {
        int i = base + j;
        if (i < n) {
            int r = excl[i] + off;
            row_ptr[i] = r;
            cursor[i] = r;
        }
    }
}

// writes (eidx, src) pairs — one 8B store per edge
__global__ void scatter_kernel(const int* __restrict__ src, const int* __restrict__ dst,
                               int* __restrict__ cursor, int2* __restrict__ pairs) {
    int e = blockIdx.x * blockDim.x + threadIdx.x;
    if (e >= EE) return;
    int d = dst[e];
    int p = atomicAdd(&cursor[d], 1);
    pairs[p] = make_int2(e, src[e]);
}

// ---- fused prep: x->bf16 + pack W1/W2/fcW1 into MFMA fragment-major bf16 ----

__device__ __forceinline__ void pack_one(const float* __restrict__ B,
                                         __hip_bfloat16* __restrict__ Bp,
                                         int K, int N, int idx) {
    int k = idx / N, n = idx % N;
    int ntile = n >> 4, ks = k >> 5, kk = k & 31;
    int lane = (n & 15) | ((kk >> 3) << 4);
    int j = kk & 7;
    int KS = K >> 5;
    Bp[((size_t)(ntile * KS + ks) * 64 + lane) * 8 + j] = __float2bfloat16(B[idx]);
}

__global__ void prep_kernel(const float* __restrict__ x, __hip_bfloat16* __restrict__ xbf,
                            const float* __restrict__ W1, __hip_bfloat16* __restrict__ W1p,
                            const float* __restrict__ W2, __hip_bfloat16* __restrict__ W2p,
                            const float* __restrict__ fcW1, __hip_bfloat16* __restrict__ fW1p) {
    int i = blockIdx.x * blockDim.x + threadIdx.x;
    const int N0 = NN * IN_DIM;
    const int N1 = N0 + IN_DIM * HID1;
    const int N2 = N1 + HID1 * HID2;
    const int N3 = N2 + HID2 * FC1;
    if (i < N0) xbf[i] = __float2bfloat16(x[i]);
    else if (i < N1) pack_one(W1, W1p, IN_DIM, HID1, i - N0);
    else if (i < N2) pack_one(W2, W2p, HID1, HID2, i - N1);
    else if (i < N3) pack_one(fcW1, fW1p, HID2, FC1, i - N2);
}

// ---------------- MFMA GEMM (bf16 in, fp8 out) + fused attention logits ----------------
// ATT=1: heads of 32 cols aligned with bn tile (layer 1): direct a_s/a_d writes.
// ATT=2: one head spanning N=128 (layer 2): atomicAdd partial sums (a_s/a_d pre-zeroed).

template <int ATT>
__global__ __launch_bounds__(256) void mgemm_kernel(const __hip_bfloat16* __restrict__ A,
                                                    const __hip_bfloat16* __restrict__ Bp,
                                                    unsigned char* __restrict__ Cf8,
                                                    const float* __restrict__ as_w,
                                                    const float* __restrict__ ad_w,
                                                    float* __restrict__ a_s,
                                                    float* __restrict__ a_d,
                                                    int M, int K, int N) {
    int w = threadIdx.x >> 6, l = threadIdx.x & 63;
    int bm = blockIdx.x * 128 + w * 32;
    int bn = blockIdx.y * 64;
    int lr = l & 15, lk = l >> 4;
    int KS = K >> 5;
    const short* Ab = (const short*)A;
    const short* Bb = (const short*)Bp;
    v4f acc[2][4];
    #pragma unroll
    for (int mi = 0; mi < 2; mi++)
        #pragma unroll
        for (int nt = 0; nt < 4; nt++) acc[mi][nt] = (v4f)(0.f);
    for (int ks = 0; ks < KS; ks++) {
        v8s a[2];
        #pragma unroll
        for (int mi = 0; mi < 2; mi++) {
            int gm = bm + mi * 16 + lr;
            a[mi] = (gm < M) ? *(const v8s*)(Ab + (size_t)gm * K + ks * 32 + lk * 8)
                             : (v8s)(short)0;
        }
        #pragma unroll
        for (int nt = 0; nt < 4; nt++) {
            int ntile = (bn >> 4) + nt;
            v8s b = *(const v8s*)(Bb + ((size_t)(ntile * KS + ks) * 64 + l) * 8);
            acc[0][nt] = __builtin_amdgcn_mfma_f32_16x16x32_bf16(a[0], b, acc[0][nt], 0, 0, 0);
            acc[1][nt] = __builtin_amdgcn_mfma_f32_16x16x32_bf16(a[1], b, acc[1][nt], 0, 0, 0);
        }
    }
    #pragma unroll
    for (int mi = 0; mi < 2; mi++) {
        #pragma unroll
        for (int nt = 0; nt < 4; nt++) {
            int gn = bn + nt * 16 + lr;
            #pragma unroll
            for (int j = 0; j < 4; j++) {
                int gm = bm + mi * 16 + lk * 4 + j;
                if (gm < M)
                    Cf8[(size_t)gm * N + gn] = f2f8(acc[mi][nt][j]);
            }
        }
    }
    // fused attention-logit epilogue (fp32 accuracy, no extra memory pass)
    float ws0 = as_w[bn + lr], ws1 = as_w[bn + 16 + lr];
    float ws2 = as_w[bn + 32 + lr], ws3 = as_w[bn + 48 + lr];
    float wd0 = ad_w[bn + lr], wd1 = ad_w[bn + 16 + lr];
    float wd2 = ad_w[bn + 32 + lr], wd3 = ad_w[bn + 48 + lr];
    float sA[2][4], dA[2][4], sB[2][4], dB[2][4];
    #pragma unroll
    for (int mi = 0; mi < 2; mi++)
        #pragma unroll
        for (int j = 0; j < 4; j++) {
            if constexpr (ATT == 1) {
                sA[mi][j] = acc[mi][0][j] * ws0 + acc[mi][1][j] * ws1;
                sB[mi][j] = acc[mi][2][j] * ws2 + acc[mi][3][j] * ws3;
                dA[mi][j] = acc[mi][0][j] * wd0 + acc[mi][1][j] * wd1;
                dB[mi][j] = acc[mi][2][j] * wd2 + acc[mi][3][j] * wd3;
            } else {
                sA[mi][j] = acc[mi][0][j] * ws0 + acc[mi][1][j] * ws1
                          + acc[mi][2][j] * ws2 + acc[mi][3][j] * ws3;
                dA[mi][j] = acc[mi][0][j] * wd0 + acc[mi][1][j] * wd1
                          + acc[mi][2][j] * wd2 + acc[mi][3][j] * wd3;
                sB[mi][j] = 0.f; dB[mi][j] = 0.f;
            }
        }
    #pragma unroll
    for (int off = 1; off < 16; off <<= 1) {
        #pragma unroll
        for (int mi = 0; mi < 2; mi++)
            #pragma unroll
            for (int j = 0; j < 4; j++) {
                sA[mi][j] += __shfl_xor(sA[mi][j], off);
                dA[mi][j] += __shfl_xor(dA[mi][j], off);
                if constexpr (ATT == 1) {
                    sB[mi][j] += __shfl_xor(sB[mi][j], off);
                    dB[mi][j] += __shfl_xor(dB[mi][j], off);
                }
            }
    }
    if (lr == 0) {
        #pragma unroll
        for (int mi = 0; mi < 2; mi++)
            #pragma unroll
            for (int j = 0; j < 4; j++) {
                int row = bm + mi * 16 + lk * 4 + j;
                if (row < M) {
                    if constexpr (ATT == 1) {
                        int h0 = bn >> 5;
                        a_s[(size_t)row * 8 + h0]     = sA[mi][j];
                        a_s[(size_t)row * 8 + h0 + 1] = sB[mi][j];
                        a_d[(size_t)row * 8 + h0]     = dA[mi][j];
                        a_d[(size_t)row * 8 + h0 + 1] = dB[mi][j];
                    } else {
                        atomicAdd(&a_s[row], sA[mi][j]);
                        atomicAdd(&a_d[row], dA[mi][j]);
                    }
                }
            }
    }
}

// ---------------- fused FC head via MFMA ----------------

__global__ __launch_bounds__(256) void fc_mfma_kernel(const __hip_bfloat16* __restrict__ A,
                                                      const __hip_bfloat16* __restrict__ Bp,
                                                      const float* __restrict__ fcb1,
                                                      const float* __restrict__ fcW2,
                                                      const float* __restrict__ fcb2,
                                                      float* __restrict__ out) {
    __shared__ float red[4][32];
    int w = threadIdx.x >> 6, l = threadIdx.x & 63;
    int bm = blockIdx.x * 32;
    int lr = l & 15, lk = l >> 4;
    const int K = HID2, KS = K >> 5;
    const short* Ab = (const short*)A;
    const short* Bb = (const short*)Bp;
    v4f acc[2][8];
    #pragma unroll
    for (int mi = 0; mi < 2; mi++)
        #pragma unroll
        for (int nt = 0; nt < 8; nt++) acc[mi][nt] = (v4f)(0.f);
    for (int ks = 0; ks < KS; ks++) {
        v8s a[2];
        #pragma unroll
        for (int mi = 0; mi < 2; mi++) {
            int gm = bm + mi * 16 + lr;
            a[mi] = (gm < NN) ? *(const v8s*)(Ab + (size_t)gm * K + ks * 32 + lk * 8)
                              : (v8s)(short)0;
        }
        #pragma unroll
        for (int nt = 0; nt < 8; nt++) {
            int ntile = w * 8 + nt;
            v8s b = *(const v8s*)(Bb + ((size_t)(ntile * KS + ks) * 64 + l) * 8);
            acc[0][nt] = __builtin_amdgcn_mfma_f32_16x16x32_bf16(a[0], b, acc[0][nt], 0, 0, 0);
            acc[1][nt] = __builtin_amdgcn_mfma_f32_16x16x32_bf16(a[1], b, acc[1][nt], 0, 0, 0);
        }
    }
    float p[2][4];
    #pragma unroll
    for (int mi = 0; mi < 2; mi++)
        #pragma unroll
        for (int j = 0; j < 4; j++) p[mi][j] = 0.f;
    #pragma unroll
    for (int nt = 0; nt < 8; nt++) {
        int col = w * 128 + nt * 16 + lr;
        float b1v = fcb1[col], w2v = fcW2[col];
        #pragma unroll
        for (int mi = 0; mi < 2; mi++) {
            #pragma unroll
            for (int j = 0; j < 4; j++) {
                float v = acc[mi][nt][j] + b1v;
                p[mi][j] += ((v > 0.f) ? v : 0.f) * w2v;
            }
        }
    }
    #pragma unroll
    for (int mi = 0; mi < 2; mi++)
        #pragma unroll
        for (int j = 0; j < 4; j++) {
            float v = p[mi][j];
            v += __shfl_xor(v, 1);
            v += __shfl_xor(v, 2);
            v += __shfl_xor(v, 4);
            v += __shfl_xor(v, 8);
            p[mi][j] = v;
        }
    if (lr == 0) {
        #pragma unroll
        for (int mi = 0; mi < 2; mi++)
            #pragma unroll
            for (int j = 0; j < 4; j++) red[w][mi * 16 + lk * 4 + j] = p[mi][j];
    }
    __syncthreads();
    int tid = threadIdx.x;
    if (tid < 32) {
        int gm = bm + tid;
        if (gm < NN)
            out[gm] = red[0][tid] + red[1][tid] + red[2][tid] + red[3][tid] + fcb2[0];
    }
}

// ---------------- fused layer-1 softmax + aggregation ----------------
// KM buckets: for KM<=4, rounds==KM exactly -> branch-free batched gathers.

template <int KM>
__device__ __forceinline__ void gat1_fast(int lane, int start, int cnt,
                                          const int2* __restrict__ pairs,
                                          const float* __restrict__ a_s, float ad,
                                          const unsigned char* __restrict__ hf8,
                                          float* __restrict__ alpha1_out,
                                          float& acc0, float& acc1, float& acc2, float& acc3) {
    int h = lane & 7, j = lane >> 3;
    int hl = lane >> 3;
    int cl = min(lane, cnt - 1);
    int2 ep = pairs[start + cl];
    int e_all = ep.x, s_all = ep.y;
    float ex[KM];
    int sj[KM];
    #pragma unroll
    for (int k = 0; k < KM; k++) {
        int idx = j + k * 8;
        sj[k] = __shfl(s_all, idx);
        float v = a_s[(size_t)sj[k] * 8 + h] + ad;
        v = (v >= 0.f) ? v : NEG_SLOPE * v;
        ex[k] = (idx < cnt) ? v : -INFINITY;
    }
    float m = ex[0];
    #pragma unroll
    for (int k = 1; k < KM; k++) m = fmaxf(m, ex[k]);
    m = fmaxf(m, __shfl_xor(m, 8));
    m = fmaxf(m, __shfl_xor(m, 16));
    m = fmaxf(m, __shfl_xor(m, 32));
    float s = 0.f;
    #pragma unroll
    for (int k = 0; k < KM; k++) {
        ex[k] = expf(ex[k] - m);
        s += ex[k];
    }
    s += __shfl_xor(s, 8);
    s += __shfl_xor(s, 16);
    s += __shfl_xor(s, 32);
    float inv = 1.f / (s + 1e-16f);
    #pragma unroll
    for (int k = 0; k < KM; k++) ex[k] *= inv;
    #pragma unroll
    for (int k = 0; k < KM; k++) {
        int idx = j + k * 8;
        int eo = __shfl(e_all, idx);
        if (idx < cnt) alpha1_out[(size_t)eo * 8 + h] = ex[k];
    }
    unsigned int pk[KM];
    #pragma unroll
    for (int k = 0; k < KM; k++)
        pk[k] = ((unsigned int)sj[k] << 16) | (unsigned int)f2bf(ex[k]);

    if constexpr (KM <= 2) {
        // branch-free full batch (8 or 16 gathers in flight)
        const int NB = KM * 8;
        float At[NB];
        unsigned int qt[NB];
        #pragma unroll
        for (int t = 0; t < NB; t++) {
            unsigned int wv = (unsigned int)__shfl((int)pk[t >> 3], (t & 7) * 8 + hl);
            At[t] = bf2f((unsigned short)wv);
            qt[t] = *(const unsigned int*)(hf8 + (size_t)(wv >> 16) * HID1 + lane * 4);
        }
        #pragma unroll
        for (int t = 0; t < NB; t++) {
            float f0, f1, f2, f3;
            f8x4(qt[t], f0, f1, f2, f3);
            acc0 += At[t] * f0;
            acc1 += At[t] * f1;
            acc2 += At[t] * f2;
            acc3 += At[t] * f3;
        }
    } else if constexpr (KM <= 4) {
        // branch-free, two halves to cap register pressure
        const int HB = KM * 4;
        #pragma unroll
        for (int half = 0; half < 2; half++) {
            float At[HB];
            unsigned int qt[HB];
            #pragma unroll
            for (int t = 0; t < HB; t++) {
                int tt = half * HB + t;
                unsigned int wv = (unsigned int)__shfl((int)pk[tt >> 3], (tt & 7) * 8 + hl);
                At[t] = bf2f((unsigned short)wv);
                qt[t] = *(const unsigned int*)(hf8 + (size_t)(wv >> 16) * HID1 + lane * 4);
            }
            #pragma unroll
            for (int t = 0; t < HB; t++) {
                float f0, f1, f2, f3;
                f8x4(qt[t], f0, f1, f2, f3);
                acc0 += At[t] * f0;
                acc1 += At[t] * f1;
                acc2 += At[t] * f2;
                acc3 += At[t] * f3;
            }
        }
    } else {
        int rounds = (cnt + 7) >> 3;
        #pragma unroll
        for (int K = 0; K < KM; K++) {
            if (K < rounds) {
                float At[8];
                unsigned int qt[8];
                #pragma unroll
                for (int t = 0; t < 8; t++) {
                    unsigned int wv = (unsigned int)__shfl((int)pk[K], t * 8 + hl);
                    At[t] = bf2f((unsigned short)wv);
                    qt[t] = *(const unsigned int*)(hf8 + (size_t)(wv >> 16) * HID1 + lane * 4);
                }
                #pragma unroll
                for (int t = 0; t < 8; t++) {
                    float f0, f1, f2, f3;
                    f8x4(qt[t], f0, f1, f2, f3);
                    acc0 += At[t] * f0;
                    acc1 += At[t] * f1;
                    acc2 += At[t] * f2;
                    acc3 += At[t] * f3;
                }
            }
        }
    }
}

__global__ __launch_bounds__(256) void gat1_kernel(const int* __restrict__ row_ptr,
                                                   const int2* __restrict__ pairs,
                                                   const float* __restrict__ a_s,
                                                   const float* __restrict__ a_d,
                                                   const unsigned char* __restrict__ h1f8,
                                                   const float* __restrict__ b1,
                                                   float* __restrict__ alpha1_out,
                                                   __hip_bfloat16* __restrict__ x1bf) {
    int wv = threadIdx.x >> 6, lane = threadIdx.x & 63;
    int n = blockIdx.x * 4 + wv;
    if (n >= NN) return;
    int start = row_ptr[n], end = row_ptr[n + 1];
    int cnt = end - start;
    int h = lane & 7, j = lane >> 3;
    int hl = lane >> 3;
    float acc0 = 0.f, acc1 = 0.f, acc2 = 0.f, acc3 = 0.f;
    if (cnt > 0 && cnt <= 64) {
        float ad = a_d[(size_t)n * 8 + h];
        if (cnt <= 8)
            gat1_fast<1>(lane, start, cnt, pairs, a_s, ad, h1f8, alpha1_out, acc0, acc1, acc2, acc3);
        else if (cnt <= 16)
            gat1_fast<2>(lane, start, cnt, pairs, a_s, ad, h1f8, alpha1_out, acc0, acc1, acc2, acc3);
        else if (cnt <= 24)
            gat1_fast<3>(lane, start, cnt, pairs, a_s, ad, h1f8, alpha1_out, acc0, acc1, acc2, acc3);
        else if (cnt <= 32)
            gat1_fast<4>(lane, start, cnt, pairs, a_s, ad, h1f8, alpha1_out, acc0, acc1, acc2, acc3);
        else
            gat1_fast<8>(lane, start, cnt, pairs, a_s, ad, h1f8, alpha1_out, acc0, acc1, acc2, acc3);
    } else if (cnt > 64) {
        float ad = a_d[(size_t)n * 8 + h];
        float m = -INFINITY;
        for (int p = start + j; p < end; p += 8) {
            float v = a_s[(size_t)pairs[p].y * 8 + h] + ad;
            v = (v >= 0.f) ? v : NEG_SLOPE * v;
            m = fmaxf(m, v);
        }
        m = fmaxf(m, __shfl_xor(m, 8));
        m = fmaxf(m, __shfl_xor(m, 16));
        m = fmaxf(m, __shfl_xor(m, 32));
        float s = 0.f;
        for (int p = start + j; p < end; p += 8) {
            float v = a_s[(size_t)pairs[p].y * 8 + h] + ad;
            v = (v >= 0.f) ? v : NEG_SLOPE * v;
            s += expf(v - m);
        }
        s += __shfl_xor(s, 8);
        s += __shfl_xor(s, 16);
        s += __shfl_xor(s, 32);
        float inv = 1.f / (s + 1e-16f);
        for (int p = start + j; p < end; p += 8) {
            int2 ep = pairs[p];
            float v = a_s[(size_t)ep.y * 8 + h] + ad;
            v = (v >= 0.f) ? v : NEG_SLOPE * v;
            alpha1_out[(size_t)ep.x * 8 + h] = expf(v - m) * inv;
        }
        float mh = __shfl(m, hl);
        float invh = __shfl(inv, hl);
        float adh = __shfl(ad, hl);
        for (int p = start; p < end; p++) {
            int sp = pairs[p].y;
            float v = a_s[(size_t)sp * 8 + hl] + adh;
            v = (v >= 0.f) ? v : NEG_SLOPE * v;
            float al = expf(v - mh) * invh;
            unsigned int q = *(const unsigned int*)(h1f8 + (size_t)sp * HID1 + lane * 4);
            float f0, f1, f2, f3;
            f8x4(q, f0, f1, f2, f3);
            acc0 += al * f0;
            acc1 += al * f1;
            acc2 += al * f2;
            acc3 += al * f3;
        }
    }
    float4 bb = *(const float4*)(b1 + lane * 4);
    float r0 = acc0 + bb.x, r1 = acc1 + bb.y, r2 = acc2 + bb.z, r3 = acc3 + bb.w;
    r0 = (r0 > 0.f) ? r0 : expf(r0) - 1.f;
    r1 = (r1 > 0.f) ? r1 : expf(r1) - 1.f;
    r2 = (r2 > 0.f) ? r2 : expf(r2) - 1.f;
    r3 = (r3 > 0.f) ? r3 : expf(r3) - 1.f;
    ushort4 o;
    o.x = f2bf(r0); o.y = f2bf(r1); o.z = f2bf(r2); o.w = f2bf(r3);
    *(ushort4*)((unsigned short*)x1bf + (size_t)n * HID1 + lane * 4) = o;
}

// ---------------- fused layer-2 softmax + aggregation ----------------

__global__ __launch_bounds__(256) void gat2_kernel(const int* __restrict__ row_ptr,
                                                   const int2* __restrict__ pairs,
                                                   const float* __restrict__ a_s,
                                                   const float* __restrict__ a_d,
                                                   const unsigned char* __restrict__ h2f8,
                                                   const float* __restrict__ b2,
                                                   float* __restrict__ alpha2_out,
                                                   __hip_bfloat16* __restrict__ x2bf) {
    int wv = threadIdx.x >> 6, lane = threadIdx.x & 63;
    int n = blockIdx.x * 4 + wv;
    if (n >= NN) return;
    int start = row_ptr[n], end = row_ptr[n + 1];
    int cnt = end - start;
    int r = lane >> 5, c = lane & 31;
    float acc0 = 0.f, acc1 = 0.f, acc2 = 0.f, acc3 = 0.f;
    if (cnt > 0 && cnt <= 64) {
        float ad = a_d[n];
        bool act = lane < cnt;
        int ii = min(lane, cnt - 1);
        int2 ep = pairs[start + ii];
        int sj = ep.y;
        float v = a_s[sj] + ad;
        v = (v >= 0.f) ? v : NEG_SLOPE * v;
        float e = act ? v : -INFINITY;
        float m = e;
        #pragma unroll
        for (int off = 1; off < 64; off <<= 1) m = fmaxf(m, __shfl_xor(m, off));
        float ex = expf(e - m);
        float s = ex;
        #pragma unroll
        for (int off = 1; off < 64; off <<= 1) s += __shfl_xor(s, off);
        float al = ex / (s + 1e-16f);
        if (act) alpha2_out[ep.x] = al;
        unsigned int pk = ((unsigned int)sj << 16) | (unsigned int)f2bf(al);
        int rounds = (cnt + 7) >> 3;
        if (rounds <= 2) {
            int nb = rounds * 4;  // wave-uniform
            float At[8];
            unsigned int qt[8];
            #pragma unroll
            for (int t = 0; t < 8; t++) {
                if (t < nb) {
                    int je = (t >> 2) * 8 + (t & 3) * 2 + r;
                    unsigned int wq = (unsigned int)__shfl((int)pk, je);
                    At[t] = bf2f((unsigned short)wq);
                    qt[t] = *(const unsigned int*)(h2f8 + (size_t)(wq >> 16) * HID2 + c * 4);
                }
            }
            #pragma unroll
            for (int t = 0; t < 8; t++) {
                if (t < nb) {
                    float f0, f1, f2, f3;
                    f8x4(qt[t], f0, f1, f2, f3);
                    acc0 += At[t] * f0;
                    acc1 += At[t] * f1;
                    acc2 += At[t] * f2;
                    acc3 += At[t] * f3;
                }
            }
        } else {
            #pragma unroll
            for (int K = 0; K < 8; K++) {
                if (K < rounds) {
                    float At[4];
                    unsigned int qt[4];
                    #pragma unroll
                    for (int t = 0; t < 4; t++) {
                        int je = K * 8 + t * 2 + r;
                        unsigned int wq = (unsigned int)__shfl((int)pk, je);
                        At[t] = bf2f((unsigned short)wq);
                        qt[t] = *(const unsigned int*)(h2f8 + (size_t)(wq >> 16) * HID2 + c * 4);
                    }
                    #pragma unroll
                    for (int t = 0; t < 4; t++) {
                        float f0, f1, f2, f3;
                        f8x4(qt[t], f0, f1, f2, f3);
                        acc0 += At[t] * f0;
                        acc1 += At[t] * f1;
                        acc2 += At[t] * f2;
                        acc3 += At[t] * f3;
                    }
                }
            }
        }
    } else if (cnt > 64) {
        float ad = a_d[n];
        float m = -INFINITY;
        for (int p = start + lane; p < end; p += 64) {
            float v = a_s[pairs[p].y] + ad;
            v = (v >= 0.f) ? v : NEG_SLOPE * v;
            m = fmaxf(m, v);
        }
        for (int off = 32; off; off >>= 1) m = fmaxf(m, __shfl_xor(m, off));
        float s = 0.f;
        for (int p = start + lane; p < end; p += 64) {
            float v = a_s[pairs[p].y] + ad;
            v = (v >= 0.f) ? v : NEG_SLOPE * v;
            s += expf(v - m);
        }
        for (int off = 32; off; off >>= 1) s += __shfl_xor(s, off);
        float inv = 1.f / (s + 1e-16f);
        for (int p = start + lane; p < end; p += 64) {
            int2 ep = pairs[p];
            float v = a_s[ep.y] + ad;
            v = (v >= 0.f) ? v : NEG_SLOPE * v;
            alpha2_out[ep.x] = expf(v - m) * inv;
        }
        for (int p = start + r; p < end; p += 2) {
            int sp = pairs[p].y;
            float v = a_s[sp] + ad;
            v = (v >= 0.f) ? v : NEG_SLOPE * v;
            float al = expf(v - m) * inv;
            unsigned int q = *(const unsigned int*)(h2f8 + (size_t)sp * HID2 + c * 4);
            float f0, f1, f2, f3;
            f8x4(q, f0, f1, f2, f3);
            acc0 += al * f0;
            acc1 += al * f1;
            acc2 += al * f2;
            acc3 += al * f3;
        }
    }
    acc0 += __shfl_xor(acc0, 32);
    acc1 += __shfl_xor(acc1, 32);
    acc2 += __shfl_xor(acc2, 32);
    acc3 += __shfl_xor(acc3, 32);
    if (r == 0) {
        float4 bb = *(const float4*)(b2 + c * 4);
        float r0 = acc0 + bb.x, r1 = acc1 + bb.y, r2 = acc2 + bb.z, r3 = acc3 + bb.w;
        r0 = (r0 > 0.f) ? r0 : 0.f;
        r1 = (r1 > 0.f) ? r1 : 0.f;
        r2 = (r2 > 0.f) ? r2 : 0.f;
        r3 = (r3 > 0.f) ? r3 : 0.f;
        ushort4 o;
        o.x = f2bf(r0); o.y = f2bf(r1); o.z = f2bf(r2); o.w = f2bf(r3);
        *(ushort4*)((unsigned short*)x2bf + (size_t)n * HID2 + c * 4) = o;
    }
}

// ---------------- host launch ----------------

extern "C" void kernel_launch(void* const* d_in, const int* in_sizes, int n_in,
                              void* d_out, int out_size, void* d_ws, size_t ws_size,
                              hipStream_t stream) {
    (void)in_sizes; (void)n_in; (void)out_size; (void)ws_size;
    const float* x        = (const float*)d_in[0];
    const int*   eindex   = (const int*)d_in[1];
    const float* W1       = (const float*)d_in[2];
    const float* att_src1 = (const float*)d_in[3];
    const float* att_dst1 = (const float*)d_in[4];
    const float* b1       = (const float*)d_in[5];
    const float* W2       = (const float*)d_in[6];
    const float* att_src2 = (const float*)d_in[7];
    const float* att_dst2 = (const float*)d_in[8];
    const float* b2       = (const float*)d_in[9];
    const float* fcW1     = (const float*)d_in[10];
    const float* fcb1     = (const float*)d_in[11];
    const float* fcW2     = (const float*)d_in[12];
    const float* fcb2     = (const float*)d_in[13];

    const int* src = eindex;
    const int* dst = eindex + EE;

    float* out_n      = (float*)d_out;               // [N]
    float* alpha1_out = out_n + NN;                  // [E,8]
    float* alpha2_out = alpha1_out + (size_t)EE * 8; // [E]

    char* ws = (char*)d_ws;
    size_t off = 0;
    auto alloc = [&](size_t bytes) {
        size_t o = off;
        off = (off + bytes + 255) & ~(size_t)255;
        return o;
    };
    size_t o_rowptr = alloc((NN + 1) * sizeof(int));
    size_t o_cursor = alloc(NN * sizeof(int));
    size_t o_counts = alloc(NN * sizeof(int));
    size_t o_excl   = alloc(NN * sizeof(int));
    size_t o_bsum   = alloc(64 * sizeof(int));
    size_t o_pairs  = alloc((size_t)EE * sizeof(int2));
    size_t o_as1    = alloc((size_t)NN * H1 * sizeof(float));
    size_t o_ad1    = alloc((size_t)NN * H1 * sizeof(float));
    size_t o_as2    = alloc((size_t)NN * sizeof(float));
    size_t o_ad2    = alloc((size_t)NN * sizeof(float));
    size_t o_h1f8   = alloc((size_t)NN * HID1);
    size_t o_xbf    = alloc((size_t)NN * IN_DIM * sizeof(__hip_bfloat16));
    size_t o_x1bf   = alloc((size_t)NN * HID1 * sizeof(__hip_bfloat16));
    size_t o_h2f8   = alloc((size_t)NN * HID2);
    size_t o_x2bf   = alloc((size_t)NN * HID2 * sizeof(__hip_bfloat16));
    size_t o_W1p    = alloc((size_t)IN_DIM * HID1 * sizeof(__hip_bfloat16));
    size_t o_W2p    = alloc((size_t)HID1 * HID2 * sizeof(__hip_bfloat16));
    size_t o_fW1p   = alloc((size_t)HID2 * FC1 * sizeof(__hip_bfloat16));

    int*   row_ptr = (int*)(ws + o_rowptr);
    int*   cursor  = (int*)(ws + o_cursor);
    int*   counts  = (int*)(ws + o_counts);
    int*   excl    = (int*)(ws + o_excl);
    int*   bsum    = (int*)(ws + o_bsum);
    int2*  pairs   = (int2*)(ws + o_pairs);
    float* a_s1    = (float*)(ws + o_as1);
    float* a_d1    = (float*)(ws + o_ad1);
    float* a_s2    = (float*)(ws + o_as2);
    float* a_d2    = (float*)(ws + o_ad2);
    unsigned char*  h1f8  = (unsigned char*)(ws + o_h1f8);
    __hip_bfloat16* xbf   = (__hip_bfloat16*)(ws + o_xbf);
    __hip_bfloat16* x1bf  = (__hip_bfloat16*)(ws + o_x1bf);
    unsigned char*  h2f8  = (unsigned char*)(ws + o_h2f8);
    __hip_bfloat16* x2bf  = (__hip_bfloat16*)(ws + o_x2bf);
    __hip_bfloat16* W1p   = (__hip_bfloat16*)(ws + o_W1p);
    __hip_bfloat16* W2p   = (__hip_bfloat16*)(ws + o_W2p);
    __hip_bfloat16* fW1p  = (__hip_bfloat16*)(ws + o_fW1p);

    const int SCAN_NB = (NN + 1023) / 1024;  // 49
    const int PREP_N = NN * IN_DIM + IN_DIM * HID1 + HID1 * HID2 + HID2 * FC1;

    // ---- zero counts + layer-2 logit accumulators ----
    hipMemsetAsync(counts, 0, NN * sizeof(int), stream);
    hipMemsetAsync(a_s2, 0, NN * sizeof(float), stream);
    hipMemsetAsync(a_d2, 0, NN * sizeof(float), stream);

    // ---- build CSR by dst ----
    hist_kernel<<<(EE + 255) / 256, 256, 0, stream>>>(dst, counts);
    scan_a_kernel<<<SCAN_NB, 256, 0, stream>>>(counts, excl, bsum, NN);
    scan_b_kernel<<<1, 64, 0, stream>>>(bsum, row_ptr, SCAN_NB, NN);
    scan_c_kernel<<<SCAN_NB, 256, 0, stream>>>(excl, bsum, row_ptr, cursor, NN);
    scatter_kernel<<<(EE + 255) / 256, 256, 0, stream>>>(src, dst, cursor, pairs);

    // ---- fused input conversion / weight packing ----
    prep_kernel<<<(PREP_N + 255) / 256, 256, 0, stream>>>(x, xbf, W1, W1p, W2, W2p, fcW1, fW1p);

    // ---- layer 1 (GEMM + fused att logits) ----
    mgemm_kernel<1><<<dim3((NN + 127) / 128, HID1 / 64), 256, 0, stream>>>(
        xbf, W1p, h1f8, att_src1, att_dst1, a_s1, a_d1, NN, IN_DIM, HID1);
    gat1_kernel<<<(NN + 3) / 4, 256, 0, stream>>>(row_ptr, pairs, a_s1, a_d1,
                                                  h1f8, b1, alpha1_out, x1bf);

    // ---- layer 2 (GEMM + fused att logits via atomics) ----
    mgemm_kernel<2><<<dim3((NN + 127) / 128, HID2 / 64), 256, 0, stream>>>(
        x1bf, W2p, h2f8, att_src2, att_dst2, a_s2, a_d2, NN, HID1, HID2);
    gat2_kernel<<<(NN + 3) / 4, 256, 0, stream>>>(row_ptr, pairs, a_s2, a_d2,
                                                  h2f8, b2, alpha2_out, x2bf);

    // ---- FC head ----
    fc_mfma_kernel<<<(NN + 31) / 32, 256, 0, stream>>>(x2bf, fW1p, fcb1, fcW2, fcb2, out_n);
}

// Round 14
// 264.459 us; speedup vs baseline: 1.6727x; 1.0074x over previous
//
#include <hip/hip_runtime.h>
#include <hip/hip_bf16.h>
#include <hip/hip_fp8.h>
#include <math.h>

#define NN 50000
#define EE 800000
#define IN_DIM 128
#define H1 8
#define D1 32
#define HID1 256
#define HID2 128
#define FC1 512
#define NEG_SLOPE 0.2f

typedef short v8s __attribute__((ext_vector_type(8)));
typedef float v4f __attribute__((ext_vector_type(4)));
typedef float v2f __attribute__((ext_vector_type(2)));
typedef unsigned int v4u __attribute__((ext_vector_type(4)));

__device__ __forceinline__ float bf2f(unsigned short u) {
    unsigned int x = ((unsigned int)u) << 16;
    return __uint_as_float(x);
}
__device__ __forceinline__ unsigned short f2bf(float v) {
    __hip_bfloat16 h = __float2bfloat16(v);
    return *(unsigned short*)&h;
}
__device__ __forceinline__ unsigned char f2f8(float v) {
    __hip_fp8_e4m3 t(v);
    return (unsigned char)t.__x;
}
__device__ __forceinline__ float f8tof(unsigned char u) {
    __hip_fp8_e4m3 t;
    t.__x = (__hip_fp8_storage_t)u;
    return (float)t;
}

__device__ __forceinline__ void f8x4(unsigned int w, float& f0, float& f1, float& f2, float& f3) {
#if __has_builtin(__builtin_amdgcn_cvt_pk_f32_fp8)
    v2f lo = __builtin_amdgcn_cvt_pk_f32_fp8((int)w, false);
    v2f hi = __builtin_amdgcn_cvt_pk_f32_fp8((int)w, true);
    f0 = lo[0]; f1 = lo[1]; f2 = hi[0]; f3 = hi[1];
#else
    f0 = f8tof((unsigned char)(w & 0xff));
    f1 = f8tof((unsigned char)((w >> 8) & 0xff));
    f2 = f8tof((unsigned char)((w >> 16) & 0xff));
    f3 = f8tof((unsigned char)(w >> 24));
#endif
}

// ---------------- CSR build ----------------

__global__ void hist_kernel(const int* __restrict__ dst, int* __restrict__ counts) {
    int e = blockIdx.x * blockDim.x + threadIdx.x;
    if (e < EE) atomicAdd(&counts[dst[e]], 1);
}

__global__ __launch_bounds__(256) void scan_a_kernel(const int* __restrict__ counts,
                                                     int* __restrict__ excl,
                                                     int* __restrict__ bsum, int n) {
    __shared__ int wsum[4];
    int tid = threadIdx.x;
    int base = blockIdx.x * 1024 + tid * 4;
    int v0 = 0, v1 = 0, v2 = 0, v3 = 0;
    if (base + 3 < n) {
        int4 t = *(const int4*)(counts + base);
        v0 = t.x; v1 = t.y; v2 = t.z; v3 = t.w;
    } else {
        if (base + 0 < n) v0 = counts[base + 0];
        if (base + 1 < n) v1 = counts[base + 1];
        if (base + 2 < n) v2 = counts[base + 2];
        if (base + 3 < n) v3 = counts[base + 3];
    }
    int tot = v0 + v1 + v2 + v3;
    int lane = tid & 63;
    int w = tid >> 6;
    int x = tot;
    #pragma unroll
    for (int off = 1; off < 64; off <<= 1) {
        int y = __shfl_up(x, off);
        if (lane >= off) x += y;
    }
    if (lane == 63) wsum[w] = x;
    __syncthreads();
    int woff = 0;
    for (int i = 0; i < w; i++) woff += wsum[i];
    int et = woff + x - tot;
    if (base + 0 < n) excl[base + 0] = et;
    if (base + 1 < n) excl[base + 1] = et + v0;
    if (base + 2 < n) excl[base + 2] = et + v0 + v1;
    if (base + 3 < n) excl[base + 3] = et + v0 + v1 + v2;
    if (tid == 255) bsum[blockIdx.x] = woff + x;
}

__global__ __launch_bounds__(64) void scan_b_kernel(int* __restrict__ bsum,
                                                    int* __restrict__ row_ptr, int nb, int n) {
    int lane = threadIdx.x;
    int v = (lane < nb) ? bsum[lane] : 0;
    int x = v;
    #pragma unroll
    for (int off = 1; off < 64; off <<= 1) {
        int y = __shfl_up(x, off);
        if (lane >= off) x += y;
    }
    if (lane < nb) bsum[lane] = x - v;
    if (lane == 63) row_ptr[n] = x;
}

__global__ __launch_bounds__(256) void scan_c_kernel(const int* __restrict__ excl,
                                                     const int* __restrict__ bsum,
                                                     int* __restrict__ row_ptr,
                                                     int* __restrict__ cursor, int n) {
    int base = blockIdx.x * 1024 + threadIdx.x * 4;
    int off = bsum[blockIdx.x];
    #pragma unroll
    for (int j = 0; j < 4; j++) {
        int i = base + j;
        if (i < n) {
            int r = excl[i] + off;
            row_ptr[i] = r;
            cursor[i] = r;
        }
    }
}

__global__ void scatter_kernel(const int* __restrict__ src, const int* __restrict__ dst,
                               int* __restrict__ cursor, int2* __restrict__ pairs) {
    int e = blockIdx.x * blockDim.x + threadIdx.x;
    if (e >= EE) return;
    int d = dst[e];
    int p = atomicAdd(&cursor[d], 1);
    pairs[p] = make_int2(e, src[e]);
}

// ---- fused prep ----

__device__ __forceinline__ void pack_one(const float* __restrict__ B,
                                         __hip_bfloat16* __restrict__ Bp,
                                         int K, int N, int idx) {
    int k = idx / N, n = idx % N;
    int ntile = n >> 4, ks = k >> 5, kk = k & 31;
    int lane = (n & 15) | ((kk >> 3) << 4);
    int j = kk & 7;
    int KS = K >> 5;
    Bp[((size_t)(ntile * KS + ks) * 64 + lane) * 8 + j] = __float2bfloat16(B[idx]);
}

__global__ void prep_kernel(const float* __restrict__ x, __hip_bfloat16* __restrict__ xbf,
                            const float* __restrict__ W1, __hip_bfloat16* __restrict__ W1p,
                            const float* __restrict__ W2, __hip_bfloat16* __restrict__ W2p,
                            const float* __restrict__ fcW1, __hip_bfloat16* __restrict__ fW1p) {
    int i = blockIdx.x * blockDim.x + threadIdx.x;
    const int N0 = NN * IN_DIM;
    const int N1 = N0 + IN_DIM * HID1;
    const int N2 = N1 + HID1 * HID2;
    const int N3 = N2 + HID2 * FC1;
    if (i < N0) xbf[i] = __float2bfloat16(x[i]);
    else if (i < N1) pack_one(W1, W1p, IN_DIM, HID1, i - N0);
    else if (i < N2) pack_one(W2, W2p, HID1, HID2, i - N1);
    else if (i < N3) pack_one(fcW1, fW1p, HID2, FC1, i - N2);
}

// ---------------- MFMA GEMM (bf16 in, fp8 out) + fused attention logits ----------------

template <int ATT>
__global__ __launch_bounds__(256) void mgemm_kernel(const __hip_bfloat16* __restrict__ A,
                                                    const __hip_bfloat16* __restrict__ Bp,
                                                    unsigned char* __restrict__ Cf8,
                                                    const float* __restrict__ as_w,
                                                    const float* __restrict__ ad_w,
                                                    float* __restrict__ a_s,
                                                    float* __restrict__ a_d,
                                                    int M, int K, int N) {
    int w = threadIdx.x >> 6, l = threadIdx.x & 63;
    int bm = blockIdx.x * 128 + w * 32;
    int bn = blockIdx.y * 64;
    int lr = l & 15, lk = l >> 4;
    int KS = K >> 5;
    const short* Ab = (const short*)A;
    const short* Bb = (const short*)Bp;
    v4f acc[2][4];
    #pragma unroll
    for (int mi = 0; mi < 2; mi++)
        #pragma unroll
        for (int nt = 0; nt < 4; nt++) acc[mi][nt] = (v4f)(0.f);
    for (int ks = 0; ks < KS; ks++) {
        v8s a[2];
        #pragma unroll
        for (int mi = 0; mi < 2; mi++) {
            int gm = bm + mi * 16 + lr;
            a[mi] = (gm < M) ? *(const v8s*)(Ab + (size_t)gm * K + ks * 32 + lk * 8)
                             : (v8s)(short)0;
        }
        #pragma unroll
        for (int nt = 0; nt < 4; nt++) {
            int ntile = (bn >> 4) + nt;
            v8s b = *(const v8s*)(Bb + ((size_t)(ntile * KS + ks) * 64 + l) * 8);
            acc[0][nt] = __builtin_amdgcn_mfma_f32_16x16x32_bf16(a[0], b, acc[0][nt], 0, 0, 0);
            acc[1][nt] = __builtin_amdgcn_mfma_f32_16x16x32_bf16(a[1], b, acc[1][nt], 0, 0, 0);
        }
    }
    #pragma unroll
    for (int mi = 0; mi < 2; mi++) {
        #pragma unroll
        for (int nt = 0; nt < 4; nt++) {
            int gn = bn + nt * 16 + lr;
            #pragma unroll
            for (int j = 0; j < 4; j++) {
                int gm = bm + mi * 16 + lk * 4 + j;
                if (gm < M)
                    Cf8[(size_t)gm * N + gn] = f2f8(acc[mi][nt][j]);
            }
        }
    }
    float ws0 = as_w[bn + lr], ws1 = as_w[bn + 16 + lr];
    float ws2 = as_w[bn + 32 + lr], ws3 = as_w[bn + 48 + lr];
    float wd0 = ad_w[bn + lr], wd1 = ad_w[bn + 16 + lr];
    float wd2 = ad_w[bn + 32 + lr], wd3 = ad_w[bn + 48 + lr];
    float sA[2][4], dA[2][4], sB[2][4], dB[2][4];
    #pragma unroll
    for (int mi = 0; mi < 2; mi++)
        #pragma unroll
        for (int j = 0; j < 4; j++) {
            if constexpr (ATT == 1) {
                sA[mi][j] = acc[mi][0][j] * ws0 + acc[mi][1][j] * ws1;
                sB[mi][j] = acc[mi][2][j] * ws2 + acc[mi][3][j] * ws3;
                dA[mi][j] = acc[mi][0][j] * wd0 + acc[mi][1][j] * wd1;
                dB[mi][j] = acc[mi][2][j] * wd2 + acc[mi][3][j] * wd3;
            } else {
                sA[mi][j] = acc[mi][0][j] * ws0 + acc[mi][1][j] * ws1
                          + acc[mi][2][j] * ws2 + acc[mi][3][j] * ws3;
                dA[mi][j] = acc[mi][0][j] * wd0 + acc[mi][1][j] * wd1
                          + acc[mi][2][j] * wd2 + acc[mi][3][j] * wd3;
                sB[mi][j] = 0.f; dB[mi][j] = 0.f;
            }
        }
    #pragma unroll
    for (int off = 1; off < 16; off <<= 1) {
        #pragma unroll
        for (int mi = 0; mi < 2; mi++)
            #pragma unroll
            for (int j = 0; j < 4; j++) {
                sA[mi][j] += __shfl_xor(sA[mi][j], off);
                dA[mi][j] += __shfl_xor(dA[mi][j], off);
                if constexpr (ATT == 1) {
                    sB[mi][j] += __shfl_xor(sB[mi][j], off);
                    dB[mi][j] += __shfl_xor(dB[mi][j], off);
                }
            }
    }
    if (lr == 0) {
        #pragma unroll
        for (int mi = 0; mi < 2; mi++)
            #pragma unroll
            for (int j = 0; j < 4; j++) {
                int row = bm + mi * 16 + lk * 4 + j;
                if (row < M) {
                    if constexpr (ATT == 1) {
                        int h0 = bn >> 5;
                        a_s[(size_t)row * 8 + h0]     = sA[mi][j];
                        a_s[(size_t)row * 8 + h0 + 1] = sB[mi][j];
                        a_d[(size_t)row * 8 + h0]     = dA[mi][j];
                        a_d[(size_t)row * 8 + h0 + 1] = dB[mi][j];
                    } else {
                        atomicAdd(&a_s[row], sA[mi][j]);
                        atomicAdd(&a_d[row], dA[mi][j]);
                    }
                }
            }
    }
}

// ---------------- fused FC head via MFMA ----------------

__global__ __launch_bounds__(256) void fc_mfma_kernel(const __hip_bfloat16* __restrict__ A,
                                                      const __hip_bfloat16* __restrict__ Bp,
                                                      const float* __restrict__ fcb1,
                                                      const float* __restrict__ fcW2,
                                                      const float* __restrict__ fcb2,
                                                      float* __restrict__ out) {
    __shared__ float red[4][32];
    int w = threadIdx.x >> 6, l = threadIdx.x & 63;
    int bm = blockIdx.x * 32;
    int lr = l & 15, lk = l >> 4;
    const int K = HID2, KS = K >> 5;
    const short* Ab = (const short*)A;
    const short* Bb = (const short*)Bp;
    v4f acc[2][8];
    #pragma unroll
    for (int mi = 0; mi < 2; mi++)
        #pragma unroll
        for (int nt = 0; nt < 8; nt++) acc[mi][nt] = (v4f)(0.f);
    for (int ks = 0; ks < KS; ks++) {
        v8s a[2];
        #pragma unroll
        for (int mi = 0; mi < 2; mi++) {
            int gm = bm + mi * 16 + lr;
            a[mi] = (gm < NN) ? *(const v8s*)(Ab + (size_t)gm * K + ks * 32 + lk * 8)
                              : (v8s)(short)0;
        }
        #pragma unroll
        for (int nt = 0; nt < 8; nt++) {
            int ntile = w * 8 + nt;
            v8s b = *(const v8s*)(Bb + ((size_t)(ntile * KS + ks) * 64 + l) * 8);
            acc[0][nt] = __builtin_amdgcn_mfma_f32_16x16x32_bf16(a[0], b, acc[0][nt], 0, 0, 0);
            acc[1][nt] = __builtin_amdgcn_mfma_f32_16x16x32_bf16(a[1], b, acc[1][nt], 0, 0, 0);
        }
    }
    float p[2][4];
    #pragma unroll
    for (int mi = 0; mi < 2; mi++)
        #pragma unroll
        for (int j = 0; j < 4; j++) p[mi][j] = 0.f;
    #pragma unroll
    for (int nt = 0; nt < 8; nt++) {
        int col = w * 128 + nt * 16 + lr;
        float b1v = fcb1[col], w2v = fcW2[col];
        #pragma unroll
        for (int mi = 0; mi < 2; mi++) {
            #pragma unroll
            for (int j = 0; j < 4; j++) {
                float v = acc[mi][nt][j] + b1v;
                p[mi][j] += ((v > 0.f) ? v : 0.f) * w2v;
            }
        }
    }
    #pragma unroll
    for (int mi = 0; mi < 2; mi++)
        #pragma unroll
        for (int j = 0; j < 4; j++) {
            float v = p[mi][j];
            v += __shfl_xor(v, 1);
            v += __shfl_xor(v, 2);
            v += __shfl_xor(v, 4);
            v += __shfl_xor(v, 8);
            p[mi][j] = v;
        }
    if (lr == 0) {
        #pragma unroll
        for (int mi = 0; mi < 2; mi++)
            #pragma unroll
            for (int j = 0; j < 4; j++) red[w][mi * 16 + lk * 4 + j] = p[mi][j];
    }
    __syncthreads();
    int tid = threadIdx.x;
    if (tid < 32) {
        int gm = bm + tid;
        if (gm < NN)
            out[gm] = red[0][tid] + red[1][tid] + red[2][tid] + red[3][tid] + fcb2[0];
    }
}

// ---------------- fused layer-1 softmax + aggregation ----------------
// issue order: pairs -> a_s gathers -> ALL h-row gathers -> softmax VALU -> combine.
// vmcnt is in-order, so a_s (issued before rows) completes while rows stay in flight.

template <int KM>
__device__ __forceinline__ void gat1_fast(int lane, int start, int cnt,
                                          const int2* __restrict__ pairs,
                                          const float* __restrict__ a_s, float ad,
                                          const unsigned char* __restrict__ hf8,
                                          float* __restrict__ alpha1_out,
                                          float& acc0, float& acc1, float& acc2, float& acc3) {
    int h = lane & 7, j = lane >> 3;
    int hl = lane >> 3;
    int cl = min(lane, cnt - 1);
    int2 ep = pairs[start + cl];
    int e_all = ep.x, s_all = ep.y;
    unsigned int loff = (unsigned int)(lane << 2);

    if constexpr (KM <= 4) {
        constexpr int NB = KM * 8;
        // softmax-side a_s gathers (issued FIRST)
        int sj[KM];
        float ev[KM];
        #pragma unroll
        for (int k = 0; k < KM; k++) {
            int idx = j + k * 8;
            sj[k] = __shfl(s_all, idx);
            ev[k] = a_s[(size_t)sj[k] * 8 + h];  // load issues here
        }
        // early issue of ALL h-row gathers (32-bit offsets)
        unsigned int qt[NB];
        #pragma unroll
        for (int e = 0; e < NB; e++) {
            int sje = __shfl(s_all, e);
            qt[e] = *(const unsigned int*)(hf8 + (((unsigned int)sje << 8) | loff));
        }
        // softmax VALU (rows still in flight)
        float ex[KM];
        #pragma unroll
        for (int k = 0; k < KM; k++) {
            int idx = j + k * 8;
            float v = ev[k] + ad;
            v = (v >= 0.f) ? v : NEG_SLOPE * v;
            ex[k] = (idx < cnt) ? v : -INFINITY;
        }
        float m = ex[0];
        #pragma unroll
        for (int k = 1; k < KM; k++) m = fmaxf(m, ex[k]);
        m = fmaxf(m, __shfl_xor(m, 8));
        m = fmaxf(m, __shfl_xor(m, 16));
        m = fmaxf(m, __shfl_xor(m, 32));
        float s = 0.f;
        #pragma unroll
        for (int k = 0; k < KM; k++) {
            ex[k] = expf(ex[k] - m);
            s += ex[k];
        }
        s += __shfl_xor(s, 8);
        s += __shfl_xor(s, 16);
        s += __shfl_xor(s, 32);
        float inv = 1.f / (s + 1e-16f);
        #pragma unroll
        for (int k = 0; k < KM; k++) ex[k] *= inv;
        #pragma unroll
        for (int k = 0; k < KM; k++) {
            int idx = j + k * 8;
            int eo = __shfl(e_all, idx);
            if (idx < cnt) alpha1_out[(size_t)eo * 8 + h] = ex[k];
        }
        // combine: alpha shfl + fp8 cvt; rows arrive by now
        #pragma unroll
        for (int e = 0; e < NB; e++) {
            float At = __shfl(ex[e >> 3], (e & 7) * 8 + hl);
            float f0, f1, f2, f3;
            f8x4(qt[e], f0, f1, f2, f3);
            acc0 += At * f0;
            acc1 += At * f1;
            acc2 += At * f2;
            acc3 += At * f3;
        }
    } else {
        // KM==8 (rare): guarded rounds
        float ex[KM];
        int sj[KM];
        #pragma unroll
        for (int k = 0; k < KM; k++) {
            int idx = j + k * 8;
            sj[k] = __shfl(s_all, idx);
            float v = a_s[(size_t)sj[k] * 8 + h] + ad;
            v = (v >= 0.f) ? v : NEG_SLOPE * v;
            ex[k] = (idx < cnt) ? v : -INFINITY;
        }
        float m = ex[0];
        #pragma unroll
        for (int k = 1; k < KM; k++) m = fmaxf(m, ex[k]);
        m = fmaxf(m, __shfl_xor(m, 8));
        m = fmaxf(m, __shfl_xor(m, 16));
        m = fmaxf(m, __shfl_xor(m, 32));
        float s = 0.f;
        #pragma unroll
        for (int k = 0; k < KM; k++) {
            ex[k] = expf(ex[k] - m);
            s += ex[k];
        }
        s += __shfl_xor(s, 8);
        s += __shfl_xor(s, 16);
        s += __shfl_xor(s, 32);
        float inv = 1.f / (s + 1e-16f);
        #pragma unroll
        for (int k = 0; k < KM; k++) ex[k] *= inv;
        #pragma unroll
        for (int k = 0; k < KM; k++) {
            int idx = j + k * 8;
            int eo = __shfl(e_all, idx);
            if (idx < cnt) alpha1_out[(size_t)eo * 8 + h] = ex[k];
        }
        unsigned int pk[KM];
        #pragma unroll
        for (int k = 0; k < KM; k++)
            pk[k] = ((unsigned int)sj[k] << 16) | (unsigned int)f2bf(ex[k]);
        int rounds = (cnt + 7) >> 3;
        #pragma unroll
        for (int K = 0; K < KM; K++) {
            if (K < rounds) {
                float At[8];
                unsigned int qt[8];
                #pragma unroll
                for (int t = 0; t < 8; t++) {
                    unsigned int wv = (unsigned int)__shfl((int)pk[K], t * 8 + hl);
                    At[t] = bf2f((unsigned short)wv);
                    qt[t] = *(const unsigned int*)(hf8 + (((wv >> 16) << 8) | loff));
                }
                #pragma unroll
                for (int t = 0; t < 8; t++) {
                    float f0, f1, f2, f3;
                    f8x4(qt[t], f0, f1, f2, f3);
                    acc0 += At[t] * f0;
                    acc1 += At[t] * f1;
                    acc2 += At[t] * f2;
                    acc3 += At[t] * f3;
                }
            }
        }
    }
}

__global__ __launch_bounds__(256) void gat1_kernel(const int* __restrict__ row_ptr,
                                                   const int2* __restrict__ pairs,
                                                   const float* __restrict__ a_s,
                                                   const float* __restrict__ a_d,
                                                   const unsigned char* __restrict__ h1f8,
                                                   const float* __restrict__ b1,
                                                   float* __restrict__ alpha1_out,
                                                   __hip_bfloat16* __restrict__ x1bf) {
    int wv = threadIdx.x >> 6, lane = threadIdx.x & 63;
    int n = blockIdx.x * 4 + wv;
    if (n >= NN) return;
    int start = row_ptr[n], end = row_ptr[n + 1];
    int cnt = end - start;
    int h = lane & 7, j = lane >> 3;
    int hl = lane >> 3;
    unsigned int loff = (unsigned int)(lane << 2);
    float acc0 = 0.f, acc1 = 0.f, acc2 = 0.f, acc3 = 0.f;
    if (cnt > 0 && cnt <= 64) {
        float ad = a_d[(size_t)n * 8 + h];
        if (cnt <= 8)
            gat1_fast<1>(lane, start, cnt, pairs, a_s, ad, h1f8, alpha1_out, acc0, acc1, acc2, acc3);
        else if (cnt <= 16)
            gat1_fast<2>(lane, start, cnt, pairs, a_s, ad, h1f8, alpha1_out, acc0, acc1, acc2, acc3);
        else if (cnt <= 24)
            gat1_fast<3>(lane, start, cnt, pairs, a_s, ad, h1f8, alpha1_out, acc0, acc1, acc2, acc3);
        else if (cnt <= 32)
            gat1_fast<4>(lane, start, cnt, pairs, a_s, ad, h1f8, alpha1_out, acc0, acc1, acc2, acc3);
        else
            gat1_fast<8>(lane, start, cnt, pairs, a_s, ad, h1f8, alpha1_out, acc0, acc1, acc2, acc3);
    } else if (cnt > 64) {
        float ad = a_d[(size_t)n * 8 + h];
        float m = -INFINITY;
        for (int p = start + j; p < end; p += 8) {
            float v = a_s[(size_t)pairs[p].y * 8 + h] + ad;
            v = (v >= 0.f) ? v : NEG_SLOPE * v;
            m = fmaxf(m, v);
        }
        m = fmaxf(m, __shfl_xor(m, 8));
        m = fmaxf(m, __shfl_xor(m, 16));
        m = fmaxf(m, __shfl_xor(m, 32));
        float s = 0.f;
        for (int p = start + j; p < end; p += 8) {
            float v = a_s[(size_t)pairs[p].y * 8 + h] + ad;
            v = (v >= 0.f) ? v : NEG_SLOPE * v;
            s += expf(v - m);
        }
        s += __shfl_xor(s, 8);
        s += __shfl_xor(s, 16);
        s += __shfl_xor(s, 32);
        float inv = 1.f / (s + 1e-16f);
        for (int p = start + j; p < end; p += 8) {
            int2 ep = pairs[p];
            float v = a_s[(size_t)ep.y * 8 + h] + ad;
            v = (v >= 0.f) ? v : NEG_SLOPE * v;
            alpha1_out[(size_t)ep.x * 8 + h] = expf(v - m) * inv;
        }
        float mh = __shfl(m, hl);
        float invh = __shfl(inv, hl);
        float adh = __shfl(ad, hl);
        for (int p = start; p < end; p++) {
            int sp = pairs[p].y;
            float v = a_s[(size_t)sp * 8 + hl] + adh;
            v = (v >= 0.f) ? v : NEG_SLOPE * v;
            float al = expf(v - mh) * invh;
            unsigned int q = *(const unsigned int*)(h1f8 + (((unsigned int)sp << 8) | loff));
            float f0, f1, f2, f3;
            f8x4(q, f0, f1, f2, f3);
            acc0 += al * f0;
            acc1 += al * f1;
            acc2 += al * f2;
            acc3 += al * f3;
        }
    }
    float4 bb = *(const float4*)(b1 + lane * 4);
    float r0 = acc0 + bb.x, r1 = acc1 + bb.y, r2 = acc2 + bb.z, r3 = acc3 + bb.w;
    r0 = (r0 > 0.f) ? r0 : expf(r0) - 1.f;
    r1 = (r1 > 0.f) ? r1 : expf(r1) - 1.f;
    r2 = (r2 > 0.f) ? r2 : expf(r2) - 1.f;
    r3 = (r3 > 0.f) ? r3 : expf(r3) - 1.f;
    ushort4 o;
    o.x = f2bf(r0); o.y = f2bf(r1); o.z = f2bf(r2); o.w = f2bf(r3);
    *(ushort4*)((unsigned short*)x1bf + (size_t)n * HID1 + lane * 4) = o;
}

// ---------------- fused layer-2 softmax + aggregation ----------------
// RM buckets (rounds); issue-early row gathers; 32-bit offsets.

template <int RM>
__device__ __forceinline__ void gat2_fast(int lane, int start, int cnt, int r, int c,
                                          const int2* __restrict__ pairs,
                                          const float* __restrict__ a_s, float ad,
                                          const unsigned char* __restrict__ hf8,
                                          float* __restrict__ alpha2_out,
                                          float& acc0, float& acc1, float& acc2, float& acc3) {
    bool act = lane < cnt;
    int ii = min(lane, cnt - 1);
    int2 ep = pairs[start + ii];
    int sj = ep.y;
    float asv = a_s[sj];  // softmax gather issued FIRST
    unsigned int coff = (unsigned int)(c << 2);
    constexpr int NB = RM * 4;
    unsigned int qt[NB];
    #pragma unroll
    for (int t = 0; t < NB; t++) {
        int je = (t >> 2) * 8 + (t & 3) * 2 + r;
        int sje = __shfl(sj, je);
        qt[t] = *(const unsigned int*)(hf8 + (((unsigned int)sje << 7) | coff));
    }
    // softmax VALU while rows in flight
    float v = asv + ad;
    v = (v >= 0.f) ? v : NEG_SLOPE * v;
    float e = act ? v : -INFINITY;
    float m = e;
    #pragma unroll
    for (int off = 1; off < 64; off <<= 1) m = fmaxf(m, __shfl_xor(m, off));
    float ex = expf(e - m);
    float s = ex;
    #pragma unroll
    for (int off = 1; off < 64; off <<= 1) s += __shfl_xor(s, off);
    float al = ex / (s + 1e-16f);  // 0 for padded lanes
    if (act) alpha2_out[ep.x] = al;
    #pragma unroll
    for (int t = 0; t < NB; t++) {
        int je = (t >> 2) * 8 + (t & 3) * 2 + r;
        float At = __shfl(al, je);
        float f0, f1, f2, f3;
        f8x4(qt[t], f0, f1, f2, f3);
        acc0 += At * f0;
        acc1 += At * f1;
        acc2 += At * f2;
        acc3 += At * f3;
    }
}

__global__ __launch_bounds__(256) void gat2_kernel(const int* __restrict__ row_ptr,
                                                   const int2* __restrict__ pairs,
                                                   const float* __restrict__ a_s,
                                                   const float* __restrict__ a_d,
                                                   const unsigned char* __restrict__ h2f8,
                                                   const float* __restrict__ b2,
                                                   float* __restrict__ alpha2_out,
                                                   __hip_bfloat16* __restrict__ x2bf) {
    int wv = threadIdx.x >> 6, lane = threadIdx.x & 63;
    int n = blockIdx.x * 4 + wv;
    if (n >= NN) return;
    int start = row_ptr[n], end = row_ptr[n + 1];
    int cnt = end - start;
    int r = lane >> 5, c = lane & 31;
    float acc0 = 0.f, acc1 = 0.f, acc2 = 0.f, acc3 = 0.f;
    if (cnt > 0 && cnt <= 64) {
        float ad = a_d[n];
        if (cnt <= 8)
            gat2_fast<1>(lane, start, cnt, r, c, pairs, a_s, ad, h2f8, alpha2_out, acc0, acc1, acc2, acc3);
        else if (cnt <= 16)
            gat2_fast<2>(lane, start, cnt, r, c, pairs, a_s, ad, h2f8, alpha2_out, acc0, acc1, acc2, acc3);
        else if (cnt <= 32)
            gat2_fast<4>(lane, start, cnt, r, c, pairs, a_s, ad, h2f8, alpha2_out, acc0, acc1, acc2, acc3);
        else
            gat2_fast<8>(lane, start, cnt, r, c, pairs, a_s, ad, h2f8, alpha2_out, acc0, acc1, acc2, acc3);
    } else if (cnt > 64) {
        float ad = a_d[n];
        unsigned int coff = (unsigned int)(c << 2);
        float m = -INFINITY;
        for (int p = start + lane; p < end; p += 64) {
            float v = a_s[pairs[p].y] + ad;
            v = (v >= 0.f) ? v : NEG_SLOPE * v;
            m = fmaxf(m, v);
        }
        for (int off = 32; off; off >>= 1) m = fmaxf(m, __shfl_xor(m, off));
        float s = 0.f;
        for (int p = start + lane; p < end; p += 64) {
            float v = a_s[pairs[p].y] + ad;
            v = (v >= 0.f) ? v : NEG_SLOPE * v;
            s += expf(v - m);
        }
        for (int off = 32; off; off >>= 1) s += __shfl_xor(s, off);
        float inv = 1.f / (s + 1e-16f);
        for (int p = start + lane; p < end; p += 64) {
            int2 ep = pairs[p];
            float v = a_s[ep.y] + ad;
            v = (v >= 0.f) ? v : NEG_SLOPE * v;
            alpha2_out[ep.x] = expf(v - m) * inv;
        }
        for (int p = start + r; p < end; p += 2) {
            int sp = pairs[p].y;
            float v = a_s[sp] + ad;
            v = (v >= 0.f) ? v : NEG_SLOPE * v;
            float al = expf(v - m) * inv;
            unsigned int q = *(const unsigned int*)(h2f8 + (((unsigned int)sp << 7) | coff));
            float f0, f1, f2, f3;
            f8x4(q, f0, f1, f2, f3);
            acc0 += al * f0;
            acc1 += al * f1;
            acc2 += al * f2;
            acc3 += al * f3;
        }
    }
    acc0 += __shfl_xor(acc0, 32);
    acc1 += __shfl_xor(acc1, 32);
    acc2 += __shfl_xor(acc2, 32);
    acc3 += __shfl_xor(acc3, 32);
    if (r == 0) {
        float4 bb = *(const float4*)(b2 + c * 4);
        float r0 = acc0 + bb.x, r1 = acc1 + bb.y, r2 = acc2 + bb.z, r3 = acc3 + bb.w;
        r0 = (r0 > 0.f) ? r0 : 0.f;
        r1 = (r1 > 0.f) ? r1 : 0.f;
        r2 = (r2 > 0.f) ? r2 : 0.f;
        r3 = (r3 > 0.f) ? r3 : 0.f;
        ushort4 o;
        o.x = f2bf(r0); o.y = f2bf(r1); o.z = f2bf(r2); o.w = f2bf(r3);
        *(ushort4*)((unsigned short*)x2bf + (size_t)n * HID2 + c * 4) = o;
    }
}

// ---------------- host launch ----------------

extern "C" void kernel_launch(void* const* d_in, const int* in_sizes, int n_in,
                              void* d_out, int out_size, void* d_ws, size_t ws_size,
                              hipStream_t stream) {
    (void)in_sizes; (void)n_in; (void)out_size; (void)ws_size;
    const float* x        = (const float*)d_in[0];
    const int*   eindex   = (const int*)d_in[1];
    const float* W1       = (const float*)d_in[2];
    const float* att_src1 = (const float*)d_in[3];
    const float* att_dst1 = (const float*)d_in[4];
    const float* b1       = (const float*)d_in[5];
    const float* W2       = (const float*)d_in[6];
    const float* att_src2 = (const float*)d_in[7];
    const float* att_dst2 = (const float*)d_in[8];
    const float* b2       = (const float*)d_in[9];
    const float* fcW1     = (const float*)d_in[10];
    const float* fcb1     = (const float*)d_in[11];
    const float* fcW2     = (const float*)d_in[12];
    const float* fcb2     = (const float*)d_in[13];

    const int* src = eindex;
    const int* dst = eindex + EE;

    float* out_n      = (float*)d_out;               // [N]
    float* alpha1_out = out_n + NN;                  // [E,8]
    float* alpha2_out = alpha1_out + (size_t)EE * 8; // [E]

    char* ws = (char*)d_ws;
    size_t off = 0;
    auto alloc = [&](size_t bytes) {
        size_t o = off;
        off = (off + bytes + 255) & ~(size_t)255;
        return o;
    };
    size_t o_rowptr = alloc((NN + 1) * sizeof(int));
    size_t o_cursor = alloc(NN * sizeof(int));
    size_t o_counts = alloc(NN * sizeof(int));
    size_t o_excl   = alloc(NN * sizeof(int));
    size_t o_bsum   = alloc(64 * sizeof(int));
    size_t o_pairs  = alloc((size_t)EE * sizeof(int2));
    size_t o_as1    = alloc((size_t)NN * H1 * sizeof(float));
    size_t o_ad1    = alloc((size_t)NN * H1 * sizeof(float));
    size_t o_as2    = alloc((size_t)NN * sizeof(float));
    size_t o_ad2    = alloc((size_t)NN * sizeof(float));
    size_t o_h1f8   = alloc((size_t)NN * HID1);
    size_t o_xbf    = alloc((size_t)NN * IN_DIM * sizeof(__hip_bfloat16));
    size_t o_x1bf   = alloc((size_t)NN * HID1 * sizeof(__hip_bfloat16));
    size_t o_h2f8   = alloc((size_t)NN * HID2);
    size_t o_x2bf   = alloc((size_t)NN * HID2 * sizeof(__hip_bfloat16));
    size_t o_W1p    = alloc((size_t)IN_DIM * HID1 * sizeof(__hip_bfloat16));
    size_t o_W2p    = alloc((size_t)HID1 * HID2 * sizeof(__hip_bfloat16));
    size_t o_fW1p   = alloc((size_t)HID2 * FC1 * sizeof(__hip_bfloat16));

    int*   row_ptr = (int*)(ws + o_rowptr);
    int*   cursor  = (int*)(ws + o_cursor);
    int*   counts  = (int*)(ws + o_counts);
    int*   excl    = (int*)(ws + o_excl);
    int*   bsum    = (int*)(ws + o_bsum);
    int2*  pairs   = (int2*)(ws + o_pairs);
    float* a_s1    = (float*)(ws + o_as1);
    float* a_d1    = (float*)(ws + o_ad1);
    float* a_s2    = (float*)(ws + o_as2);
    float* a_d2    = (float*)(ws + o_ad2);
    unsigned char*  h1f8  = (unsigned char*)(ws + o_h1f8);
    __hip_bfloat16* xbf   = (__hip_bfloat16*)(ws + o_xbf);
    __hip_bfloat16* x1bf  = (__hip_bfloat16*)(ws + o_x1bf);
    unsigned char*  h2f8  = (unsigned char*)(ws + o_h2f8);
    __hip_bfloat16* x2bf  = (__hip_bfloat16*)(ws + o_x2bf);
    __hip_bfloat16* W1p   = (__hip_bfloat16*)(ws + o_W1p);
    __hip_bfloat16* W2p   = (__hip_bfloat16*)(ws + o_W2p);
    __hip_bfloat16* fW1p  = (__hip_bfloat16*)(ws + o_fW1p);

    const int SCAN_NB = (NN + 1023) / 1024;  // 49
    const int PREP_N = NN * IN_DIM + IN_DIM * HID1 + HID1 * HID2 + HID2 * FC1;

    hipMemsetAsync(counts, 0, NN * sizeof(int), stream);
    hipMemsetAsync(a_s2, 0, NN * sizeof(float), stream);
    hipMemsetAsync(a_d2, 0, NN * sizeof(float), stream);

    hist_kernel<<<(EE + 255) / 256, 256, 0, stream>>>(dst, counts);
    scan_a_kernel<<<SCAN_NB, 256, 0, stream>>>(counts, excl, bsum, NN);
    scan_b_kernel<<<1, 64, 0, stream>>>(bsum, row_ptr, SCAN_NB, NN);
    scan_c_kernel<<<SCAN_NB, 256, 0, stream>>>(excl, bsum, row_ptr, cursor, NN);
    scatter_kernel<<<(EE + 255) / 256, 256, 0, stream>>>(src, dst, cursor, pairs);

    prep_kernel<<<(PREP_N + 255) / 256, 256, 0, stream>>>(x, xbf, W1, W1p, W2, W2p, fcW1, fW1p);

    mgemm_kernel<1><<<dim3((NN + 127) / 128, HID1 / 64), 256, 0, stream>>>(
        xbf, W1p, h1f8, att_src1, att_dst1, a_s1, a_d1, NN, IN_DIM, HID1);
    gat1_kernel<<<(NN + 3) / 4, 256, 0, stream>>>(row_ptr, pairs, a_s1, a_d1,
                                                  h1f8, b1, alpha1_out, x1bf);

    mgemm_kernel<2><<<dim3((NN + 127) / 128, HID2 / 64), 256, 0, stream>>>(
        x1bf, W2p, h2f8, att_src2, att_dst2, a_s2, a_d2, NN, HID1, HID2);
    gat2_kernel<<<(NN + 3) / 4, 256, 0, stream>>>(row_ptr, pairs, a_s2, a_d2,
                                                  h2f8, b2, alpha2_out, x2bf);

    fc_mfma_kernel<<<(NN + 31) / 32, 256, 0, stream>>>(x2bf, fW1p, fcb1, fcW2, fcb2, out_n);
}

// Round 15
// 259.611 us; speedup vs baseline: 1.7040x; 1.0187x over previous
//
#include <hip/hip_runtime.h>
#include <hip/hip_bf16.h>
#include <hip/hip_fp8.h>
#include <math.h>

#define NN 50000
#define EE 800000
#define IN_DIM 128
#define H1 8
#define D1 32
#define HID1 256
#define HID2 128
#define FC1 512
#define NEG_SLOPE 0.2f
#define NREP 16

typedef short v8s __attribute__((ext_vector_type(8)));
typedef float v4f __attribute__((ext_vector_type(4)));
typedef float v2f __attribute__((ext_vector_type(2)));
typedef unsigned int v4u __attribute__((ext_vector_type(4)));

__device__ __forceinline__ float bf2f(unsigned short u) {
    unsigned int x = ((unsigned int)u) << 16;
    return __uint_as_float(x);
}
__device__ __forceinline__ unsigned short f2bf(float v) {
    __hip_bfloat16 h = __float2bfloat16(v);
    return *(unsigned short*)&h;
}
__device__ __forceinline__ unsigned char f2f8(float v) {
    __hip_fp8_e4m3 t(v);
    return (unsigned char)t.__x;
}
__device__ __forceinline__ float f8tof(unsigned char u) {
    __hip_fp8_e4m3 t;
    t.__x = (__hip_fp8_storage_t)u;
    return (float)t;
}

__device__ __forceinline__ void f8x4(unsigned int w, float& f0, float& f1, float& f2, float& f3) {
#if __has_builtin(__builtin_amdgcn_cvt_pk_f32_fp8)
    v2f lo = __builtin_amdgcn_cvt_pk_f32_fp8((int)w, false);
    v2f hi = __builtin_amdgcn_cvt_pk_f32_fp8((int)w, true);
    f0 = lo[0]; f1 = lo[1]; f2 = hi[0]; f3 = hi[1];
#else
    f0 = f8tof((unsigned char)(w & 0xff));
    f1 = f8tof((unsigned char)((w >> 8) & 0xff));
    f2 = f8tof((unsigned char)((w >> 16) & 0xff));
    f3 = f8tof((unsigned char)(w >> 24));
#endif
}

// ---------------- CSR build (16-way replicated counters to kill atomic contention) ----

__global__ void hist_kernel(const int* __restrict__ dst, int* __restrict__ counts_rep) {
    int e = blockIdx.x * blockDim.x + threadIdx.x;
    if (e >= EE) return;
    int r = blockIdx.x & (NREP - 1);
    atomicAdd(&counts_rep[r * NN + dst[e]], 1);
}

// counts_total[d] = sum over replicas (coalesced per replica)
__global__ void reduce_kernel(const int* __restrict__ counts_rep, int* __restrict__ counts_total) {
    int d = blockIdx.x * blockDim.x + threadIdx.x;
    if (d >= NN) return;
    int t = 0;
    #pragma unroll
    for (int r = 0; r < NREP; r++) t += counts_rep[r * NN + d];
    counts_total[d] = t;
}

__global__ __launch_bounds__(256) void scan_a_kernel(const int* __restrict__ counts,
                                                     int* __restrict__ excl,
                                                     int* __restrict__ bsum, int n) {
    __shared__ int wsum[4];
    int tid = threadIdx.x;
    int base = blockIdx.x * 1024 + tid * 4;
    int v0 = 0, v1 = 0, v2 = 0, v3 = 0;
    if (base + 3 < n) {
        int4 t = *(const int4*)(counts + base);
        v0 = t.x; v1 = t.y; v2 = t.z; v3 = t.w;
    } else {
        if (base + 0 < n) v0 = counts[base + 0];
        if (base + 1 < n) v1 = counts[base + 1];
        if (base + 2 < n) v2 = counts[base + 2];
        if (base + 3 < n) v3 = counts[base + 3];
    }
    int tot = v0 + v1 + v2 + v3;
    int lane = tid & 63;
    int w = tid >> 6;
    int x = tot;
    #pragma unroll
    for (int off = 1; off < 64; off <<= 1) {
        int y = __shfl_up(x, off);
        if (lane >= off) x += y;
    }
    if (lane == 63) wsum[w] = x;
    __syncthreads();
    int woff = 0;
    for (int i = 0; i < w; i++) woff += wsum[i];
    int et = woff + x - tot;
    if (base + 0 < n) excl[base + 0] = et;
    if (base + 1 < n) excl[base + 1] = et + v0;
    if (base + 2 < n) excl[base + 2] = et + v0 + v1;
    if (base + 3 < n) excl[base + 3] = et + v0 + v1 + v2;
    if (tid == 255) bsum[blockIdx.x] = woff + x;
}

__global__ __launch_bounds__(64) void scan_b_kernel(int* __restrict__ bsum,
                                                    int* __restrict__ row_ptr, int nb, int n) {
    int lane = threadIdx.x;
    int v = (lane < nb) ? bsum[lane] : 0;
    int x = v;
    #pragma unroll
    for (int off = 1; off < 64; off <<= 1) {
        int y = __shfl_up(x, off);
        if (lane >= off) x += y;
    }
    if (lane < nb) bsum[lane] = x - v;
    if (lane == 63) row_ptr[n] = x;
}

__global__ __launch_bounds__(256) void scan_c_kernel(const int* __restrict__ excl,
                                                     const int* __restrict__ bsum,
                                                     int* __restrict__ row_ptr, int n) {
    int base = blockIdx.x * 1024 + threadIdx.x * 4;
    int off = bsum[blockIdx.x];
    #pragma unroll
    for (int j = 0; j < 4; j++) {
        int i = base + j;
        if (i < n) row_ptr[i] = excl[i] + off;
    }
}

// per-replica scatter bases: cursor[r][d] = row_ptr[d] + sum_{r'<r} counts[r'][d]
__global__ void base_kernel(const int* __restrict__ row_ptr, const int* __restrict__ counts_rep,
                            int* __restrict__ cursor_rep) {
    int d = blockIdx.x * blockDim.x + threadIdx.x;
    if (d >= NN) return;
    int running = row_ptr[d];
    #pragma unroll
    for (int r = 0; r < NREP; r++) {
        cursor_rep[r * NN + d] = running;
        running += counts_rep[r * NN + d];
    }
}

__global__ void scatter_kernel(const int* __restrict__ src, const int* __restrict__ dst,
                               int* __restrict__ cursor_rep, int2* __restrict__ pairs) {
    int e = blockIdx.x * blockDim.x + threadIdx.x;
    if (e >= EE) return;
    int r = blockIdx.x & (NREP - 1);
    int d = dst[e];
    int p = atomicAdd(&cursor_rep[r * NN + d], 1);
    pairs[p] = make_int2(e, src[e]);
}

// ---- fused prep ----

__device__ __forceinline__ void pack_one(const float* __restrict__ B,
                                         __hip_bfloat16* __restrict__ Bp,
                                         int K, int N, int idx) {
    int k = idx / N, n = idx % N;
    int ntile = n >> 4, ks = k >> 5, kk = k & 31;
    int lane = (n & 15) | ((kk >> 3) << 4);
    int j = kk & 7;
    int KS = K >> 5;
    Bp[((size_t)(ntile * KS + ks) * 64 + lane) * 8 + j] = __float2bfloat16(B[idx]);
}

__global__ void prep_kernel(const float* __restrict__ x, __hip_bfloat16* __restrict__ xbf,
                            const float* __restrict__ W1, __hip_bfloat16* __restrict__ W1p,
                            const float* __restrict__ W2, __hip_bfloat16* __restrict__ W2p,
                            const float* __restrict__ fcW1, __hip_bfloat16* __restrict__ fW1p) {
    int i = blockIdx.x * blockDim.x + threadIdx.x;
    const int N0 = NN * IN_DIM;
    const int N1 = N0 + IN_DIM * HID1;
    const int N2 = N1 + HID1 * HID2;
    const int N3 = N2 + HID2 * FC1;
    if (i < N0) xbf[i] = __float2bfloat16(x[i]);
    else if (i < N1) pack_one(W1, W1p, IN_DIM, HID1, i - N0);
    else if (i < N2) pack_one(W2, W2p, HID1, HID2, i - N1);
    else if (i < N3) pack_one(fcW1, fW1p, HID2, FC1, i - N2);
}

// ---------------- MFMA GEMM (bf16 in, fp8 out) + fused attention logits ----------------

template <int ATT>
__global__ __launch_bounds__(256) void mgemm_kernel(const __hip_bfloat16* __restrict__ A,
                                                    const __hip_bfloat16* __restrict__ Bp,
                                                    unsigned char* __restrict__ Cf8,
                                                    const float* __restrict__ as_w,
                                                    const float* __restrict__ ad_w,
                                                    float* __restrict__ a_s,
                                                    float* __restrict__ a_d,
                                                    int M, int K, int N) {
    int w = threadIdx.x >> 6, l = threadIdx.x & 63;
    int bm = blockIdx.x * 128 + w * 32;
    int bn = blockIdx.y * 64;
    int lr = l & 15, lk = l >> 4;
    int KS = K >> 5;
    const short* Ab = (const short*)A;
    const short* Bb = (const short*)Bp;
    v4f acc[2][4];
    #pragma unroll
    for (int mi = 0; mi < 2; mi++)
        #pragma unroll
        for (int nt = 0; nt < 4; nt++) acc[mi][nt] = (v4f)(0.f);
    for (int ks = 0; ks < KS; ks++) {
        v8s a[2];
        #pragma unroll
        for (int mi = 0; mi < 2; mi++) {
            int gm = bm + mi * 16 + lr;
            a[mi] = (gm < M) ? *(const v8s*)(Ab + (size_t)gm * K + ks * 32 + lk * 8)
                             : (v8s)(short)0;
        }
        #pragma unroll
        for (int nt = 0; nt < 4; nt++) {
            int ntile = (bn >> 4) + nt;
            v8s b = *(const v8s*)(Bb + ((size_t)(ntile * KS + ks) * 64 + l) * 8);
            acc[0][nt] = __builtin_amdgcn_mfma_f32_16x16x32_bf16(a[0], b, acc[0][nt], 0, 0, 0);
            acc[1][nt] = __builtin_amdgcn_mfma_f32_16x16x32_bf16(a[1], b, acc[1][nt], 0, 0, 0);
        }
    }
    #pragma unroll
    for (int mi = 0; mi < 2; mi++) {
        #pragma unroll
        for (int nt = 0; nt < 4; nt++) {
            int gn = bn + nt * 16 + lr;
            #pragma unroll
            for (int j = 0; j < 4; j++) {
                int gm = bm + mi * 16 + lk * 4 + j;
                if (gm < M)
                    Cf8[(size_t)gm * N + gn] = f2f8(acc[mi][nt][j]);
            }
        }
    }
    float ws0 = as_w[bn + lr], ws1 = as_w[bn + 16 + lr];
    float ws2 = as_w[bn + 32 + lr], ws3 = as_w[bn + 48 + lr];
    float wd0 = ad_w[bn + lr], wd1 = ad_w[bn + 16 + lr];
    float wd2 = ad_w[bn + 32 + lr], wd3 = ad_w[bn + 48 + lr];
    float sA[2][4], dA[2][4], sB[2][4], dB[2][4];
    #pragma unroll
    for (int mi = 0; mi < 2; mi++)
        #pragma unroll
        for (int j = 0; j < 4; j++) {
            if constexpr (ATT == 1) {
                sA[mi][j] = acc[mi][0][j] * ws0 + acc[mi][1][j] * ws1;
                sB[mi][j] = acc[mi][2][j] * ws2 + acc[mi][3][j] * ws3;
                dA[mi][j] = acc[mi][0][j] * wd0 + acc[mi][1][j] * wd1;
                dB[mi][j] = acc[mi][2][j] * wd2 + acc[mi][3][j] * wd3;
            } else {
                sA[mi][j] = acc[mi][0][j] * ws0 + acc[mi][1][j] * ws1
                          + acc[mi][2][j] * ws2 + acc[mi][3][j] * ws3;
                dA[mi][j] = acc[mi][0][j] * wd0 + acc[mi][1][j] * wd1
                          + acc[mi][2][j] * wd2 + acc[mi][3][j] * wd3;
                sB[mi][j] = 0.f; dB[mi][j] = 0.f;
            }
        }
    #pragma unroll
    for (int off = 1; off < 16; off <<= 1) {
        #pragma unroll
        for (int mi = 0; mi < 2; mi++)
            #pragma unroll
            for (int j = 0; j < 4; j++) {
                sA[mi][j] += __shfl_xor(sA[mi][j], off);
                dA[mi][j] += __shfl_xor(dA[mi][j], off);
                if constexpr (ATT == 1) {
                    sB[mi][j] += __shfl_xor(sB[mi][j], off);
                    dB[mi][j] += __shfl_xor(dB[mi][j], off);
                }
            }
    }
    if (lr == 0) {
        #pragma unroll
        for (int mi = 0; mi < 2; mi++)
            #pragma unroll
            for (int j = 0; j < 4; j++) {
                int row = bm + mi * 16 + lk * 4 + j;
                if (row < M) {
                    if constexpr (ATT == 1) {
                        int h0 = bn >> 5;
                        a_s[(size_t)row * 8 + h0]     = sA[mi][j];
                        a_s[(size_t)row * 8 + h0 + 1] = sB[mi][j];
                        a_d[(size_t)row * 8 + h0]     = dA[mi][j];
                        a_d[(size_t)row * 8 + h0 + 1] = dB[mi][j];
                    } else {
                        atomicAdd(&a_s[row], sA[mi][j]);
                        atomicAdd(&a_d[row], dA[mi][j]);
                    }
                }
            }
    }
}

// ---------------- fused FC head via MFMA ----------------

__global__ __launch_bounds__(256) void fc_mfma_kernel(const __hip_bfloat16* __restrict__ A,
                                                      const __hip_bfloat16* __restrict__ Bp,
                                                      const float* __restrict__ fcb1,
                                                      const float* __restrict__ fcW2,
                                                      const float* __restrict__ fcb2,
                                                      float* __restrict__ out) {
    __shared__ float red[4][32];
    int w = threadIdx.x >> 6, l = threadIdx.x & 63;
    int bm = blockIdx.x * 32;
    int lr = l & 15, lk = l >> 4;
    const int K = HID2, KS = K >> 5;
    const short* Ab = (const short*)A;
    const short* Bb = (const short*)Bp;
    v4f acc[2][8];
    #pragma unroll
    for (int mi = 0; mi < 2; mi++)
        #pragma unroll
        for (int nt = 0; nt < 8; nt++) acc[mi][nt] = (v4f)(0.f);
    for (int ks = 0; ks < KS; ks++) {
        v8s a[2];
        #pragma unroll
        for (int mi = 0; mi < 2; mi++) {
            int gm = bm + mi * 16 + lr;
            a[mi] = (gm < NN) ? *(const v8s*)(Ab + (size_t)gm * K + ks * 32 + lk * 8)
                              : (v8s)(short)0;
        }
        #pragma unroll
        for (int nt = 0; nt < 8; nt++) {
            int ntile = w * 8 + nt;
            v8s b = *(const v8s*)(Bb + ((size_t)(ntile * KS + ks) * 64 + l) * 8);
            acc[0][nt] = __builtin_amdgcn_mfma_f32_16x16x32_bf16(a[0], b, acc[0][nt], 0, 0, 0);
            acc[1][nt] = __builtin_amdgcn_mfma_f32_16x16x32_bf16(a[1], b, acc[1][nt], 0, 0, 0);
        }
    }
    float p[2][4];
    #pragma unroll
    for (int mi = 0; mi < 2; mi++)
        #pragma unroll
        for (int j = 0; j < 4; j++) p[mi][j] = 0.f;
    #pragma unroll
    for (int nt = 0; nt < 8; nt++) {
        int col = w * 128 + nt * 16 + lr;
        float b1v = fcb1[col], w2v = fcW2[col];
        #pragma unroll
        for (int mi = 0; mi < 2; mi++) {
            #pragma unroll
            for (int j = 0; j < 4; j++) {
                float v = acc[mi][nt][j] + b1v;
                p[mi][j] += ((v > 0.f) ? v : 0.f) * w2v;
            }
        }
    }
    #pragma unroll
    for (int mi = 0; mi < 2; mi++)
        #pragma unroll
        for (int j = 0; j < 4; j++) {
            float v = p[mi][j];
            v += __shfl_xor(v, 1);
            v += __shfl_xor(v, 2);
            v += __shfl_xor(v, 4);
            v += __shfl_xor(v, 8);
            p[mi][j] = v;
        }
    if (lr == 0) {
        #pragma unroll
        for (int mi = 0; mi < 2; mi++)
            #pragma unroll
            for (int j = 0; j < 4; j++) red[w][mi * 16 + lk * 4 + j] = p[mi][j];
    }
    __syncthreads();
    int tid = threadIdx.x;
    if (tid < 32) {
        int gm = bm + tid;
        if (gm < NN)
            out[gm] = red[0][tid] + red[1][tid] + red[2][tid] + red[3][tid] + fcb2[0];
    }
}

// ---------------- fused layer-1 softmax + aggregation ----------------

template <int KM>
__device__ __forceinline__ void gat1_fast(int lane, int start, int cnt,
                                          const int2* __restrict__ pairs,
                                          const float* __restrict__ a_s, float ad,
                                          const unsigned char* __restrict__ hf8,
                                          float* __restrict__ alpha1_out,
                                          float& acc0, float& acc1, float& acc2, float& acc3) {
    int h = lane & 7, j = lane >> 3;
    int hl = lane >> 3;
    int cl = min(lane, cnt - 1);
    int2 ep = pairs[start + cl];
    int e_all = ep.x, s_all = ep.y;
    unsigned int loff = (unsigned int)(lane << 2);

    if constexpr (KM <= 4) {
        constexpr int NB = KM * 8;
        int sj[KM];
        float ev[KM];
        #pragma unroll
        for (int k = 0; k < KM; k++) {
            int idx = j + k * 8;
            sj[k] = __shfl(s_all, idx);
            ev[k] = a_s[(size_t)sj[k] * 8 + h];
        }
        unsigned int qt[NB];
        #pragma unroll
        for (int e = 0; e < NB; e++) {
            int sje = __shfl(s_all, e);
            qt[e] = *(const unsigned int*)(hf8 + (((unsigned int)sje << 8) | loff));
        }
        float ex[KM];
        #pragma unroll
        for (int k = 0; k < KM; k++) {
            int idx = j + k * 8;
            float v = ev[k] + ad;
            v = (v >= 0.f) ? v : NEG_SLOPE * v;
            ex[k] = (idx < cnt) ? v : -INFINITY;
        }
        float m = ex[0];
        #pragma unroll
        for (int k = 1; k < KM; k++) m = fmaxf(m, ex[k]);
        m = fmaxf(m, __shfl_xor(m, 8));
        m = fmaxf(m, __shfl_xor(m, 16));
        m = fmaxf(m, __shfl_xor(m, 32));
        float s = 0.f;
        #pragma unroll
        for (int k = 0; k < KM; k++) {
            ex[k] = expf(ex[k] - m);
            s += ex[k];
        }
        s += __shfl_xor(s, 8);
        s += __shfl_xor(s, 16);
        s += __shfl_xor(s, 32);
        float inv = 1.f / (s + 1e-16f);
        #pragma unroll
        for (int k = 0; k < KM; k++) ex[k] *= inv;
        #pragma unroll
        for (int k = 0; k < KM; k++) {
            int idx = j + k * 8;
            int eo = __shfl(e_all, idx);
            if (idx < cnt) alpha1_out[(size_t)eo * 8 + h] = ex[k];
        }
        #pragma unroll
        for (int e = 0; e < NB; e++) {
            float At = __shfl(ex[e >> 3], (e & 7) * 8 + hl);
            float f0, f1, f2, f3;
            f8x4(qt[e], f0, f1, f2, f3);
            acc0 += At * f0;
            acc1 += At * f1;
            acc2 += At * f2;
            acc3 += At * f3;
        }
    } else {
        float ex[KM];
        int sj[KM];
        #pragma unroll
        for (int k = 0; k < KM; k++) {
            int idx = j + k * 8;
            sj[k] = __shfl(s_all, idx);
            float v = a_s[(size_t)sj[k] * 8 + h] + ad;
            v = (v >= 0.f) ? v : NEG_SLOPE * v;
            ex[k] = (idx < cnt) ? v : -INFINITY;
        }
        float m = ex[0];
        #pragma unroll
        for (int k = 1; k < KM; k++) m = fmaxf(m, ex[k]);
        m = fmaxf(m, __shfl_xor(m, 8));
        m = fmaxf(m, __shfl_xor(m, 16));
        m = fmaxf(m, __shfl_xor(m, 32));
        float s = 0.f;
        #pragma unroll
        for (int k = 0; k < KM; k++) {
            ex[k] = expf(ex[k] - m);
            s += ex[k];
        }
        s += __shfl_xor(s, 8);
        s += __shfl_xor(s, 16);
        s += __shfl_xor(s, 32);
        float inv = 1.f / (s + 1e-16f);
        #pragma unroll
        for (int k = 0; k < KM; k++) ex[k] *= inv;
        #pragma unroll
        for (int k = 0; k < KM; k++) {
            int idx = j + k * 8;
            int eo = __shfl(e_all, idx);
            if (idx < cnt) alpha1_out[(size_t)eo * 8 + h] = ex[k];
        }
        unsigned int pk[KM];
        #pragma unroll
        for (int k = 0; k < KM; k++)
            pk[k] = ((unsigned int)sj[k] << 16) | (unsigned int)f2bf(ex[k]);
        int rounds = (cnt + 7) >> 3;
        #pragma unroll
        for (int K = 0; K < KM; K++) {
            if (K < rounds) {
                float At[8];
                unsigned int qt[8];
                #pragma unroll
                for (int t = 0; t < 8; t++) {
                    unsigned int wv = (unsigned int)__shfl((int)pk[K], t * 8 + hl);
                    At[t] = bf2f((unsigned short)wv);
                    qt[t] = *(const unsigned int*)(hf8 + (((wv >> 16) << 8) | loff));
                }
                #pragma unroll
                for (int t = 0; t < 8; t++) {
                    float f0, f1, f2, f3;
                    f8x4(qt[t], f0, f1, f2, f3);
                    acc0 += At[t] * f0;
                    acc1 += At[t] * f1;
                    acc2 += At[t] * f2;
                    acc3 += At[t] * f3;
                }
            }
        }
    }
}

__global__ __launch_bounds__(256) void gat1_kernel(const int* __restrict__ row_ptr,
                                                   const int2* __restrict__ pairs,
                                                   const float* __restrict__ a_s,
                                                   const float* __restrict__ a_d,
                                                   const unsigned char* __restrict__ h1f8,
                                                   const float* __restrict__ b1,
                                                   float* __restrict__ alpha1_out,
                                                   __hip_bfloat16* __restrict__ x1bf) {
    int wv = threadIdx.x >> 6, lane = threadIdx.x & 63;
    int n = blockIdx.x * 4 + wv;
    if (n >= NN) return;
    int start = row_ptr[n], end = row_ptr[n + 1];
    int cnt = end - start;
    int h = lane & 7, j = lane >> 3;
    int hl = lane >> 3;
    unsigned int loff = (unsigned int)(lane << 2);
    float acc0 = 0.f, acc1 = 0.f, acc2 = 0.f, acc3 = 0.f;
    if (cnt > 0 && cnt <= 64) {
        float ad = a_d[(size_t)n * 8 + h];
        if (cnt <= 8)
            gat1_fast<1>(lane, start, cnt, pairs, a_s, ad, h1f8, alpha1_out, acc0, acc1, acc2, acc3);
        else if (cnt <= 16)
            gat1_fast<2>(lane, start, cnt, pairs, a_s, ad, h1f8, alpha1_out, acc0, acc1, acc2, acc3);
        else if (cnt <= 24)
            gat1_fast<3>(lane, start, cnt, pairs, a_s, ad, h1f8, alpha1_out, acc0, acc1, acc2, acc3);
        else if (cnt <= 32)
            gat1_fast<4>(lane, start, cnt, pairs, a_s, ad, h1f8, alpha1_out, acc0, acc1, acc2, acc3);
        else
            gat1_fast<8>(lane, start, cnt, pairs, a_s, ad, h1f8, alpha1_out, acc0, acc1, acc2, acc3);
    } else if (cnt > 64) {
        float ad = a_d[(size_t)n * 8 + h];
        float m = -INFINITY;
        for (int p = start + j; p < end; p += 8) {
            float v = a_s[(size_t)pairs[p].y * 8 + h] + ad;
            v = (v >= 0.f) ? v : NEG_SLOPE * v;
            m = fmaxf(m, v);
        }
        m = fmaxf(m, __shfl_xor(m, 8));
        m = fmaxf(m, __shfl_xor(m, 16));
        m = fmaxf(m, __shfl_xor(m, 32));
        float s = 0.f;
        for (int p = start + j; p < end; p += 8) {
            float v = a_s[(size_t)pairs[p].y * 8 + h] + ad;
            v = (v >= 0.f) ? v : NEG_SLOPE * v;
            s += expf(v - m);
        }
        s += __shfl_xor(s, 8);
        s += __shfl_xor(s, 16);
        s += __shfl_xor(s, 32);
        float inv = 1.f / (s + 1e-16f);
        for (int p = start + j; p < end; p += 8) {
            int2 ep = pairs[p];
            float v = a_s[(size_t)ep.y * 8 + h] + ad;
            v = (v >= 0.f) ? v : NEG_SLOPE * v;
            alpha1_out[(size_t)ep.x * 8 + h] = expf(v - m) * inv;
        }
        float mh = __shfl(m, hl);
        float invh = __shfl(inv, hl);
        float adh = __shfl(ad, hl);
        for (int p = start; p < end; p++) {
            int sp = pairs[p].y;
            float v = a_s[(size_t)sp * 8 + hl] + adh;
            v = (v >= 0.f) ? v : NEG_SLOPE * v;
            float al = expf(v - mh) * invh;
            unsigned int q = *(const unsigned int*)(h1f8 + (((unsigned int)sp << 8) | loff));
            float f0, f1, f2, f3;
            f8x4(q, f0, f1, f2, f3);
            acc0 += al * f0;
            acc1 += al * f1;
            acc2 += al * f2;
            acc3 += al * f3;
        }
    }
    float4 bb = *(const float4*)(b1 + lane * 4);
    float r0 = acc0 + bb.x, r1 = acc1 + bb.y, r2 = acc2 + bb.z, r3 = acc3 + bb.w;
    r0 = (r0 > 0.f) ? r0 : expf(r0) - 1.f;
    r1 = (r1 > 0.f) ? r1 : expf(r1) - 1.f;
    r2 = (r2 > 0.f) ? r2 : expf(r2) - 1.f;
    r3 = (r3 > 0.f) ? r3 : expf(r3) - 1.f;
    ushort4 o;
    o.x = f2bf(r0); o.y = f2bf(r1); o.z = f2bf(r2); o.w = f2bf(r3);
    *(ushort4*)((unsigned short*)x1bf + (size_t)n * HID1 + lane * 4) = o;
}

// ---------------- fused layer-2 softmax + aggregation ----------------

template <int RM>
__device__ __forceinline__ void gat2_fast(int lane, int start, int cnt, int r, int c,
                                          const int2* __restrict__ pairs,
                                          const float* __restrict__ a_s, float ad,
                                          const unsigned char* __restrict__ hf8,
                                          float* __restrict__ alpha2_out,
                                          float& acc0, float& acc1, float& acc2, float& acc3) {
    bool act = lane < cnt;
    int ii = min(lane, cnt - 1);
    int2 ep = pairs[start + ii];
    int sj = ep.y;
    float asv = a_s[sj];
    unsigned int coff = (unsigned int)(c << 2);
    constexpr int NB = RM * 4;
    unsigned int qt[NB];
    #pragma unroll
    for (int t = 0; t < NB; t++) {
        int je = (t >> 2) * 8 + (t & 3) * 2 + r;
        int sje = __shfl(sj, je);
        qt[t] = *(const unsigned int*)(hf8 + (((unsigned int)sje << 7) | coff));
    }
    float v = asv + ad;
    v = (v >= 0.f) ? v : NEG_SLOPE * v;
    float e = act ? v : -INFINITY;
    float m = e;
    #pragma unroll
    for (int off = 1; off < 64; off <<= 1) m = fmaxf(m, __shfl_xor(m, off));
    float ex = expf(e - m);
    float s = ex;
    #pragma unroll
    for (int off = 1; off < 64; off <<= 1) s += __shfl_xor(s, off);
    float al = ex / (s + 1e-16f);
    if (act) alpha2_out[ep.x] = al;
    #pragma unroll
    for (int t = 0; t < NB; t++) {
        int je = (t >> 2) * 8 + (t & 3) * 2 + r;
        float At = __shfl(al, je);
        float f0, f1, f2, f3;
        f8x4(qt[t], f0, f1, f2, f3);
        acc0 += At * f0;
        acc1 += At * f1;
        acc2 += At * f2;
        acc3 += At * f3;
    }
}

__global__ __launch_bounds__(256) void gat2_kernel(const int* __restrict__ row_ptr,
                                                   const int2* __restrict__ pairs,
                                                   const float* __restrict__ a_s,
                                                   const float* __restrict__ a_d,
                                                   const unsigned char* __restrict__ h2f8,
                                                   const float* __restrict__ b2,
                                                   float* __restrict__ alpha2_out,
                                                   __hip_bfloat16* __restrict__ x2bf) {
    int wv = threadIdx.x >> 6, lane = threadIdx.x & 63;
    int n = blockIdx.x * 4 + wv;
    if (n >= NN) return;
    int start = row_ptr[n], end = row_ptr[n + 1];
    int cnt = end - start;
    int r = lane >> 5, c = lane & 31;
    float acc0 = 0.f, acc1 = 0.f, acc2 = 0.f, acc3 = 0.f;
    if (cnt > 0 && cnt <= 64) {
        float ad = a_d[n];
        if (cnt <= 8)
            gat2_fast<1>(lane, start, cnt, r, c, pairs, a_s, ad, h2f8, alpha2_out, acc0, acc1, acc2, acc3);
        else if (cnt <= 16)
            gat2_fast<2>(lane, start, cnt, r, c, pairs, a_s, ad, h2f8, alpha2_out, acc0, acc1, acc2, acc3);
        else if (cnt <= 32)
            gat2_fast<4>(lane, start, cnt, r, c, pairs, a_s, ad, h2f8, alpha2_out, acc0, acc1, acc2, acc3);
        else
            gat2_fast<8>(lane, start, cnt, r, c, pairs, a_s, ad, h2f8, alpha2_out, acc0, acc1, acc2, acc3);
    } else if (cnt > 64) {
        float ad = a_d[n];
        unsigned int coff = (unsigned int)(c << 2);
        float m = -INFINITY;
        for (int p = start + lane; p < end; p += 64) {
            float v = a_s[pairs[p].y] + ad;
            v = (v >= 0.f) ? v : NEG_SLOPE * v;
            m = fmaxf(m, v);
        }
        for (int off = 32; off; off >>= 1) m = fmaxf(m, __shfl_xor(m, off));
        float s = 0.f;
        for (int p = start + lane; p < end; p += 64) {
            float v = a_s[pairs[p].y] + ad;
            v = (v >= 0.f) ? v : NEG_SLOPE * v;
            s += expf(v - m);
        }
        for (int off = 32; off; off >>= 1) s += __shfl_xor(s, off);
        float inv = 1.f / (s + 1e-16f);
        for (int p = start + lane; p < end; p += 64) {
            int2 ep = pairs[p];
            float v = a_s[ep.y] + ad;
            v = (v >= 0.f) ? v : NEG_SLOPE * v;
            alpha2_out[ep.x] = expf(v - m) * inv;
        }
        for (int p = start + r; p < end; p += 2) {
            int sp = pairs[p].y;
            float v = a_s[sp] + ad;
            v = (v >= 0.f) ? v : NEG_SLOPE * v;
            float al = expf(v - m) * inv;
            unsigned int q = *(const unsigned int*)(h2f8 + (((unsigned int)sp << 7) | coff));
            float f0, f1, f2, f3;
            f8x4(q, f0, f1, f2, f3);
            acc0 += al * f0;
            acc1 += al * f1;
            acc2 += al * f2;
            acc3 += al * f3;
        }
    }
    acc0 += __shfl_xor(acc0, 32);
    acc1 += __shfl_xor(acc1, 32);
    acc2 += __shfl_xor(acc2, 32);
    acc3 += __shfl_xor(acc3, 32);
    if (r == 0) {
        float4 bb = *(const float4*)(b2 + c * 4);
        float r0 = acc0 + bb.x, r1 = acc1 + bb.y, r2 = acc2 + bb.z, r3 = acc3 + bb.w;
        r0 = (r0 > 0.f) ? r0 : 0.f;
        r1 = (r1 > 0.f) ? r1 : 0.f;
        r2 = (r2 > 0.f) ? r2 : 0.f;
        r3 = (r3 > 0.f) ? r3 : 0.f;
        ushort4 o;
        o.x = f2bf(r0); o.y = f2bf(r1); o.z = f2bf(r2); o.w = f2bf(r3);
        *(ushort4*)((unsigned short*)x2bf + (size_t)n * HID2 + c * 4) = o;
    }
}

// ---------------- host launch ----------------

extern "C" void kernel_launch(void* const* d_in, const int* in_sizes, int n_in,
                              void* d_out, int out_size, void* d_ws, size_t ws_size,
                              hipStream_t stream) {
    (void)in_sizes; (void)n_in; (void)out_size; (void)ws_size;
    const float* x        = (const float*)d_in[0];
    const int*   eindex   = (const int*)d_in[1];
    const float* W1       = (const float*)d_in[2];
    const float* att_src1 = (const float*)d_in[3];
    const float* att_dst1 = (const float*)d_in[4];
    const float* b1       = (const float*)d_in[5];
    const float* W2       = (const float*)d_in[6];
    const float* att_src2 = (const float*)d_in[7];
    const float* att_dst2 = (const float*)d_in[8];
    const float* b2       = (const float*)d_in[9];
    const float* fcW1     = (const float*)d_in[10];
    const float* fcb1     = (const float*)d_in[11];
    const float* fcW2     = (const float*)d_in[12];
    const float* fcb2     = (const float*)d_in[13];

    const int* src = eindex;
    const int* dst = eindex + EE;

    float* out_n      = (float*)d_out;               // [N]
    float* alpha1_out = out_n + NN;                  // [E,8]
    float* alpha2_out = alpha1_out + (size_t)EE * 8; // [E]

    char* ws = (char*)d_ws;
    size_t off = 0;
    auto alloc = [&](size_t bytes) {
        size_t o = off;
        off = (off + bytes + 255) & ~(size_t)255;
        return o;
    };
    size_t o_rowptr = alloc((NN + 1) * sizeof(int));
    size_t o_crep   = alloc((size_t)NREP * NN * sizeof(int));  // replicated counts
    size_t o_curs   = alloc((size_t)NREP * NN * sizeof(int));  // replicated cursors
    size_t o_ctot   = alloc(NN * sizeof(int));
    size_t o_excl   = alloc(NN * sizeof(int));
    size_t o_bsum   = alloc(64 * sizeof(int));
    size_t o_pairs  = alloc((size_t)EE * sizeof(int2));
    size_t o_as1    = alloc((size_t)NN * H1 * sizeof(float));
    size_t o_ad1    = alloc((size_t)NN * H1 * sizeof(float));
    size_t o_as2    = alloc((size_t)NN * sizeof(float));
    size_t o_ad2    = alloc((size_t)NN * sizeof(float));
    size_t o_h1f8   = alloc((size_t)NN * HID1);
    size_t o_xbf    = alloc((size_t)NN * IN_DIM * sizeof(__hip_bfloat16));
    size_t o_x1bf   = alloc((size_t)NN * HID1 * sizeof(__hip_bfloat16));
    size_t o_h2f8   = alloc((size_t)NN * HID2);
    size_t o_x2bf   = alloc((size_t)NN * HID2 * sizeof(__hip_bfloat16));
    size_t o_W1p    = alloc((size_t)IN_DIM * HID1 * sizeof(__hip_bfloat16));
    size_t o_W2p    = alloc((size_t)HID1 * HID2 * sizeof(__hip_bfloat16));
    size_t o_fW1p   = alloc((size_t)HID2 * FC1 * sizeof(__hip_bfloat16));

    int*   row_ptr    = (int*)(ws + o_rowptr);
    int*   counts_rep = (int*)(ws + o_crep);
    int*   cursor_rep = (int*)(ws + o_curs);
    int*   counts_tot = (int*)(ws + o_ctot);
    int*   excl       = (int*)(ws + o_excl);
    int*   bsum       = (int*)(ws + o_bsum);
    int2*  pairs      = (int2*)(ws + o_pairs);
    float* a_s1       = (float*)(ws + o_as1);
    float* a_d1       = (float*)(ws + o_ad1);
    float* a_s2       = (float*)(ws + o_as2);
    float* a_d2       = (float*)(ws + o_ad2);
    unsigned char*  h1f8  = (unsigned char*)(ws + o_h1f8);
    __hip_bfloat16* xbf   = (__hip_bfloat16*)(ws + o_xbf);
    __hip_bfloat16* x1bf  = (__hip_bfloat16*)(ws + o_x1bf);
    unsigned char*  h2f8  = (unsigned char*)(ws + o_h2f8);
    __hip_bfloat16* x2bf  = (__hip_bfloat16*)(ws + o_x2bf);
    __hip_bfloat16* W1p   = (__hip_bfloat16*)(ws + o_W1p);
    __hip_bfloat16* W2p   = (__hip_bfloat16*)(ws + o_W2p);
    __hip_bfloat16* fW1p  = (__hip_bfloat16*)(ws + o_fW1p);

    const int SCAN_NB = (NN + 1023) / 1024;  // 49
    const int PREP_N = NN * IN_DIM + IN_DIM * HID1 + HID1 * HID2 + HID2 * FC1;

    hipMemsetAsync(counts_rep, 0, (size_t)NREP * NN * sizeof(int), stream);
    hipMemsetAsync(a_s2, 0, NN * sizeof(float), stream);
    hipMemsetAsync(a_d2, 0, NN * sizeof(float), stream);

    // ---- CSR build with contention-spread atomics ----
    hist_kernel<<<(EE + 255) / 256, 256, 0, stream>>>(dst, counts_rep);
    reduce_kernel<<<(NN + 255) / 256, 256, 0, stream>>>(counts_rep, counts_tot);
    scan_a_kernel<<<SCAN_NB, 256, 0, stream>>>(counts_tot, excl, bsum, NN);
    scan_b_kernel<<<1, 64, 0, stream>>>(bsum, row_ptr, SCAN_NB, NN);
    scan_c_kernel<<<SCAN_NB, 256, 0, stream>>>(excl, bsum, row_ptr, NN);
    base_kernel<<<(NN + 255) / 256, 256, 0, stream>>>(row_ptr, counts_rep, cursor_rep);
    scatter_kernel<<<(EE + 255) / 256, 256, 0, stream>>>(src, dst, cursor_rep, pairs);

    prep_kernel<<<(PREP_N + 255) / 256, 256, 0, stream>>>(x, xbf, W1, W1p, W2, W2p, fcW1, fW1p);

    mgemm_kernel<1><<<dim3((NN + 127) / 128, HID1 / 64), 256, 0, stream>>>(
        xbf, W1p, h1f8, att_src1, att_dst1, a_s1, a_d1, NN, IN_DIM, HID1);
    gat1_kernel<<<(NN + 3) / 4, 256, 0, stream>>>(row_ptr, pairs, a_s1, a_d1,
                                                  h1f8, b1, alpha1_out, x1bf);

    mgemm_kernel<2><<<dim3((NN + 127) / 128, HID2 / 64), 256, 0, stream>>>(
        x1bf, W2p, h2f8, att_src2, att_dst2, a_s2, a_d2, NN, HID1, HID2);
    gat2_kernel<<<(NN + 3) / 4, 256, 0, stream>>>(row_ptr, pairs, a_s2, a_d2,
                                                  h2f8, b2, alpha2_out, x2bf);

    fc_mfma_kernel<<<(NN + 31) / 32, 256, 0, stream>>>(x2bf, fW1p, fcb1, fcW2, fcb2, out_n);
}